// Round 3
// baseline (1333.486 us; speedup 1.0000x reference)
//
#include <hip/hip_runtime.h>
#include <stdint.h>

#define B_ 2
#define S_ 2048
#define D_ 4096
#define H_ 32
#define KV_ 8
#define HD_ 128
#define M_ (B_*S_)          // 4096 rows (b*S+s)
#define NQ_ (H_*HD_)        // 4096
#define NKV_ (KV_*HD_)      // 1024

typedef unsigned short u16;
typedef __bf16 bf16x8 __attribute__((ext_vector_type(8)));
typedef float f32x4 __attribute__((ext_vector_type(4)));
typedef u16 u16x8 __attribute__((ext_vector_type(8)));
typedef u16 u16x4 __attribute__((ext_vector_type(4)));

__device__ __forceinline__ u16 f2bf(float f) {
  union { float f; unsigned u; } v; v.f = f;
  unsigned r = v.u + 0x7fffu + ((v.u >> 16) & 1u);
  return (u16)(r >> 16);
}
__device__ __forceinline__ u16 f2bft(float f) {  // truncating (for P; values in [0,1])
  union { float f; unsigned u; } v; v.f = f;
  return (u16)(v.u >> 16);
}
__device__ __forceinline__ float bf2f(u16 u) {
  union { unsigned u; float f; } v; v.u = ((unsigned)u) << 16;
  return v.f;
}
__device__ __forceinline__ f32x4 mfma16(bf16x8 a, bf16x8 b, f32x4 c) {
  return __builtin_amdgcn_mfma_f32_16x16x32_bf16(a, b, c, 0, 0, 0);
}

#define GLDS16(gp, lp) __builtin_amdgcn_global_load_lds( \
    (const __attribute__((address_space(1))) unsigned int*)(gp), \
    (__attribute__((address_space(3))) unsigned int*)(lp), 16, 0, 0)

// ---------------- fp32 -> bf16 convert (vectorized) ----------------
__global__ __launch_bounds__(256) void cvt_bf16(const float* __restrict__ in,
                                                u16* __restrict__ out, int n) {
  int i = (blockIdx.x * 256 + threadIdx.x) * 8;
  if (i >= n) return;
  float4 a = *(const float4*)(in + i);
  float4 b = *(const float4*)(in + i + 4);
  u16x8 o;
  o[0]=f2bf(a.x); o[1]=f2bf(a.y); o[2]=f2bf(a.z); o[3]=f2bf(a.w);
  o[4]=f2bf(b.x); o[5]=f2bf(b.y); o[6]=f2bf(b.z); o[7]=f2bf(b.w);
  *(u16x8*)(out + i) = o;
}

// ---------------- transpose + convert: out[c][r] = in[r][c] ----------------
__global__ __launch_bounds__(256) void tcvt(const float* __restrict__ in,
                                            u16* __restrict__ out, int R, int C) {
  __shared__ __attribute__((aligned(16))) u16 tile[32][33];
  int c0 = blockIdx.x * 32, r0 = blockIdx.y * 32;
  int tx = threadIdx.x & 31, ty = threadIdx.x >> 5;
  #pragma unroll
  for (int j = ty; j < 32; j += 8)
    tile[j][tx] = f2bf(in[(size_t)(r0 + j) * C + c0 + tx]);
  __syncthreads();
  #pragma unroll
  for (int j = ty; j < 32; j += 8)
    out[(size_t)(c0 + j) * R + r0 + tx] = tile[tx][j];
}

// ---------------- GEMM: C = A[M,K] * BT[N,K]^T ----------------
// OUTMODE: 0 = bf16 row-major C[M][N]; 1 = f32 row-major;
//          2 = bf16 V^T tiled: out[((b*KV+kv)*32 + t)*8192 + d*64 + s6]
//              where row=b*2048+t*64+s6 (s), col=kv*128+d. 16KB contiguous tiles.
template<int OUTMODE>
__global__ __launch_bounds__(256) void gemm_bt(const u16* __restrict__ A,
    const u16* __restrict__ BT, void* __restrict__ Cv, int M, int N, int K) {
  __shared__ __attribute__((aligned(16))) u16 As[128 * 32];
  __shared__ __attribute__((aligned(16))) u16 Bs[128 * 32];
  const int tid = threadIdx.x;
  const int bn0 = blockIdx.x * 128, bm0 = blockIdx.y * 128;
  const int w = tid >> 6, l = tid & 63, g = l >> 4, q = l & 15;
  const int wm = (w >> 1) * 64, wn = (w & 1) * 64;
  f32x4 acc[4][4] = {};
  for (int kt = 0; kt < K; kt += 32) {
    __syncthreads();
    #pragma unroll
    for (int p = 0; p < 2; ++p) {
      int c = tid + p * 256;
      int row = c >> 2, slot = c & 3;
      int srck = (slot ^ ((row >> 1) & 3)) << 3;
      GLDS16(A + (size_t)(bm0 + row) * K + kt + srck, As + c * 8);
      GLDS16(BT + (size_t)(bn0 + row) * K + kt + srck, Bs + c * 8);
    }
    __syncthreads();
    bf16x8 af[4], bfr[4];
    #pragma unroll
    for (int m = 0; m < 4; ++m) {
      int row = wm + m * 16 + q;
      af[m] = *(const bf16x8*)(As + row * 32 + ((g ^ ((row >> 1) & 3)) << 3));
    }
    #pragma unroll
    for (int n = 0; n < 4; ++n) {
      int row = wn + n * 16 + q;
      bfr[n] = *(const bf16x8*)(Bs + row * 32 + ((g ^ ((row >> 1) & 3)) << 3));
    }
    #pragma unroll
    for (int m = 0; m < 4; ++m)
      #pragma unroll
      for (int n = 0; n < 4; ++n)
        acc[m][n] = mfma16(af[m], bfr[n], acc[m][n]);
  }
  #pragma unroll
  for (int m = 0; m < 4; ++m)
    #pragma unroll
    for (int n = 0; n < 4; ++n) {
      if (OUTMODE == 2) {
        int row0 = bm0 + wm + m * 16 + g * 4;      // s index (global over b*S)
        int col  = bn0 + wn + n * 16 + q;          // kv*128 + d
        u16x4 pk;
        #pragma unroll
        for (int j = 0; j < 4; ++j) pk[j] = f2bf(acc[m][n][j]);
        size_t off = ((size_t)((row0 >> 11) * KV_ + (col >> 7)) * 32 + ((row0 >> 6) & 31)) * 8192
                   + (size_t)(col & 127) * 64 + (row0 & 63);
        *(u16x4*)((u16*)Cv + off) = pk;
      } else {
        #pragma unroll
        for (int j = 0; j < 4; ++j) {
          size_t off = (size_t)(bm0 + wm + m * 16 + g * 4 + j) * N + (bn0 + wn + n * 16 + q);
          if (OUTMODE == 1) ((float*)Cv)[off] = acc[m][n][j];
          else              ((u16*)Cv)[off]  = f2bf(acc[m][n][j]);
        }
      }
    }
}

// ---------------- RoPE (interleaved pairs, in-place on bf16) ----------------
__global__ __launch_bounds__(256) void rope_kernel(u16* __restrict__ t,
    const float* __restrict__ fc, const float* __restrict__ fs,
    int log2ppr, int total_pairs) {
  int i = blockIdx.x * 256 + threadIdx.x;
  if (i >= total_pairs) return;
  int fi = i & 63;
  int row = i >> log2ppr;           // b*S + s
  int pos = row & (S_ - 1);
  float c = fc[pos * 64 + fi], s = fs[pos * 64 + fi];
  unsigned* p = (unsigned*)(t + 2 * (size_t)i);
  unsigned v = *p;
  float x0 = bf2f((u16)(v & 0xffffu)), x1 = bf2f((u16)(v >> 16));
  float r0 = x0 * c - x1 * s, r1 = x0 * s + x1 * c;
  *p = (unsigned)f2bf(r0) | ((unsigned)f2bf(r1) << 16);
}

// ---------------- causal GQA flash attention ----------------
// grid (16, H, B), qt = 15-bx (long tiles first); block 256 = 4 waves,
// QT=128 (32 q-rows/wave), KT=64. K LDS [64][128] swz(row&7);
// V^T LDS [128][64] swz(row&7) staged from CONTIGUOUS 16KB global tiles;
// P LDS per-wave [32][64] swz((r>>1)&7). All b128 reads 2-way max (free).
__global__ __launch_bounds__(256, 3) void attn_kernel(
    const u16* __restrict__ Qb, const u16* __restrict__ Kb,
    const u16* __restrict__ VTg, u16* __restrict__ Ob) {
  __shared__ __attribute__((aligned(16))) u16 SM[24576]; // 48KB
  __shared__ float fstat[4][32];
  __shared__ float lstat[4][32];
  u16* Ks  = SM;           // [64][128] swz
  u16* VTs = SM + 8192;    // [128][64] swz
  u16* Ps  = SM + 16384;   // 4 x [32][64] swz
  const int qt = 15 - (int)blockIdx.x;
  const int h = blockIdx.y, b = blockIdx.z;
  const int kvh = h >> 2;               // N_REP = 4
  const int tid = threadIdx.x, w = tid >> 6, l = tid & 63, g = l >> 4, q = l & 15;
  const float SL2E = 0.08838834764831845f * 1.4426950408889634f;
  const u16* Qh = Qb + (size_t)b * S_ * NQ_ + h * HD_;
  const u16* Kh = Kb + ((size_t)b * S_ * KV_ + kvh) * HD_;
  const u16* Vh = VTg + (size_t)(b * KV_ + kvh) * (32 * 8192);
  u16* Oh = Ob + (size_t)b * S_ * NQ_ + h * HD_;

  bf16x8 aq[2][4];
  #pragma unroll
  for (int qb = 0; qb < 2; ++qb)
    #pragma unroll
    for (int kk = 0; kk < 4; ++kk)
      aq[qb][kk] = *(const bf16x8*)(Qh + (size_t)(qt * 128 + w * 32 + qb * 16 + q) * NQ_ + kk * 32 + g * 8);

  f32x4 o[2][8] = {};
  float mrow[2][4], lrow[2][4];
  #pragma unroll
  for (int qb = 0; qb < 2; ++qb)
    #pragma unroll
    for (int j = 0; j < 4; ++j) { mrow[qb][j] = -3.0e38f; lrow[qb][j] = 0.f; }

  const int nkt = 2 * qt + 2;
  for (int kt = 0; kt < nkt; ++kt) {
    __syncthreads();
    #pragma unroll
    for (int p = 0; p < 4; ++p) {   // K: [64][128]
      int c = tid + p * 256;
      int row = c >> 4, slot = c & 15;
      GLDS16(Kh + (size_t)(kt * 64 + row) * (KV_ * HD_) + ((slot ^ (row & 7)) << 3), Ks + c * 8);
    }
    #pragma unroll
    for (int p = 0; p < 4; ++p) {   // V^T: [128][64] from contiguous 16KB tile
      int c = tid + p * 256;
      int row = c >> 3, slot = c & 7;
      GLDS16(Vh + (size_t)kt * 8192 + row * 64 + ((slot ^ (row & 7)) << 3), VTs + c * 8);
    }
    __syncthreads();

    if (kt * 64 <= qt * 128 + w * 32 + 31) {   // wave-uniform activity gate
      // ---- QK^T ----
      f32x4 sc[2][4] = {};
      #pragma unroll
      for (int kk = 0; kk < 4; ++kk) {
        bf16x8 bk[4];
        #pragma unroll
        for (int n = 0; n < 4; ++n) {
          int row = n * 16 + q;
          bk[n] = *(const bf16x8*)(Ks + row * 128 + (((kk * 4 + g) ^ (row & 7)) << 3));
        }
        #pragma unroll
        for (int qb = 0; qb < 2; ++qb)
          #pragma unroll
          for (int n = 0; n < 4; ++n)
            sc[qb][n] = mfma16(aq[qb][kk], bk[n], sc[qb][n]);
      }
      // ---- causal mask (diagonal tiles only) ----
      if (kt * 64 + 63 > qt * 128 + w * 32) {
        #pragma unroll
        for (int qb = 0; qb < 2; ++qb)
          #pragma unroll
          for (int n = 0; n < 4; ++n)
            #pragma unroll
            for (int j = 0; j < 4; ++j) {
              int kglob = kt * 64 + n * 16 + q;
              int qglob = qt * 128 + w * 32 + qb * 16 + g * 4 + j;
              if (kglob > qglob) sc[qb][n][j] = -3.0e38f;
            }
      }
      // ---- online softmax ----
      float fct[2][4];
      #pragma unroll
      for (int qb = 0; qb < 2; ++qb)
        #pragma unroll
        for (int j = 0; j < 4; ++j) {
          float mx = fmaxf(fmaxf(sc[qb][0][j], sc[qb][1][j]),
                           fmaxf(sc[qb][2][j], sc[qb][3][j]));
          mx = fmaxf(mx, __shfl_xor(mx, 1));
          mx = fmaxf(mx, __shfl_xor(mx, 2));
          mx = fmaxf(mx, __shfl_xor(mx, 4));
          mx = fmaxf(mx, __shfl_xor(mx, 8));
          float mnew = fmaxf(mrow[qb][j], mx);
          float f = exp2f((mrow[qb][j] - mnew) * SL2E);
          float rs = 0.f;
          #pragma unroll
          for (int n = 0; n < 4; ++n) {
            float pv = exp2f((sc[qb][n][j] - mnew) * SL2E);
            sc[qb][n][j] = pv; rs += pv;
          }
          rs += __shfl_xor(rs, 1); rs += __shfl_xor(rs, 2);
          rs += __shfl_xor(rs, 4); rs += __shfl_xor(rs, 8);
          lrow[qb][j] = lrow[qb][j] * f + rs;
          mrow[qb][j] = mnew;
          fct[qb][j] = f;
        }
      if (q == 0) {
        #pragma unroll
        for (int qb = 0; qb < 2; ++qb)
          #pragma unroll
          for (int j = 0; j < 4; ++j)
            fstat[w][qb * 16 + g * 4 + j] = fct[qb][j];
      }
      // P -> LDS (swizzled [32][64], chunk ^= (r>>1)&7; truncating convert)
      #pragma unroll
      for (int qb = 0; qb < 2; ++qb)
        #pragma unroll
        for (int n = 0; n < 4; ++n)
          #pragma unroll
          for (int j = 0; j < 4; ++j) {
            int r = qb * 16 + g * 4 + j;
            Ps[w * 2048 + r * 64 + (((n * 2 + (q >> 3)) ^ ((r >> 1) & 7)) << 3) + (q & 7)]
                = f2bft(sc[qb][n][j]);
          }
      // rescale O
      #pragma unroll
      for (int qb = 0; qb < 2; ++qb) {
        float ff = fstat[w][qb * 16 + q];
        #pragma unroll
        for (int m = 0; m < 8; ++m) o[qb][m] *= ff;
      }
      // ---- PV: O^T = V^T * P^T ----
      #pragma unroll
      for (int kk2 = 0; kk2 < 2; ++kk2) {
        bf16x8 bp[2];
        #pragma unroll
        for (int qb = 0; qb < 2; ++qb) {
          int row = qb * 16 + q;
          bp[qb] = *(const bf16x8*)(Ps + w * 2048 + row * 64 + (((kk2 * 4 + g) ^ ((row >> 1) & 7)) << 3));
        }
        #pragma unroll
        for (int m = 0; m < 8; ++m) {
          int row = m * 16 + q;
          bf16x8 av = *(const bf16x8*)(VTs + row * 64 + (((kk2 * 4 + g) ^ (row & 7)) << 3));
          #pragma unroll
          for (int qb = 0; qb < 2; ++qb)
            o[qb][m] = mfma16(av, bp[qb], o[qb][m]);
        }
      }
    }
  }
  // ---- epilogue: normalize, transpose via LDS, coalesced store ----
  __syncthreads();
  if (q == 0) {
    #pragma unroll
    for (int qb = 0; qb < 2; ++qb)
      #pragma unroll
      for (int j = 0; j < 4; ++j)
        lstat[w][qb * 16 + g * 4 + j] = lrow[qb][j];
  }
  __syncthreads();
  u16* OS = SM; // [128][136]
  #pragma unroll
  for (int qb = 0; qb < 2; ++qb) {
    float linv = 1.0f / lstat[w][qb * 16 + q];
    #pragma unroll
    for (int m = 0; m < 8; ++m)
      #pragma unroll
      for (int j = 0; j < 4; ++j)
        OS[(w * 32 + qb * 16 + q) * 136 + m * 16 + g * 4 + j] = f2bf(o[qb][m][j] * linv);
  }
  __syncthreads();
  #pragma unroll
  for (int p = 0; p < 8; ++p) {
    int c = tid + p * 256;
    int row = c >> 4, col8 = c & 15;
    u16x8 d = *(const u16x8*)(OS + row * 136 + col8 * 8);
    *(u16x8*)(Oh + (size_t)(qt * 128 + row) * NQ_ + col8 * 8) = d;
  }
}

extern "C" void kernel_launch(void* const* d_in, const int* in_sizes, int n_in,
                              void* d_out, int out_size, void* d_ws, size_t ws_size,
                              hipStream_t stream) {
  const float* x  = (const float*)d_in[0];
  const float* fc = (const float*)d_in[1];
  const float* fs = (const float*)d_in[2];
  // d_in[3] = mask (causal, applied analytically)
  const float* wq = (const float*)d_in[4];
  const float* wk = (const float*)d_in[5];
  const float* wv = (const float*)d_in[6];
  const float* wo = (const float*)d_in[7];

  char* ws = (char*)d_ws;
  u16* xb  = (u16*)(ws + 0);          // 33554432 B
  u16* wqT = (u16*)(ws + 33554432);   // 33554432
  u16* wkT = (u16*)(ws + 67108864);   // 8388608
  u16* wvT = (u16*)(ws + 75497472);   // 8388608
  u16* woT = (u16*)(ws + 83886080);   // 33554432
  u16* qb  = (u16*)(ws + 117440512);  // 33554432
  u16* kb  = (u16*)(ws + 150994944);  // 8388608
  u16* vtg = (u16*)(ws + 159383552);  // 8388608  (V^T tiled: [B][KV][32][128][64])
  u16* ob  = (u16*)(ws + 167772160);  // 33554432  -> total 201326592
  if (ws_size < 201326592u) return;

  cvt_bf16<<<(M_ * D_) / (8 * 256), 256, 0, stream>>>(x, xb, M_ * D_);
  tcvt<<<dim3(NQ_ / 32, D_ / 32), 256, 0, stream>>>(wq, wqT, D_, NQ_);
  tcvt<<<dim3(NKV_ / 32, D_ / 32), 256, 0, stream>>>(wk, wkT, D_, NKV_);
  tcvt<<<dim3(NKV_ / 32, D_ / 32), 256, 0, stream>>>(wv, wvT, D_, NKV_);
  tcvt<<<dim3(D_ / 32, NQ_ / 32), 256, 0, stream>>>(wo, woT, NQ_, D_);

  gemm_bt<0><<<dim3(NQ_ / 128, M_ / 128), 256, 0, stream>>>(xb, wqT, qb, M_, NQ_, D_);
  gemm_bt<0><<<dim3(NKV_ / 128, M_ / 128), 256, 0, stream>>>(xb, wkT, kb, M_, NKV_, D_);
  gemm_bt<2><<<dim3(NKV_ / 128, M_ / 128), 256, 0, stream>>>(xb, wvT, vtg, M_, NKV_, D_);

  rope_kernel<<<(M_ * NQ_ / 2) / 256, 256, 0, stream>>>(qb, fc, fs, 11, M_ * NQ_ / 2);
  rope_kernel<<<(M_ * NKV_ / 2) / 256, 256, 0, stream>>>(kb, fc, fs, 9, M_ * NKV_ / 2);

  attn_kernel<<<dim3(16, H_, B_), 256, 0, stream>>>(qb, kb, vtg, ob);

  gemm_bt<1><<<dim3(D_ / 128, M_ / 128), 256, 0, stream>>>(ob, woT, d_out, M_, D_, NQ_);
}

// Round 4
// 960.694 us; speedup vs baseline: 1.3880x; 1.3880x over previous
//
#include <hip/hip_runtime.h>
#include <stdint.h>

#define B_ 2
#define S_ 2048
#define D_ 4096
#define H_ 32
#define KV_ 8
#define HD_ 128
#define M_ (B_*S_)          // 4096 rows (b*S+s)
#define NQ_ (H_*HD_)        // 4096
#define NKV_ (KV_*HD_)      // 1024

typedef unsigned short u16;
typedef __bf16 bf16x8 __attribute__((ext_vector_type(8)));
typedef float f32x4 __attribute__((ext_vector_type(4)));
typedef u16 u16x8 __attribute__((ext_vector_type(8)));
typedef u16 u16x4 __attribute__((ext_vector_type(4)));

__device__ __forceinline__ u16 f2bf(float f) {
  union { float f; unsigned u; } v; v.f = f;
  unsigned r = v.u + 0x7fffu + ((v.u >> 16) & 1u);
  return (u16)(r >> 16);
}
__device__ __forceinline__ u16 f2bft(float f) {  // truncating (for P; values in [0,1])
  union { float f; unsigned u; } v; v.f = f;
  return (u16)(v.u >> 16);
}
__device__ __forceinline__ float bf2f(u16 u) {
  union { unsigned u; float f; } v; v.u = ((unsigned)u) << 16;
  return v.f;
}
__device__ __forceinline__ f32x4 mfma16(bf16x8 a, bf16x8 b, f32x4 c) {
  return __builtin_amdgcn_mfma_f32_16x16x32_bf16(a, b, c, 0, 0, 0);
}

#define GLDS16(gp, lp) __builtin_amdgcn_global_load_lds( \
    (const __attribute__((address_space(1))) unsigned int*)(gp), \
    (__attribute__((address_space(3))) unsigned int*)(lp), 16, 0, 0)

// ---------------- fp32 -> bf16 convert (vectorized) ----------------
__global__ __launch_bounds__(256) void cvt_bf16(const float* __restrict__ in,
                                                u16* __restrict__ out, int n) {
  int i = (blockIdx.x * 256 + threadIdx.x) * 8;
  if (i >= n) return;
  float4 a = *(const float4*)(in + i);
  float4 b = *(const float4*)(in + i + 4);
  u16x8 o;
  o[0]=f2bf(a.x); o[1]=f2bf(a.y); o[2]=f2bf(a.z); o[3]=f2bf(a.w);
  o[4]=f2bf(b.x); o[5]=f2bf(b.y); o[6]=f2bf(b.z); o[7]=f2bf(b.w);
  *(u16x8*)(out + i) = o;
}

// ---------------- transpose + convert: out[c][r] = in[r][c] ----------------
__global__ __launch_bounds__(256) void tcvt(const float* __restrict__ in,
                                            u16* __restrict__ out, int R, int C) {
  __shared__ __attribute__((aligned(16))) u16 tile[32][33];
  int c0 = blockIdx.x * 32, r0 = blockIdx.y * 32;
  int tx = threadIdx.x & 31, ty = threadIdx.x >> 5;
  #pragma unroll
  for (int j = ty; j < 32; j += 8)
    tile[j][tx] = f2bf(in[(size_t)(r0 + j) * C + c0 + tx]);
  __syncthreads();
  #pragma unroll
  for (int j = ty; j < 32; j += 8)
    out[(size_t)(c0 + j) * R + r0 + tx] = tile[tx][j];
}

// ---------------- GEMM: C = A[M,K] * BT[N,K]^T ----------------
// OUTMODE: 0 = bf16 row-major C[M][N]; 1 = f32 row-major;
//          2 = bf16 V^T tiled: out[((b*KV+kv)*32 + t)*8192 + d*64 + s6]
//              where row=b*2048+t*64+s6 (s), col=kv*128+d. 16KB contiguous tiles.
template<int OUTMODE>
__global__ __launch_bounds__(256) void gemm_bt(const u16* __restrict__ A,
    const u16* __restrict__ BT, void* __restrict__ Cv, int M, int N, int K) {
  __shared__ __attribute__((aligned(16))) u16 As[128 * 32];
  __shared__ __attribute__((aligned(16))) u16 Bs[128 * 32];
  const int tid = threadIdx.x;
  const int bn0 = blockIdx.x * 128, bm0 = blockIdx.y * 128;
  const int w = tid >> 6, l = tid & 63, g = l >> 4, q = l & 15;
  const int wm = (w >> 1) * 64, wn = (w & 1) * 64;
  f32x4 acc[4][4] = {};
  for (int kt = 0; kt < K; kt += 32) {
    __syncthreads();
    #pragma unroll
    for (int p = 0; p < 2; ++p) {
      int c = tid + p * 256;
      int row = c >> 2, slot = c & 3;
      int srck = (slot ^ ((row >> 1) & 3)) << 3;
      GLDS16(A + (size_t)(bm0 + row) * K + kt + srck, As + c * 8);
      GLDS16(BT + (size_t)(bn0 + row) * K + kt + srck, Bs + c * 8);
    }
    __syncthreads();
    bf16x8 af[4], bfr[4];
    #pragma unroll
    for (int m = 0; m < 4; ++m) {
      int row = wm + m * 16 + q;
      af[m] = *(const bf16x8*)(As + row * 32 + ((g ^ ((row >> 1) & 3)) << 3));
    }
    #pragma unroll
    for (int n = 0; n < 4; ++n) {
      int row = wn + n * 16 + q;
      bfr[n] = *(const bf16x8*)(Bs + row * 32 + ((g ^ ((row >> 1) & 3)) << 3));
    }
    #pragma unroll
    for (int m = 0; m < 4; ++m)
      #pragma unroll
      for (int n = 0; n < 4; ++n)
        acc[m][n] = mfma16(af[m], bfr[n], acc[m][n]);
  }
  #pragma unroll
  for (int m = 0; m < 4; ++m)
    #pragma unroll
    for (int n = 0; n < 4; ++n) {
      if (OUTMODE == 2) {
        int row0 = bm0 + wm + m * 16 + g * 4;      // s index (global over b*S)
        int col  = bn0 + wn + n * 16 + q;          // kv*128 + d
        u16x4 pk;
        #pragma unroll
        for (int j = 0; j < 4; ++j) pk[j] = f2bf(acc[m][n][j]);
        size_t off = ((size_t)((row0 >> 11) * KV_ + (col >> 7)) * 32 + ((row0 >> 6) & 31)) * 8192
                   + (size_t)(col & 127) * 64 + (row0 & 63);
        *(u16x4*)((u16*)Cv + off) = pk;
      } else {
        #pragma unroll
        for (int j = 0; j < 4; ++j) {
          size_t off = (size_t)(bm0 + wm + m * 16 + g * 4 + j) * N + (bn0 + wn + n * 16 + q);
          if (OUTMODE == 1) ((float*)Cv)[off] = acc[m][n][j];
          else              ((u16*)Cv)[off]  = f2bf(acc[m][n][j]);
        }
      }
    }
}

// ---------------- RoPE (interleaved pairs, in-place on bf16) ----------------
__global__ __launch_bounds__(256) void rope_kernel(u16* __restrict__ t,
    const float* __restrict__ fc, const float* __restrict__ fs,
    int log2ppr, int total_pairs) {
  int i = blockIdx.x * 256 + threadIdx.x;
  if (i >= total_pairs) return;
  int fi = i & 63;
  int row = i >> log2ppr;           // b*S + s
  int pos = row & (S_ - 1);
  float c = fc[pos * 64 + fi], s = fs[pos * 64 + fi];
  unsigned* p = (unsigned*)(t + 2 * (size_t)i);
  unsigned v = *p;
  float x0 = bf2f((u16)(v & 0xffffu)), x1 = bf2f((u16)(v >> 16));
  float r0 = x0 * c - x1 * s, r1 = x0 * s + x1 * c;
  *p = (unsigned)f2bf(r0) | ((unsigned)f2bf(r1) << 16);
}

// ---------------- causal GQA flash attention ----------------
// grid (16, H, B), qt = 15-bx (long tiles first); block 256 = 4 waves,
// QT=128 (32 q-rows/wave), KT=64. K LDS [64][128] swz(row&7);
// V^T LDS [128][64] swz(row&7) staged from CONTIGUOUS 16KB global tiles;
// P LDS per-wave [32][64] swz((r>>1)&7).
// launch_bounds (256,2): 84-VGPR cap at (256,3) spilled ~300MB/dispatch to
// scratch (R2/R3 regression) — o[2][8]+aq[2][4] need ~96 regs live.
__global__ __launch_bounds__(256, 2) void attn_kernel(
    const u16* __restrict__ Qb, const u16* __restrict__ Kb,
    const u16* __restrict__ VTg, u16* __restrict__ Ob) {
  __shared__ __attribute__((aligned(16))) u16 SM[24576]; // 48KB
  __shared__ float fstat[4][32];
  __shared__ float lstat[4][32];
  u16* Ks  = SM;           // [64][128] swz
  u16* VTs = SM + 8192;    // [128][64] swz
  u16* Ps  = SM + 16384;   // 4 x [32][64] swz
  const int qt = 15 - (int)blockIdx.x;
  const int h = blockIdx.y, b = blockIdx.z;
  const int kvh = h >> 2;               // N_REP = 4
  const int tid = threadIdx.x, w = tid >> 6, l = tid & 63, g = l >> 4, q = l & 15;
  const float SL2E = 0.08838834764831845f * 1.4426950408889634f;
  const u16* Qh = Qb + (size_t)b * S_ * NQ_ + h * HD_;
  const u16* Kh = Kb + ((size_t)b * S_ * KV_ + kvh) * HD_;
  const u16* Vh = VTg + (size_t)(b * KV_ + kvh) * (32 * 8192);
  u16* Oh = Ob + (size_t)b * S_ * NQ_ + h * HD_;

  bf16x8 aq[2][4];
  #pragma unroll
  for (int qb = 0; qb < 2; ++qb)
    #pragma unroll
    for (int kk = 0; kk < 4; ++kk)
      aq[qb][kk] = *(const bf16x8*)(Qh + (size_t)(qt * 128 + w * 32 + qb * 16 + q) * NQ_ + kk * 32 + g * 8);

  f32x4 o[2][8] = {};
  float mrow[2][4], lrow[2][4];
  #pragma unroll
  for (int qb = 0; qb < 2; ++qb)
    #pragma unroll
    for (int j = 0; j < 4; ++j) { mrow[qb][j] = -3.0e38f; lrow[qb][j] = 0.f; }

  const int nkt = 2 * qt + 2;
  for (int kt = 0; kt < nkt; ++kt) {
    __syncthreads();
    #pragma unroll
    for (int p = 0; p < 4; ++p) {   // K: [64][128]
      int c = tid + p * 256;
      int row = c >> 4, slot = c & 15;
      GLDS16(Kh + (size_t)(kt * 64 + row) * (KV_ * HD_) + ((slot ^ (row & 7)) << 3), Ks + c * 8);
    }
    #pragma unroll
    for (int p = 0; p < 4; ++p) {   // V^T: [128][64] from contiguous 16KB tile
      int c = tid + p * 256;
      int row = c >> 3, slot = c & 7;
      GLDS16(Vh + (size_t)kt * 8192 + row * 64 + ((slot ^ (row & 7)) << 3), VTs + c * 8);
    }
    __syncthreads();

    if (kt * 64 <= qt * 128 + w * 32 + 31) {   // wave-uniform activity gate
      // ---- QK^T ----
      f32x4 sc[2][4] = {};
      #pragma unroll
      for (int kk = 0; kk < 4; ++kk) {
        bf16x8 bk[4];
        #pragma unroll
        for (int n = 0; n < 4; ++n) {
          int row = n * 16 + q;
          bk[n] = *(const bf16x8*)(Ks + row * 128 + (((kk * 4 + g) ^ (row & 7)) << 3));
        }
        #pragma unroll
        for (int qb = 0; qb < 2; ++qb)
          #pragma unroll
          for (int n = 0; n < 4; ++n)
            sc[qb][n] = mfma16(aq[qb][kk], bk[n], sc[qb][n]);
      }
      // ---- causal mask (diagonal tiles only) ----
      if (kt * 64 + 63 > qt * 128 + w * 32) {
        #pragma unroll
        for (int qb = 0; qb < 2; ++qb)
          #pragma unroll
          for (int n = 0; n < 4; ++n)
            #pragma unroll
            for (int j = 0; j < 4; ++j) {
              int kglob = kt * 64 + n * 16 + q;
              int qglob = qt * 128 + w * 32 + qb * 16 + g * 4 + j;
              if (kglob > qglob) sc[qb][n][j] = -3.0e38f;
            }
      }
      // ---- online softmax ----
      float fct[2][4];
      #pragma unroll
      for (int qb = 0; qb < 2; ++qb)
        #pragma unroll
        for (int j = 0; j < 4; ++j) {
          float mx = fmaxf(fmaxf(sc[qb][0][j], sc[qb][1][j]),
                           fmaxf(sc[qb][2][j], sc[qb][3][j]));
          mx = fmaxf(mx, __shfl_xor(mx, 1));
          mx = fmaxf(mx, __shfl_xor(mx, 2));
          mx = fmaxf(mx, __shfl_xor(mx, 4));
          mx = fmaxf(mx, __shfl_xor(mx, 8));
          float mnew = fmaxf(mrow[qb][j], mx);
          float f = exp2f((mrow[qb][j] - mnew) * SL2E);
          float rs = 0.f;
          #pragma unroll
          for (int n = 0; n < 4; ++n) {
            float pv = exp2f((sc[qb][n][j] - mnew) * SL2E);
            sc[qb][n][j] = pv; rs += pv;
          }
          rs += __shfl_xor(rs, 1); rs += __shfl_xor(rs, 2);
          rs += __shfl_xor(rs, 4); rs += __shfl_xor(rs, 8);
          lrow[qb][j] = lrow[qb][j] * f + rs;
          mrow[qb][j] = mnew;
          fct[qb][j] = f;
        }
      if (q == 0) {
        #pragma unroll
        for (int qb = 0; qb < 2; ++qb)
          #pragma unroll
          for (int j = 0; j < 4; ++j)
            fstat[w][qb * 16 + g * 4 + j] = fct[qb][j];
      }
      // P -> LDS (swizzled [32][64], chunk ^= (r>>1)&7; truncating convert)
      #pragma unroll
      for (int qb = 0; qb < 2; ++qb)
        #pragma unroll
        for (int n = 0; n < 4; ++n)
          #pragma unroll
          for (int j = 0; j < 4; ++j) {
            int r = qb * 16 + g * 4 + j;
            Ps[w * 2048 + r * 64 + (((n * 2 + (q >> 3)) ^ ((r >> 1) & 7)) << 3) + (q & 7)]
                = f2bft(sc[qb][n][j]);
          }
      // rescale O
      #pragma unroll
      for (int qb = 0; qb < 2; ++qb) {
        float ff = fstat[w][qb * 16 + q];
        #pragma unroll
        for (int m = 0; m < 8; ++m) o[qb][m] *= ff;
      }
      // ---- PV: O^T = V^T * P^T ----
      #pragma unroll
      for (int kk2 = 0; kk2 < 2; ++kk2) {
        bf16x8 bp[2];
        #pragma unroll
        for (int qb = 0; qb < 2; ++qb) {
          int row = qb * 16 + q;
          bp[qb] = *(const bf16x8*)(Ps + w * 2048 + row * 64 + (((kk2 * 4 + g) ^ ((row >> 1) & 7)) << 3));
        }
        #pragma unroll
        for (int m = 0; m < 8; ++m) {
          int row = m * 16 + q;
          bf16x8 av = *(const bf16x8*)(VTs + row * 64 + (((kk2 * 4 + g) ^ (row & 7)) << 3));
          #pragma unroll
          for (int qb = 0; qb < 2; ++qb)
            o[qb][m] = mfma16(av, bp[qb], o[qb][m]);
        }
      }
    }
  }
  // ---- epilogue: normalize, transpose via LDS, coalesced store ----
  __syncthreads();
  if (q == 0) {
    #pragma unroll
    for (int qb = 0; qb < 2; ++qb)
      #pragma unroll
      for (int j = 0; j < 4; ++j)
        lstat[w][qb * 16 + g * 4 + j] = lrow[qb][j];
  }
  __syncthreads();
  u16* OS = SM; // [128][136]
  #pragma unroll
  for (int qb = 0; qb < 2; ++qb) {
    float linv = 1.0f / lstat[w][qb * 16 + q];
    #pragma unroll
    for (int m = 0; m < 8; ++m)
      #pragma unroll
      for (int j = 0; j < 4; ++j)
        OS[(w * 32 + qb * 16 + q) * 136 + m * 16 + g * 4 + j] = f2bf(o[qb][m][j] * linv);
  }
  __syncthreads();
  #pragma unroll
  for (int p = 0; p < 8; ++p) {
    int c = tid + p * 256;
    int row = c >> 4, col8 = c & 15;
    u16x8 d = *(const u16x8*)(OS + row * 136 + col8 * 8);
    *(u16x8*)(Oh + (size_t)(qt * 128 + row) * NQ_ + col8 * 8) = d;
  }
}

extern "C" void kernel_launch(void* const* d_in, const int* in_sizes, int n_in,
                              void* d_out, int out_size, void* d_ws, size_t ws_size,
                              hipStream_t stream) {
  const float* x  = (const float*)d_in[0];
  const float* fc = (const float*)d_in[1];
  const float* fs = (const float*)d_in[2];
  // d_in[3] = mask (causal, applied analytically)
  const float* wq = (const float*)d_in[4];
  const float* wk = (const float*)d_in[5];
  const float* wv = (const float*)d_in[6];
  const float* wo = (const float*)d_in[7];

  char* ws = (char*)d_ws;
  u16* xb  = (u16*)(ws + 0);          // 33554432 B
  u16* wqT = (u16*)(ws + 33554432);   // 33554432
  u16* wkT = (u16*)(ws + 67108864);   // 8388608
  u16* wvT = (u16*)(ws + 75497472);   // 8388608
  u16* woT = (u16*)(ws + 83886080);   // 33554432
  u16* qb  = (u16*)(ws + 117440512);  // 33554432
  u16* kb  = (u16*)(ws + 150994944);  // 8388608
  u16* vtg = (u16*)(ws + 159383552);  // 8388608  (V^T tiled: [B][KV][32][128][64])
  u16* ob  = (u16*)(ws + 167772160);  // 33554432  -> total 201326592
  if (ws_size < 201326592u) return;

  cvt_bf16<<<(M_ * D_) / (8 * 256), 256, 0, stream>>>(x, xb, M_ * D_);
  tcvt<<<dim3(NQ_ / 32, D_ / 32), 256, 0, stream>>>(wq, wqT, D_, NQ_);
  tcvt<<<dim3(NKV_ / 32, D_ / 32), 256, 0, stream>>>(wk, wkT, D_, NKV_);
  tcvt<<<dim3(NKV_ / 32, D_ / 32), 256, 0, stream>>>(wv, wvT, D_, NKV_);
  tcvt<<<dim3(D_ / 32, NQ_ / 32), 256, 0, stream>>>(wo, woT, NQ_, D_);

  gemm_bt<0><<<dim3(NQ_ / 128, M_ / 128), 256, 0, stream>>>(xb, wqT, qb, M_, NQ_, D_);
  gemm_bt<0><<<dim3(NKV_ / 128, M_ / 128), 256, 0, stream>>>(xb, wkT, kb, M_, NKV_, D_);
  gemm_bt<2><<<dim3(NKV_ / 128, M_ / 128), 256, 0, stream>>>(xb, wvT, vtg, M_, NKV_, D_);

  rope_kernel<<<(M_ * NQ_ / 2) / 256, 256, 0, stream>>>(qb, fc, fs, 11, M_ * NQ_ / 2);
  rope_kernel<<<(M_ * NKV_ / 2) / 256, 256, 0, stream>>>(kb, fc, fs, 9, M_ * NKV_ / 2);

  attn_kernel<<<dim3(16, H_, B_), 256, 0, stream>>>(qb, kb, vtg, ob);

  gemm_bt<1><<<dim3(D_ / 128, M_ / 128), 256, 0, stream>>>(ob, woT, d_out, M_, D_, NQ_);
}

// Round 5
// 715.241 us; speedup vs baseline: 1.8644x; 1.3432x over previous
//
#include <hip/hip_runtime.h>
#include <stdint.h>

#define B_ 2
#define S_ 2048
#define D_ 4096
#define H_ 32
#define KV_ 8
#define HD_ 128
#define M_ (B_*S_)          // 4096 rows (b*S+s)
#define NQ_ (H_*HD_)        // 4096
#define NKV_ (KV_*HD_)      // 1024

typedef unsigned short u16;
typedef __bf16 bf16x8 __attribute__((ext_vector_type(8)));
typedef float f32x4 __attribute__((ext_vector_type(4)));
typedef u16 u16x8 __attribute__((ext_vector_type(8)));
typedef u16 u16x4 __attribute__((ext_vector_type(4)));

__device__ __forceinline__ u16 f2bf(float f) {
  union { float f; unsigned u; } v; v.f = f;
  unsigned r = v.u + 0x7fffu + ((v.u >> 16) & 1u);
  return (u16)(r >> 16);
}
__device__ __forceinline__ u16 f2bft(float f) {  // truncating (for P; values in [0,1])
  union { float f; unsigned u; } v; v.f = f;
  return (u16)(v.u >> 16);
}
__device__ __forceinline__ float bf2f(u16 u) {
  union { unsigned u; float f; } v; v.u = ((unsigned)u) << 16;
  return v.f;
}
__device__ __forceinline__ f32x4 mfma16(bf16x8 a, bf16x8 b, f32x4 c) {
  return __builtin_amdgcn_mfma_f32_16x16x32_bf16(a, b, c, 0, 0, 0);
}

#define GLDS16(gp, lp) __builtin_amdgcn_global_load_lds( \
    (const __attribute__((address_space(1))) unsigned int*)(gp), \
    (__attribute__((address_space(3))) unsigned int*)(lp), 16, 0, 0)

// ---------------- fp32 -> bf16 convert (vectorized) ----------------
__global__ __launch_bounds__(256) void cvt_bf16(const float* __restrict__ in,
                                                u16* __restrict__ out, int n) {
  int i = (blockIdx.x * 256 + threadIdx.x) * 8;
  if (i >= n) return;
  float4 a = *(const float4*)(in + i);
  float4 b = *(const float4*)(in + i + 4);
  u16x8 o;
  o[0]=f2bf(a.x); o[1]=f2bf(a.y); o[2]=f2bf(a.z); o[3]=f2bf(a.w);
  o[4]=f2bf(b.x); o[5]=f2bf(b.y); o[6]=f2bf(b.z); o[7]=f2bf(b.w);
  *(u16x8*)(out + i) = o;
}

// ---------------- transpose + convert: out[c][r] = in[r][c] ----------------
__global__ __launch_bounds__(256) void tcvt(const float* __restrict__ in,
                                            u16* __restrict__ out, int R, int C) {
  __shared__ __attribute__((aligned(16))) u16 tile[32][33];
  int c0 = blockIdx.x * 32, r0 = blockIdx.y * 32;
  int tx = threadIdx.x & 31, ty = threadIdx.x >> 5;
  #pragma unroll
  for (int j = ty; j < 32; j += 8)
    tile[j][tx] = f2bf(in[(size_t)(r0 + j) * C + c0 + tx]);
  __syncthreads();
  #pragma unroll
  for (int j = ty; j < 32; j += 8)
    out[(size_t)(c0 + j) * R + r0 + tx] = tile[tx][j];
}

// ---------------- 128x128 GEMM (m97-style), kept for K/V proj ----------------
// OUTMODE: 0 = bf16 row-major; 2 = bf16 V^T tiled [B][KV][32][128][64]
template<int OUTMODE>
__global__ __launch_bounds__(256) void gemm_bt(const u16* __restrict__ A,
    const u16* __restrict__ BT, void* __restrict__ Cv, int M, int N, int K) {
  __shared__ __attribute__((aligned(16))) u16 As[128 * 32];
  __shared__ __attribute__((aligned(16))) u16 Bs[128 * 32];
  const int tid = threadIdx.x;
  const int bn0 = blockIdx.x * 128, bm0 = blockIdx.y * 128;
  const int w = tid >> 6, l = tid & 63, g = l >> 4, q = l & 15;
  const int wm = (w >> 1) * 64, wn = (w & 1) * 64;
  f32x4 acc[4][4] = {};
  for (int kt = 0; kt < K; kt += 32) {
    __syncthreads();
    #pragma unroll
    for (int p = 0; p < 2; ++p) {
      int c = tid + p * 256;
      int row = c >> 2, slot = c & 3;
      int srck = (slot ^ ((row >> 1) & 3)) << 3;
      GLDS16(A + (size_t)(bm0 + row) * K + kt + srck, As + c * 8);
      GLDS16(BT + (size_t)(bn0 + row) * K + kt + srck, Bs + c * 8);
    }
    __syncthreads();
    bf16x8 af[4], bfr[4];
    #pragma unroll
    for (int m = 0; m < 4; ++m) {
      int row = wm + m * 16 + q;
      af[m] = *(const bf16x8*)(As + row * 32 + ((g ^ ((row >> 1) & 3)) << 3));
    }
    #pragma unroll
    for (int n = 0; n < 4; ++n) {
      int row = wn + n * 16 + q;
      bfr[n] = *(const bf16x8*)(Bs + row * 32 + ((g ^ ((row >> 1) & 3)) << 3));
    }
    #pragma unroll
    for (int m = 0; m < 4; ++m)
      #pragma unroll
      for (int n = 0; n < 4; ++n)
        acc[m][n] = mfma16(af[m], bfr[n], acc[m][n]);
  }
  #pragma unroll
  for (int m = 0; m < 4; ++m)
    #pragma unroll
    for (int n = 0; n < 4; ++n) {
      if (OUTMODE == 2) {
        int row0 = bm0 + wm + m * 16 + g * 4;      // s index (global over b*S)
        int col  = bn0 + wn + n * 16 + q;          // kv*128 + d
        u16x4 pk;
        #pragma unroll
        for (int j = 0; j < 4; ++j) pk[j] = f2bf(acc[m][n][j]);
        size_t off = ((size_t)((row0 >> 11) * KV_ + (col >> 7)) * 32 + ((row0 >> 6) & 31)) * 8192
                   + (size_t)(col & 127) * 64 + (row0 & 63);
        *(u16x4*)((u16*)Cv + off) = pk;
      } else {
        #pragma unroll
        for (int j = 0; j < 4; ++j) {
          size_t off = (size_t)(bm0 + wm + m * 16 + g * 4 + j) * N + (bn0 + wn + n * 16 + q);
          ((u16*)Cv)[off] = f2bf(acc[m][n][j]);
        }
      }
    }
}

// ---------------- 256x256 dbuf GEMM, counted vmcnt (T3+T4+T5) ----------------
// 512 thr = 8 waves (2M x 4N), per-wave 128x64 out = 8x4 16x16 frags, BK=64.
// LDS: dynamic 128 KiB = 2 bufs x (A[256][64] + B[256][64]) u16, 16B-slot
// swizzle slot^=(row&7) (both-sides: pre-swizzled gload_lds source + swz read).
// Schedule per K-tile: 4 quadrant phases {ds_read subtile; 16 MFMA w/ setprio},
// then lgkm(0)+barrier; STAGE(t+2 -> this buf); vmcnt(8) (tile t+1 landed,
// t+2's 8 loads stay in flight -- never drains); barrier.
// OUTMODE: 0 = bf16 row-major, 1 = f32 row-major.
template<int OUTMODE>
__global__ __launch_bounds__(512, 2) void gemm256(const u16* __restrict__ A,
    const u16* __restrict__ BT, void* __restrict__ Cv, int M, int N, int K) {
  extern __shared__ __attribute__((aligned(16))) u16 DL[];  // [2][2][16384]
  const int tid = threadIdx.x;
  const int bn0 = blockIdx.x * 256, bm0 = blockIdx.y * 256;
  const int l = tid & 63, g = l >> 4, q = l & 15;
  const int w = tid >> 6;
  const int wm = (w >> 2) * 128, wn = (w & 3) * 64;
  const int nt = K >> 6;
  f32x4 acc[8][4] = {};

  auto STAGE = [&](int t, int buf) {
    const int kt = t << 6;
    u16* Ad = DL + buf * 32768;
    u16* Bd = Ad + 16384;
    #pragma unroll
    for (int p = 0; p < 4; ++p) {
      int idx = tid + p * 512;
      int row = idx >> 3, slot = idx & 7;
      int sk = (slot ^ (row & 7)) << 3;
      GLDS16(A + (size_t)(bm0 + row) * K + kt + sk, Ad + idx * 8);
    }
    #pragma unroll
    for (int p = 0; p < 4; ++p) {
      int idx = tid + p * 512;
      int row = idx >> 3, slot = idx & 7;
      int sk = (slot ^ (row & 7)) << 3;
      GLDS16(BT + (size_t)(bn0 + row) * K + kt + sk, Bd + idx * 8);
    }
  };

  STAGE(0, 0);
  STAGE(1, 1);
  asm volatile("s_waitcnt vmcnt(8)" ::: "memory");   // tile0 landed; tile1 in flight
  __builtin_amdgcn_s_barrier();

  for (int t = 0; t < nt; ++t) {
    const int buf = t & 1;
    const u16* As = DL + buf * 32768;
    const u16* Bs = As + 16384;
    #pragma unroll
    for (int ks = 0; ks < 2; ++ks) {
      bf16x8 a[8], bb[2];
      #pragma unroll
      for (int m = 0; m < 8; ++m) {
        int row = wm + m * 16 + q;
        a[m] = *(const bf16x8*)(As + row * 64 + (((ks * 4 + g) ^ (row & 7)) << 3));
      }
      #pragma unroll
      for (int n = 0; n < 2; ++n) {
        int row = wn + n * 16 + q;
        bb[n] = *(const bf16x8*)(Bs + row * 64 + (((ks * 4 + g) ^ (row & 7)) << 3));
      }
      __builtin_amdgcn_s_setprio(1);
      #pragma unroll
      for (int m = 0; m < 8; ++m)
        #pragma unroll
        for (int n = 0; n < 2; ++n)
          acc[m][n] = mfma16(a[m], bb[n], acc[m][n]);
      __builtin_amdgcn_s_setprio(0);
      #pragma unroll
      for (int n = 0; n < 2; ++n) {
        int row = wn + (n + 2) * 16 + q;
        bb[n] = *(const bf16x8*)(Bs + row * 64 + (((ks * 4 + g) ^ (row & 7)) << 3));
      }
      __builtin_amdgcn_s_setprio(1);
      #pragma unroll
      for (int m = 0; m < 8; ++m)
        #pragma unroll
        for (int n = 0; n < 2; ++n)
          acc[m][n + 2] = mfma16(a[m], bb[n], acc[m][n + 2]);
      __builtin_amdgcn_s_setprio(0);
    }
    if (t + 1 < nt) {
      asm volatile("s_waitcnt lgkmcnt(0)" ::: "memory");
      __builtin_amdgcn_s_barrier();            // all waves done reading buf
      if (t + 2 < nt) {
        STAGE(t + 2, buf);
        asm volatile("s_waitcnt vmcnt(8)" ::: "memory");  // tile t+1 complete
      } else {
        asm volatile("s_waitcnt vmcnt(0)" ::: "memory");
      }
      __builtin_amdgcn_s_barrier();            // buf^1 (tile t+1) ready for all
    }
  }

  #pragma unroll
  for (int m = 0; m < 8; ++m)
    #pragma unroll
    for (int n = 0; n < 4; ++n)
      #pragma unroll
      for (int j = 0; j < 4; ++j) {
        size_t off = (size_t)(bm0 + wm + m * 16 + g * 4 + j) * N + (bn0 + wn + n * 16 + q);
        if (OUTMODE == 1) ((float*)Cv)[off] = acc[m][n][j];
        else              ((u16*)Cv)[off]  = f2bf(acc[m][n][j]);
      }
}

// ---------------- RoPE (interleaved pairs, in-place on bf16) ----------------
__global__ __launch_bounds__(256) void rope_kernel(u16* __restrict__ t,
    const float* __restrict__ fc, const float* __restrict__ fs,
    int log2ppr, int total_pairs) {
  int i = blockIdx.x * 256 + threadIdx.x;
  if (i >= total_pairs) return;
  int fi = i & 63;
  int row = i >> log2ppr;           // b*S + s
  int pos = row & (S_ - 1);
  float c = fc[pos * 64 + fi], s = fs[pos * 64 + fi];
  unsigned* p = (unsigned*)(t + 2 * (size_t)i);
  unsigned v = *p;
  float x0 = bf2f((u16)(v & 0xffffu)), x1 = bf2f((u16)(v >> 16));
  float r0 = x0 * c - x1 * s, r1 = x0 * s + x1 * c;
  *p = (unsigned)f2bf(r0) | ((unsigned)f2bf(r1) << 16);
}

// ---------------- causal GQA flash attention ----------------
// grid (8, H, B); block 256 = 4 waves. q-tile pairing: block p does
// qt=15-p then qt=p -> uniform 34 K-iters/block; 512 blocks = exactly 2/CU,
// all resident, no tail (R4 was 11% occupancy from 16x work spread).
// launch_bounds (256,2): (256,3)'s 84-VGPR cap spilled ~300MB/dispatch (R2/R3).
__global__ __launch_bounds__(256, 2) void attn_kernel(
    const u16* __restrict__ Qb, const u16* __restrict__ Kb,
    const u16* __restrict__ VTg, u16* __restrict__ Ob) {
  __shared__ __attribute__((aligned(16))) u16 SM[24576]; // 48KB
  __shared__ float fstat[4][32];
  __shared__ float lstat[4][32];
  u16* Ks  = SM;           // [64][128] swz
  u16* VTs = SM + 8192;    // [128][64] swz
  u16* Ps  = SM + 16384;   // 4 x [32][64] swz
  const int pr = blockIdx.x;            // 0..7
  const int h = blockIdx.y, b = blockIdx.z;
  const int kvh = h >> 2;               // N_REP = 4
  const int tid = threadIdx.x, w = tid >> 6, l = tid & 63, g = l >> 4, q = l & 15;
  const float SL2E = 0.08838834764831845f * 1.4426950408889634f;
  const u16* Qh = Qb + (size_t)b * S_ * NQ_ + h * HD_;
  const u16* Kh = Kb + ((size_t)b * S_ * KV_ + kvh) * HD_;
  const u16* Vh = VTg + (size_t)(b * KV_ + kvh) * (32 * 8192);
  u16* Oh = Ob + (size_t)b * S_ * NQ_ + h * HD_;

  for (int ph = 0; ph < 2; ++ph) {
    const int qt = ph ? pr : 15 - pr;
    bf16x8 aq[2][4];
    #pragma unroll
    for (int qb = 0; qb < 2; ++qb)
      #pragma unroll
      for (int kk = 0; kk < 4; ++kk)
        aq[qb][kk] = *(const bf16x8*)(Qh + (size_t)(qt * 128 + w * 32 + qb * 16 + q) * NQ_ + kk * 32 + g * 8);

    f32x4 o[2][8] = {};
    float mrow[2][4], lrow[2][4];
    #pragma unroll
    for (int qb = 0; qb < 2; ++qb)
      #pragma unroll
      for (int j = 0; j < 4; ++j) { mrow[qb][j] = -3.0e38f; lrow[qb][j] = 0.f; }

    const int nkt = 2 * qt + 2;
    for (int kt = 0; kt < nkt; ++kt) {
      __syncthreads();
      #pragma unroll
      for (int p = 0; p < 4; ++p) {   // K: [64][128]
        int c = tid + p * 256;
        int row = c >> 4, slot = c & 15;
        GLDS16(Kh + (size_t)(kt * 64 + row) * (KV_ * HD_) + ((slot ^ (row & 7)) << 3), Ks + c * 8);
      }
      #pragma unroll
      for (int p = 0; p < 4; ++p) {   // V^T: [128][64] from contiguous 16KB tile
        int c = tid + p * 256;
        int row = c >> 3, slot = c & 7;
        GLDS16(Vh + (size_t)kt * 8192 + row * 64 + ((slot ^ (row & 7)) << 3), VTs + c * 8);
      }
      __syncthreads();

      if (kt * 64 <= qt * 128 + w * 32 + 31) {   // wave-uniform activity gate
        // ---- QK^T ----
        f32x4 sc[2][4] = {};
        #pragma unroll
        for (int kk = 0; kk < 4; ++kk) {
          bf16x8 bk[4];
          #pragma unroll
          for (int n = 0; n < 4; ++n) {
            int row = n * 16 + q;
            bk[n] = *(const bf16x8*)(Ks + row * 128 + (((kk * 4 + g) ^ (row & 7)) << 3));
          }
          #pragma unroll
          for (int qb = 0; qb < 2; ++qb)
            #pragma unroll
            for (int n = 0; n < 4; ++n)
              sc[qb][n] = mfma16(aq[qb][kk], bk[n], sc[qb][n]);
        }
        // ---- causal mask (diagonal tiles only) ----
        if (kt * 64 + 63 > qt * 128 + w * 32) {
          #pragma unroll
          for (int qb = 0; qb < 2; ++qb)
            #pragma unroll
            for (int n = 0; n < 4; ++n)
              #pragma unroll
              for (int j = 0; j < 4; ++j) {
                int kglob = kt * 64 + n * 16 + q;
                int qglob = qt * 128 + w * 32 + qb * 16 + g * 4 + j;
                if (kglob > qglob) sc[qb][n][j] = -3.0e38f;
              }
        }
        // ---- online softmax ----
        float fct[2][4];
        #pragma unroll
        for (int qb = 0; qb < 2; ++qb)
          #pragma unroll
          for (int j = 0; j < 4; ++j) {
            float mx = fmaxf(fmaxf(sc[qb][0][j], sc[qb][1][j]),
                             fmaxf(sc[qb][2][j], sc[qb][3][j]));
            mx = fmaxf(mx, __shfl_xor(mx, 1));
            mx = fmaxf(mx, __shfl_xor(mx, 2));
            mx = fmaxf(mx, __shfl_xor(mx, 4));
            mx = fmaxf(mx, __shfl_xor(mx, 8));
            float mnew = fmaxf(mrow[qb][j], mx);
            float f = exp2f((mrow[qb][j] - mnew) * SL2E);
            float rs = 0.f;
            #pragma unroll
            for (int n = 0; n < 4; ++n) {
              float pv = exp2f((sc[qb][n][j] - mnew) * SL2E);
              sc[qb][n][j] = pv; rs += pv;
            }
            rs += __shfl_xor(rs, 1); rs += __shfl_xor(rs, 2);
            rs += __shfl_xor(rs, 4); rs += __shfl_xor(rs, 8);
            lrow[qb][j] = lrow[qb][j] * f + rs;
            mrow[qb][j] = mnew;
            fct[qb][j] = f;
          }
        if (q == 0) {
          #pragma unroll
          for (int qb = 0; qb < 2; ++qb)
            #pragma unroll
            for (int j = 0; j < 4; ++j)
              fstat[w][qb * 16 + g * 4 + j] = fct[qb][j];
        }
        // P -> LDS (swizzled [32][64], chunk ^= (r>>1)&7; truncating convert)
        #pragma unroll
        for (int qb = 0; qb < 2; ++qb)
          #pragma unroll
          for (int n = 0; n < 4; ++n)
            #pragma unroll
            for (int j = 0; j < 4; ++j) {
              int r = qb * 16 + g * 4 + j;
              Ps[w * 2048 + r * 64 + (((n * 2 + (q >> 3)) ^ ((r >> 1) & 7)) << 3) + (q & 7)]
                  = f2bft(sc[qb][n][j]);
            }
        // rescale O
        #pragma unroll
        for (int qb = 0; qb < 2; ++qb) {
          float ff = fstat[w][qb * 16 + q];
          #pragma unroll
          for (int m = 0; m < 8; ++m) o[qb][m] *= ff;
        }
        // ---- PV: O^T = V^T * P^T ----
        #pragma unroll
        for (int kk2 = 0; kk2 < 2; ++kk2) {
          bf16x8 bp[2];
          #pragma unroll
          for (int qb = 0; qb < 2; ++qb) {
            int row = qb * 16 + q;
            bp[qb] = *(const bf16x8*)(Ps + w * 2048 + row * 64 + (((kk2 * 4 + g) ^ ((row >> 1) & 7)) << 3));
          }
          #pragma unroll
          for (int m = 0; m < 8; ++m) {
            int row = m * 16 + q;
            bf16x8 av = *(const bf16x8*)(VTs + row * 64 + (((kk2 * 4 + g) ^ (row & 7)) << 3));
            #pragma unroll
            for (int qb = 0; qb < 2; ++qb)
              o[qb][m] = mfma16(av, bp[qb], o[qb][m]);
          }
        }
      }
    }
    // ---- epilogue: normalize, transpose via LDS, coalesced store ----
    __syncthreads();
    if (q == 0) {
      #pragma unroll
      for (int qb = 0; qb < 2; ++qb)
        #pragma unroll
        for (int j = 0; j < 4; ++j)
          lstat[w][qb * 16 + g * 4 + j] = lrow[qb][j];
    }
    __syncthreads();
    u16* OS = SM; // [128][136]
    #pragma unroll
    for (int qb = 0; qb < 2; ++qb) {
      float linv = 1.0f / lstat[w][qb * 16 + q];
      #pragma unroll
      for (int m = 0; m < 8; ++m)
        #pragma unroll
        for (int j = 0; j < 4; ++j)
          OS[(w * 32 + qb * 16 + q) * 136 + m * 16 + g * 4 + j] = f2bf(o[qb][m][j] * linv);
    }
    __syncthreads();
    #pragma unroll
    for (int p = 0; p < 8; ++p) {
      int c = tid + p * 256;
      int row = c >> 4, col8 = c & 15;
      u16x8 d = *(const u16x8*)(OS + row * 136 + col8 * 8);
      *(u16x8*)(Oh + (size_t)(qt * 128 + row) * NQ_ + col8 * 8) = d;
    }
  }
}

extern "C" void kernel_launch(void* const* d_in, const int* in_sizes, int n_in,
                              void* d_out, int out_size, void* d_ws, size_t ws_size,
                              hipStream_t stream) {
  const float* x  = (const float*)d_in[0];
  const float* fc = (const float*)d_in[1];
  const float* fs = (const float*)d_in[2];
  // d_in[3] = mask (causal, applied analytically)
  const float* wq = (const float*)d_in[4];
  const float* wk = (const float*)d_in[5];
  const float* wv = (const float*)d_in[6];
  const float* wo = (const float*)d_in[7];

  char* ws = (char*)d_ws;
  u16* xb  = (u16*)(ws + 0);          // 33554432 B
  u16* wqT = (u16*)(ws + 33554432);   // 33554432
  u16* wkT = (u16*)(ws + 67108864);   // 8388608
  u16* wvT = (u16*)(ws + 75497472);   // 8388608
  u16* woT = (u16*)(ws + 83886080);   // 33554432
  u16* qb  = (u16*)(ws + 117440512);  // 33554432
  u16* kb  = (u16*)(ws + 150994944);  // 8388608
  u16* vtg = (u16*)(ws + 159383552);  // 8388608  (V^T tiled: [B][KV][32][128][64])
  u16* ob  = (u16*)(ws + 167772160);  // 33554432  -> total 201326592
  if (ws_size < 201326592u) return;

  cvt_bf16<<<(M_ * D_) / (8 * 256), 256, 0, stream>>>(x, xb, M_ * D_);
  tcvt<<<dim3(NQ_ / 32, D_ / 32), 256, 0, stream>>>(wq, wqT, D_, NQ_);
  tcvt<<<dim3(NKV_ / 32, D_ / 32), 256, 0, stream>>>(wk, wkT, D_, NKV_);
  tcvt<<<dim3(NKV_ / 32, D_ / 32), 256, 0, stream>>>(wv, wvT, D_, NKV_);
  tcvt<<<dim3(D_ / 32, NQ_ / 32), 256, 0, stream>>>(wo, woT, NQ_, D_);

  gemm256<0><<<dim3(NQ_ / 256, M_ / 256), 512, 131072, stream>>>(xb, wqT, qb, M_, NQ_, D_);
  gemm_bt<0><<<dim3(NKV_ / 128, M_ / 128), 256, 0, stream>>>(xb, wkT, kb, M_, NKV_, D_);
  gemm_bt<2><<<dim3(NKV_ / 128, M_ / 128), 256, 0, stream>>>(xb, wvT, vtg, M_, NKV_, D_);

  rope_kernel<<<(M_ * NQ_ / 2) / 256, 256, 0, stream>>>(qb, fc, fs, 11, M_ * NQ_ / 2);
  rope_kernel<<<(M_ * NKV_ / 2) / 256, 256, 0, stream>>>(kb, fc, fs, 9, M_ * NKV_ / 2);

  attn_kernel<<<dim3(8, H_, B_), 256, 0, stream>>>(qb, kb, vtg, ob);

  gemm256<1><<<dim3(D_ / 256, M_ / 256), 512, 131072, stream>>>(ob, woT, d_out, M_, D_, NQ_);
}

// Round 6
// 643.808 us; speedup vs baseline: 2.0712x; 1.1110x over previous
//
#include <hip/hip_runtime.h>
#include <stdint.h>

#define B_ 2
#define S_ 2048
#define D_ 4096
#define H_ 32
#define KV_ 8
#define HD_ 128
#define M_ (B_*S_)          // 4096 rows (b*S+s)
#define NQ_ (H_*HD_)        // 4096
#define NKV_ (KV_*HD_)      // 1024

typedef unsigned short u16;
typedef __bf16 bf16x8 __attribute__((ext_vector_type(8)));
typedef float f32x4 __attribute__((ext_vector_type(4)));
typedef u16 u16x8 __attribute__((ext_vector_type(8)));
typedef u16 u16x4 __attribute__((ext_vector_type(4)));

__device__ __forceinline__ u16 f2bf(float f) {
  union { float f; unsigned u; } v; v.f = f;
  unsigned r = v.u + 0x7fffu + ((v.u >> 16) & 1u);
  return (u16)(r >> 16);
}
__device__ __forceinline__ u16 f2bft(float f) {  // truncating (for P; values in [0,1])
  union { float f; unsigned u; } v; v.f = f;
  return (u16)(v.u >> 16);
}
__device__ __forceinline__ float bf2f(u16 u) {
  union { unsigned u; float f; } v; v.u = ((unsigned)u) << 16;
  return v.f;
}
__device__ __forceinline__ f32x4 mfma16(bf16x8 a, bf16x8 b, f32x4 c) {
  return __builtin_amdgcn_mfma_f32_16x16x32_bf16(a, b, c, 0, 0, 0);
}

#define GLDS16(gp, lp) __builtin_amdgcn_global_load_lds( \
    (const __attribute__((address_space(1))) unsigned int*)(gp), \
    (__attribute__((address_space(3))) unsigned int*)(lp), 16, 0, 0)

// ---------------- fp32 -> bf16 convert (vectorized) ----------------
__global__ __launch_bounds__(256) void cvt_bf16(const float* __restrict__ in,
                                                u16* __restrict__ out, int n) {
  int i = (blockIdx.x * 256 + threadIdx.x) * 8;
  if (i >= n) return;
  float4 a = *(const float4*)(in + i);
  float4 b = *(const float4*)(in + i + 4);
  u16x8 o;
  o[0]=f2bf(a.x); o[1]=f2bf(a.y); o[2]=f2bf(a.z); o[3]=f2bf(a.w);
  o[4]=f2bf(b.x); o[5]=f2bf(b.y); o[6]=f2bf(b.z); o[7]=f2bf(b.w);
  *(u16x8*)(out + i) = o;
}

// ---------------- transpose + convert: out[c][r] = in[r][c] ----------------
__global__ __launch_bounds__(256) void tcvt(const float* __restrict__ in,
                                            u16* __restrict__ out, int R, int C) {
  __shared__ __attribute__((aligned(16))) u16 tile[32][33];
  int c0 = blockIdx.x * 32, r0 = blockIdx.y * 32;
  int tx = threadIdx.x & 31, ty = threadIdx.x >> 5;
  #pragma unroll
  for (int j = ty; j < 32; j += 8)
    tile[j][tx] = f2bf(in[(size_t)(r0 + j) * C + c0 + tx]);
  __syncthreads();
  #pragma unroll
  for (int j = ty; j < 32; j += 8)
    out[(size_t)(c0 + j) * R + r0 + tx] = tile[tx][j];
}

// ---------------- 128x128 GEMM (m97-style) ----------------
// OUTMODE 3 = fused K/V projection: N=2048; col<1024 -> K row-major (Cv, stride
// 1024); col>=1024 -> V^T 16KB-tiled (Cv2): off = ((b*KV+kv)*32+t)*8192+d*64+s6.
template<int OUTMODE>
__global__ __launch_bounds__(256) void gemm_bt(const u16* __restrict__ A,
    const u16* __restrict__ BT, void* __restrict__ Cv, void* __restrict__ Cv2,
    int M, int N, int K) {
  __shared__ __attribute__((aligned(16))) u16 As[128 * 32];
  __shared__ __attribute__((aligned(16))) u16 Bs[128 * 32];
  const int tid = threadIdx.x;
  const int bn0 = blockIdx.x * 128, bm0 = blockIdx.y * 128;
  const int w = tid >> 6, l = tid & 63, g = l >> 4, q = l & 15;
  const int wm = (w >> 1) * 64, wn = (w & 1) * 64;
  f32x4 acc[4][4] = {};
  for (int kt = 0; kt < K; kt += 32) {
    __syncthreads();
    #pragma unroll
    for (int p = 0; p < 2; ++p) {
      int c = tid + p * 256;
      int row = c >> 2, slot = c & 3;
      int srck = (slot ^ ((row >> 1) & 3)) << 3;
      GLDS16(A + (size_t)(bm0 + row) * K + kt + srck, As + c * 8);
      GLDS16(BT + (size_t)(bn0 + row) * K + kt + srck, Bs + c * 8);
    }
    __syncthreads();
    bf16x8 af[4], bfr[4];
    #pragma unroll
    for (int m = 0; m < 4; ++m) {
      int row = wm + m * 16 + q;
      af[m] = *(const bf16x8*)(As + row * 32 + ((g ^ ((row >> 1) & 3)) << 3));
    }
    #pragma unroll
    for (int n = 0; n < 4; ++n) {
      int row = wn + n * 16 + q;
      bfr[n] = *(const bf16x8*)(Bs + row * 32 + ((g ^ ((row >> 1) & 3)) << 3));
    }
    #pragma unroll
    for (int m = 0; m < 4; ++m)
      #pragma unroll
      for (int n = 0; n < 4; ++n)
        acc[m][n] = mfma16(af[m], bfr[n], acc[m][n]);
  }
  #pragma unroll
  for (int m = 0; m < 4; ++m)
    #pragma unroll
    for (int n = 0; n < 4; ++n) {
      if (OUTMODE == 3) {
        int row0 = bm0 + wm + m * 16 + g * 4;
        int col  = bn0 + wn + n * 16 + q;
        if (col < 1024) {
          #pragma unroll
          for (int j = 0; j < 4; ++j)
            ((u16*)Cv)[(size_t)(row0 + j) * 1024 + col] = f2bf(acc[m][n][j]);
        } else {
          int c2 = col - 1024;
          u16x4 pk;
          #pragma unroll
          for (int j = 0; j < 4; ++j) pk[j] = f2bf(acc[m][n][j]);
          size_t off = ((size_t)((row0 >> 11) * KV_ + (c2 >> 7)) * 32 + ((row0 >> 6) & 31)) * 8192
                     + (size_t)(c2 & 127) * 64 + (row0 & 63);
          *(u16x4*)((u16*)Cv2 + off) = pk;
        }
      } else {
        #pragma unroll
        for (int j = 0; j < 4; ++j) {
          size_t off = (size_t)(bm0 + wm + m * 16 + g * 4 + j) * N + (bn0 + wn + n * 16 + q);
          if (OUTMODE == 1) ((float*)Cv)[off] = acc[m][n][j];
          else              ((u16*)Cv)[off]  = f2bf(acc[m][n][j]);
        }
      }
    }
}

// ---------------- 256x256 dbuf GEMM, counted vmcnt (T3+T4+T5) ----------------
template<int OUTMODE>
__global__ __launch_bounds__(512, 2) void gemm256(const u16* __restrict__ A,
    const u16* __restrict__ BT, void* __restrict__ Cv, int M, int N, int K) {
  extern __shared__ __attribute__((aligned(16))) u16 DL[];  // [2][2][16384]
  const int tid = threadIdx.x;
  const int bn0 = blockIdx.x * 256, bm0 = blockIdx.y * 256;
  const int l = tid & 63, g = l >> 4, q = l & 15;
  const int w = tid >> 6;
  const int wm = (w >> 2) * 128, wn = (w & 3) * 64;
  const int nt = K >> 6;
  f32x4 acc[8][4] = {};

  auto STAGE = [&](int t, int buf) {
    const int kt = t << 6;
    u16* Ad = DL + buf * 32768;
    u16* Bd = Ad + 16384;
    #pragma unroll
    for (int p = 0; p < 4; ++p) {
      int idx = tid + p * 512;
      int row = idx >> 3, slot = idx & 7;
      int sk = (slot ^ (row & 7)) << 3;
      GLDS16(A + (size_t)(bm0 + row) * K + kt + sk, Ad + idx * 8);
    }
    #pragma unroll
    for (int p = 0; p < 4; ++p) {
      int idx = tid + p * 512;
      int row = idx >> 3, slot = idx & 7;
      int sk = (slot ^ (row & 7)) << 3;
      GLDS16(BT + (size_t)(bn0 + row) * K + kt + sk, Bd + idx * 8);
    }
  };

  STAGE(0, 0);
  STAGE(1, 1);
  asm volatile("s_waitcnt vmcnt(8)" ::: "memory");   // tile0 landed; tile1 in flight
  __builtin_amdgcn_s_barrier();

  for (int t = 0; t < nt; ++t) {
    const int buf = t & 1;
    const u16* As = DL + buf * 32768;
    const u16* Bs = As + 16384;
    #pragma unroll
    for (int ks = 0; ks < 2; ++ks) {
      bf16x8 a[8], bb[2];
      #pragma unroll
      for (int m = 0; m < 8; ++m) {
        int row = wm + m * 16 + q;
        a[m] = *(const bf16x8*)(As + row * 64 + (((ks * 4 + g) ^ (row & 7)) << 3));
      }
      #pragma unroll
      for (int n = 0; n < 2; ++n) {
        int row = wn + n * 16 + q;
        bb[n] = *(const bf16x8*)(Bs + row * 64 + (((ks * 4 + g) ^ (row & 7)) << 3));
      }
      __builtin_amdgcn_s_setprio(1);
      #pragma unroll
      for (int m = 0; m < 8; ++m)
        #pragma unroll
        for (int n = 0; n < 2; ++n)
          acc[m][n] = mfma16(a[m], bb[n], acc[m][n]);
      __builtin_amdgcn_s_setprio(0);
      #pragma unroll
      for (int n = 0; n < 2; ++n) {
        int row = wn + (n + 2) * 16 + q;
        bb[n] = *(const bf16x8*)(Bs + row * 64 + (((ks * 4 + g) ^ (row & 7)) << 3));
      }
      __builtin_amdgcn_s_setprio(1);
      #pragma unroll
      for (int m = 0; m < 8; ++m)
        #pragma unroll
        for (int n = 0; n < 2; ++n)
          acc[m][n + 2] = mfma16(a[m], bb[n], acc[m][n + 2]);
      __builtin_amdgcn_s_setprio(0);
    }
    if (t + 1 < nt) {
      asm volatile("s_waitcnt lgkmcnt(0)" ::: "memory");
      __builtin_amdgcn_s_barrier();            // all waves done reading buf
      if (t + 2 < nt) {
        STAGE(t + 2, buf);
        asm volatile("s_waitcnt vmcnt(8)" ::: "memory");  // tile t+1 complete
      } else {
        asm volatile("s_waitcnt vmcnt(0)" ::: "memory");
      }
      __builtin_amdgcn_s_barrier();            // buf^1 (tile t+1) ready for all
    }
  }

  #pragma unroll
  for (int m = 0; m < 8; ++m)
    #pragma unroll
    for (int n = 0; n < 4; ++n)
      #pragma unroll
      for (int j = 0; j < 4; ++j) {
        size_t off = (size_t)(bm0 + wm + m * 16 + g * 4 + j) * N + (bn0 + wn + n * 16 + q);
        if (OUTMODE == 1) ((float*)Cv)[off] = acc[m][n][j];
        else              ((u16*)Cv)[off]  = f2bf(acc[m][n][j]);
      }
}

// ---------------- RoPE (interleaved pairs, in-place on bf16) ----------------
__global__ __launch_bounds__(256) void rope_kernel(u16* __restrict__ t,
    const float* __restrict__ fc, const float* __restrict__ fs,
    int log2ppr, int total_pairs) {
  int i = blockIdx.x * 256 + threadIdx.x;
  if (i >= total_pairs) return;
  int fi = i & 63;
  int row = i >> log2ppr;           // b*S + s
  int pos = row & (S_ - 1);
  float c = fc[pos * 64 + fi], s = fs[pos * 64 + fi];
  unsigned* p = (unsigned*)(t + 2 * (size_t)i);
  unsigned v = *p;
  float x0 = bf2f((u16)(v & 0xffffu)), x1 = bf2f((u16)(v >> 16));
  float r0 = x0 * c - x1 * s, r1 = x0 * s + x1 * c;
  *p = (unsigned)f2bf(r0) | ((unsigned)f2bf(r1) << 16);
}

// ---------------- causal GQA flash attention ----------------
// grid (8, H, B); block 256 = 4 waves; q-tile pairing {15-p, p} (uniform 34
// K-iters). K double-buffered + V single-buffered in LDS, staged via
// gload_lds with counted vmcnt (K(kt+1) prefetched during compute(kt);
// V(kt) hidden under QK^T+softmax). Raw s_barrier (no full vmcnt drain).
// LDS 66.5KB -> 2 blocks/CU. launch_bounds (256,2): (256,3) spilled (R2/R3).
__global__ __launch_bounds__(256, 2) void attn_kernel(
    const u16* __restrict__ Qb, const u16* __restrict__ Kb,
    const u16* __restrict__ VTg, u16* __restrict__ Ob) {
  __shared__ __attribute__((aligned(16))) u16 SM[32768]; // 64KB
  __shared__ float fstat[4][32];
  __shared__ float lstat[4][32];
  // SM: Kd[2][64][128] (el 0..16384) | Vs[128][64] (16384..24576) | Ps 4x[32][64]
  u16* Vs = SM + 16384;
  u16* Ps = SM + 24576;
  const int pr = blockIdx.x;            // 0..7
  const int h = blockIdx.y, b = blockIdx.z;
  const int kvh = h >> 2;               // N_REP = 4
  const int tid = threadIdx.x, w = tid >> 6, l = tid & 63, g = l >> 4, q = l & 15;
  const float SL2E = 0.08838834764831845f * 1.4426950408889634f;
  const u16* Qh = Qb + (size_t)b * S_ * NQ_ + h * HD_;
  const u16* Kh = Kb + ((size_t)b * S_ * KV_ + kvh) * HD_;
  const u16* Vh = VTg + (size_t)(b * KV_ + kvh) * (32 * 8192);
  u16* Oh = Ob + (size_t)b * S_ * NQ_ + h * HD_;

  for (int ph = 0; ph < 2; ++ph) {
    const int qt = ph ? pr : 15 - pr;
    __syncthreads();   // SM (epilogue scratch) free before restaging
    bf16x8 aq[2][4];
    #pragma unroll
    for (int qb = 0; qb < 2; ++qb)
      #pragma unroll
      for (int kk = 0; kk < 4; ++kk)
        aq[qb][kk] = *(const bf16x8*)(Qh + (size_t)(qt * 128 + w * 32 + qb * 16 + q) * NQ_ + kk * 32 + g * 8);

    f32x4 o[2][8] = {};
    float mrow[2][4], lrow[2][4];
    #pragma unroll
    for (int qb = 0; qb < 2; ++qb)
      #pragma unroll
      for (int j = 0; j < 4; ++j) { mrow[qb][j] = -3.0e38f; lrow[qb][j] = 0.f; }

    const int nkt = 2 * qt + 2;
    // prologue: stage K tile 0 into buf 0
    #pragma unroll
    for (int p = 0; p < 4; ++p) {
      int c = tid + p * 256;
      int row = c >> 4, slot = c & 15;
      GLDS16(Kh + (size_t)(row) * (KV_ * HD_) + ((slot ^ (row & 7)) << 3), SM + c * 8);
    }
    for (int kt = 0; kt < nkt; ++kt) {
      // stage V(kt) (single buffer; prior PV done per end-barrier)
      #pragma unroll
      for (int p = 0; p < 4; ++p) {
        int c = tid + p * 256;
        int row = c >> 3, slot = c & 7;
        GLDS16(Vh + (size_t)kt * 8192 + row * 64 + ((slot ^ (row & 7)) << 3), Vs + c * 8);
      }
      if (kt + 1 < nkt) {
        // stage K(kt+1) into buf (kt+1)&1
        u16* Kn = SM + ((kt + 1) & 1) * 8192;
        #pragma unroll
        for (int p = 0; p < 4; ++p) {
          int c = tid + p * 256;
          int row = c >> 4, slot = c & 15;
          GLDS16(Kh + (size_t)((kt + 1) * 64 + row) * (KV_ * HD_) + ((slot ^ (row & 7)) << 3), Kn + c * 8);
        }
        asm volatile("s_waitcnt vmcnt(4)" ::: "memory");  // K(kt)+V(kt) landed
      } else {
        asm volatile("s_waitcnt vmcnt(0)" ::: "memory");
      }
      __builtin_amdgcn_s_barrier();
      const u16* Kc = SM + (kt & 1) * 8192;

      if (kt * 64 <= qt * 128 + w * 32 + 31) {   // wave-uniform activity gate
        // ---- QK^T ----
        f32x4 sc[2][4] = {};
        #pragma unroll
        for (int kk = 0; kk < 4; ++kk) {
          bf16x8 bk[4];
          #pragma unroll
          for (int n = 0; n < 4; ++n) {
            int row = n * 16 + q;
            bk[n] = *(const bf16x8*)(Kc + row * 128 + (((kk * 4 + g) ^ (row & 7)) << 3));
          }
          #pragma unroll
          for (int qb = 0; qb < 2; ++qb)
            #pragma unroll
            for (int n = 0; n < 4; ++n)
              sc[qb][n] = mfma16(aq[qb][kk], bk[n], sc[qb][n]);
        }
        // ---- causal mask (diagonal tiles only) ----
        if (kt * 64 + 63 > qt * 128 + w * 32) {
          #pragma unroll
          for (int qb = 0; qb < 2; ++qb)
            #pragma unroll
            for (int n = 0; n < 4; ++n)
              #pragma unroll
              for (int j = 0; j < 4; ++j) {
                int kglob = kt * 64 + n * 16 + q;
                int qglob = qt * 128 + w * 32 + qb * 16 + g * 4 + j;
                if (kglob > qglob) sc[qb][n][j] = -3.0e38f;
              }
        }
        // ---- online softmax ----
        float fct[2][4];
        #pragma unroll
        for (int qb = 0; qb < 2; ++qb)
          #pragma unroll
          for (int j = 0; j < 4; ++j) {
            float mx = fmaxf(fmaxf(sc[qb][0][j], sc[qb][1][j]),
                             fmaxf(sc[qb][2][j], sc[qb][3][j]));
            mx = fmaxf(mx, __shfl_xor(mx, 1));
            mx = fmaxf(mx, __shfl_xor(mx, 2));
            mx = fmaxf(mx, __shfl_xor(mx, 4));
            mx = fmaxf(mx, __shfl_xor(mx, 8));
            float mnew = fmaxf(mrow[qb][j], mx);
            float f = exp2f((mrow[qb][j] - mnew) * SL2E);
            float rs = 0.f;
            #pragma unroll
            for (int n = 0; n < 4; ++n) {
              float pv = exp2f((sc[qb][n][j] - mnew) * SL2E);
              sc[qb][n][j] = pv; rs += pv;
            }
            rs += __shfl_xor(rs, 1); rs += __shfl_xor(rs, 2);
            rs += __shfl_xor(rs, 4); rs += __shfl_xor(rs, 8);
            lrow[qb][j] = lrow[qb][j] * f + rs;
            mrow[qb][j] = mnew;
            fct[qb][j] = f;
          }
        if (q == 0) {
          #pragma unroll
          for (int qb = 0; qb < 2; ++qb)
            #pragma unroll
            for (int j = 0; j < 4; ++j)
              fstat[w][qb * 16 + g * 4 + j] = fct[qb][j];
        }
        // P -> LDS (swizzled [32][64], chunk ^= (r>>1)&7; truncating convert)
        #pragma unroll
        for (int qb = 0; qb < 2; ++qb)
          #pragma unroll
          for (int n = 0; n < 4; ++n)
            #pragma unroll
            for (int j = 0; j < 4; ++j) {
              int r = qb * 16 + g * 4 + j;
              Ps[w * 2048 + r * 64 + (((n * 2 + (q >> 3)) ^ ((r >> 1) & 7)) << 3) + (q & 7)]
                  = f2bft(sc[qb][n][j]);
            }
        // rescale O
        #pragma unroll
        for (int qb = 0; qb < 2; ++qb) {
          float ff = fstat[w][qb * 16 + q];
          #pragma unroll
          for (int m = 0; m < 8; ++m) o[qb][m] *= ff;
        }
        // ---- PV: O^T = V^T * P^T ----
        #pragma unroll
        for (int kk2 = 0; kk2 < 2; ++kk2) {
          bf16x8 bp[2];
          #pragma unroll
          for (int qb = 0; qb < 2; ++qb) {
            int row = qb * 16 + q;
            bp[qb] = *(const bf16x8*)(Ps + w * 2048 + row * 64 + (((kk2 * 4 + g) ^ ((row >> 1) & 7)) << 3));
          }
          #pragma unroll
          for (int m = 0; m < 8; ++m) {
            int row = m * 16 + q;
            bf16x8 av = *(const bf16x8*)(Vs + row * 64 + (((kk2 * 4 + g) ^ (row & 7)) << 3));
            #pragma unroll
            for (int qb = 0; qb < 2; ++qb)
              o[qb][m] = mfma16(av, bp[qb], o[qb][m]);
          }
        }
      }
      __builtin_amdgcn_s_barrier();   // all waves done with Kd[kt&1]/Vs
    }
    // ---- epilogue: normalize, transpose via LDS, coalesced store ----
    __syncthreads();
    if (q == 0) {
      #pragma unroll
      for (int qb = 0; qb < 2; ++qb)
        #pragma unroll
        for (int j = 0; j < 4; ++j)
          lstat[w][qb * 16 + g * 4 + j] = lrow[qb][j];
    }
    __syncthreads();
    u16* OS = SM; // [128][136]
    #pragma unroll
    for (int qb = 0; qb < 2; ++qb) {
      float linv = 1.0f / lstat[w][qb * 16 + q];
      #pragma unroll
      for (int m = 0; m < 8; ++m)
        #pragma unroll
        for (int j = 0; j < 4; ++j)
          OS[(w * 32 + qb * 16 + q) * 136 + m * 16 + g * 4 + j] = f2bf(o[qb][m][j] * linv);
    }
    __syncthreads();
    #pragma unroll
    for (int p = 0; p < 8; ++p) {
      int c = tid + p * 256;
      int row = c >> 4, col8 = c & 15;
      u16x8 d = *(const u16x8*)(OS + row * 136 + col8 * 8);
      *(u16x8*)(Oh + (size_t)(qt * 128 + row) * NQ_ + col8 * 8) = d;
    }
  }
}

extern "C" void kernel_launch(void* const* d_in, const int* in_sizes, int n_in,
                              void* d_out, int out_size, void* d_ws, size_t ws_size,
                              hipStream_t stream) {
  const float* x  = (const float*)d_in[0];
  const float* fc = (const float*)d_in[1];
  const float* fs = (const float*)d_in[2];
  // d_in[3] = mask (causal, applied analytically)
  const float* wq = (const float*)d_in[4];
  const float* wk = (const float*)d_in[5];
  const float* wv = (const float*)d_in[6];
  const float* wo = (const float*)d_in[7];

  char* ws = (char*)d_ws;
  u16* xb  = (u16*)(ws + 0);          // 33554432 B
  u16* wqT = (u16*)(ws + 33554432);   // 33554432
  u16* wkT = (u16*)(ws + 67108864);   // 8388608   (wkT||wvT = [2048][4096])
  u16* wvT = (u16*)(ws + 75497472);   // 8388608
  u16* woT = (u16*)(ws + 83886080);   // 33554432
  u16* qb  = (u16*)(ws + 117440512);  // 33554432
  u16* kb  = (u16*)(ws + 150994944);  // 8388608
  u16* vtg = (u16*)(ws + 159383552);  // 8388608  (V^T tiled: [B][KV][32][128][64])
  u16* ob  = (u16*)(ws + 167772160);  // 33554432  -> total 201326592
  if (ws_size < 201326592u) return;

  cvt_bf16<<<(M_ * D_) / (8 * 256), 256, 0, stream>>>(x, xb, M_ * D_);
  tcvt<<<dim3(NQ_ / 32, D_ / 32), 256, 0, stream>>>(wq, wqT, D_, NQ_);
  tcvt<<<dim3(NKV_ / 32, D_ / 32), 256, 0, stream>>>(wk, wkT, D_, NKV_);
  tcvt<<<dim3(NKV_ / 32, D_ / 32), 256, 0, stream>>>(wv, wvT, D_, NKV_);
  tcvt<<<dim3(D_ / 32, NQ_ / 32), 256, 0, stream>>>(wo, woT, NQ_, D_);

  gemm256<0><<<dim3(NQ_ / 256, M_ / 256), 512, 131072, stream>>>(xb, wqT, qb, M_, NQ_, D_);
  // fused K+V projection: N=2048 (wkT||wvT contiguous)
  gemm_bt<3><<<dim3(2048 / 128, M_ / 128), 256, 0, stream>>>(xb, wkT, kb, vtg, M_, 2048, D_);

  rope_kernel<<<(M_ * NQ_ / 2) / 256, 256, 0, stream>>>(qb, fc, fs, 11, M_ * NQ_ / 2);
  rope_kernel<<<(M_ * NKV_ / 2) / 256, 256, 0, stream>>>(kb, fc, fs, 9, M_ * NKV_ / 2);

  attn_kernel<<<dim3(8, H_, B_), 256, 0, stream>>>(qb, kb, vtg, ob);

  gemm256<1><<<dim3(D_ / 256, M_ / 256), 512, 131072, stream>>>(ob, woT, d_out, M_, D_, NQ_);
}

// Round 7
// 587.659 us; speedup vs baseline: 2.2691x; 1.0955x over previous
//
#include <hip/hip_runtime.h>
#include <stdint.h>

#define B_ 2
#define S_ 2048
#define D_ 4096
#define H_ 32
#define KV_ 8
#define HD_ 128
#define M_ (B_*S_)          // 4096 rows (b*S+s)
#define NQ_ (H_*HD_)        // 4096
#define NKV_ (KV_*HD_)      // 1024

typedef unsigned short u16;
typedef __bf16 bf16x8 __attribute__((ext_vector_type(8)));
typedef float f32x4 __attribute__((ext_vector_type(4)));
typedef u16 u16x8 __attribute__((ext_vector_type(8)));
typedef u16 u16x4 __attribute__((ext_vector_type(4)));

__device__ __forceinline__ u16 f2bf(float f) {
  union { float f; unsigned u; } v; v.f = f;
  unsigned r = v.u + 0x7fffu + ((v.u >> 16) & 1u);
  return (u16)(r >> 16);
}
__device__ __forceinline__ u16 f2bft(float f) {  // truncating (for P; values in [0,4.2])
  union { float f; unsigned u; } v; v.f = f;
  return (u16)(v.u >> 16);
}
__device__ __forceinline__ float bf2f(u16 u) {
  union { unsigned u; float f; } v; v.u = ((unsigned)u) << 16;
  return v.f;
}
__device__ __forceinline__ f32x4 mfma16(bf16x8 a, bf16x8 b, f32x4 c) {
  return __builtin_amdgcn_mfma_f32_16x16x32_bf16(a, b, c, 0, 0, 0);
}

#define GLDS16(gp, lp) __builtin_amdgcn_global_load_lds( \
    (const __attribute__((address_space(1))) unsigned int*)(gp), \
    (__attribute__((address_space(3))) unsigned int*)(lp), 16, 0, 0)

// ---------------- fp32 -> bf16 convert (vectorized) ----------------
__global__ __launch_bounds__(256) void cvt_bf16(const float* __restrict__ in,
                                                u16* __restrict__ out, int n) {
  int i = (blockIdx.x * 256 + threadIdx.x) * 8;
  if (i >= n) return;
  float4 a = *(const float4*)(in + i);
  float4 b = *(const float4*)(in + i + 4);
  u16x8 o;
  o[0]=f2bf(a.x); o[1]=f2bf(a.y); o[2]=f2bf(a.z); o[3]=f2bf(a.w);
  o[4]=f2bf(b.x); o[5]=f2bf(b.y); o[6]=f2bf(b.z); o[7]=f2bf(b.w);
  *(u16x8*)(out + i) = o;
}

// ---------------- transpose + convert: out[c][r] = in[r][c] ----------------
__global__ __launch_bounds__(256) void tcvt(const float* __restrict__ in,
                                            u16* __restrict__ out, int R, int C) {
  __shared__ __attribute__((aligned(16))) u16 tile[32][33];
  int c0 = blockIdx.x * 32, r0 = blockIdx.y * 32;
  int tx = threadIdx.x & 31, ty = threadIdx.x >> 5;
  #pragma unroll
  for (int j = ty; j < 32; j += 8)
    tile[j][tx] = f2bf(in[(size_t)(r0 + j) * C + c0 + tx]);
  __syncthreads();
  #pragma unroll
  for (int j = ty; j < 32; j += 8)
    out[(size_t)(c0 + j) * R + r0 + tx] = tile[tx][j];
}

// ---------------- 128x128 GEMM (m97-style) ----------------
// OUTMODE 3 = fused K/V projection: N=2048; col<1024 -> K row-major (Cv, stride
// 1024); col>=1024 -> V^T 16KB-tiled (Cv2): off = ((b*KV+kv)*32+t)*8192+d*64+s6.
template<int OUTMODE>
__global__ __launch_bounds__(256) void gemm_bt(const u16* __restrict__ A,
    const u16* __restrict__ BT, void* __restrict__ Cv, void* __restrict__ Cv2,
    int M, int N, int K) {
  __shared__ __attribute__((aligned(16))) u16 As[128 * 32];
  __shared__ __attribute__((aligned(16))) u16 Bs[128 * 32];
  const int tid = threadIdx.x;
  const int bn0 = blockIdx.x * 128, bm0 = blockIdx.y * 128;
  const int w = tid >> 6, l = tid & 63, g = l >> 4, q = l & 15;
  const int wm = (w >> 1) * 64, wn = (w & 1) * 64;
  f32x4 acc[4][4] = {};
  for (int kt = 0; kt < K; kt += 32) {
    __syncthreads();
    #pragma unroll
    for (int p = 0; p < 2; ++p) {
      int c = tid + p * 256;
      int row = c >> 2, slot = c & 3;
      int srck = (slot ^ ((row >> 1) & 3)) << 3;
      GLDS16(A + (size_t)(bm0 + row) * K + kt + srck, As + c * 8);
      GLDS16(BT + (size_t)(bn0 + row) * K + kt + srck, Bs + c * 8);
    }
    __syncthreads();
    bf16x8 af[4], bfr[4];
    #pragma unroll
    for (int m = 0; m < 4; ++m) {
      int row = wm + m * 16 + q;
      af[m] = *(const bf16x8*)(As + row * 32 + ((g ^ ((row >> 1) & 3)) << 3));
    }
    #pragma unroll
    for (int n = 0; n < 4; ++n) {
      int row = wn + n * 16 + q;
      bfr[n] = *(const bf16x8*)(Bs + row * 32 + ((g ^ ((row >> 1) & 3)) << 3));
    }
    #pragma unroll
    for (int m = 0; m < 4; ++m)
      #pragma unroll
      for (int n = 0; n < 4; ++n)
        acc[m][n] = mfma16(af[m], bfr[n], acc[m][n]);
  }
  #pragma unroll
  for (int m = 0; m < 4; ++m)
    #pragma unroll
    for (int n = 0; n < 4; ++n) {
      if (OUTMODE == 3) {
        int row0 = bm0 + wm + m * 16 + g * 4;
        int col  = bn0 + wn + n * 16 + q;
        if (col < 1024) {
          #pragma unroll
          for (int j = 0; j < 4; ++j)
            ((u16*)Cv)[(size_t)(row0 + j) * 1024 + col] = f2bf(acc[m][n][j]);
        } else {
          int c2 = col - 1024;
          u16x4 pk;
          #pragma unroll
          for (int j = 0; j < 4; ++j) pk[j] = f2bf(acc[m][n][j]);
          size_t off = ((size_t)((row0 >> 11) * KV_ + (c2 >> 7)) * 32 + ((row0 >> 6) & 31)) * 8192
                     + (size_t)(c2 & 127) * 64 + (row0 & 63);
          *(u16x4*)((u16*)Cv2 + off) = pk;
        }
      } else {
        #pragma unroll
        for (int j = 0; j < 4; ++j) {
          size_t off = (size_t)(bm0 + wm + m * 16 + g * 4 + j) * N + (bn0 + wn + n * 16 + q);
          if (OUTMODE == 1) ((float*)Cv)[off] = acc[m][n][j];
          else              ((u16*)Cv)[off]  = f2bf(acc[m][n][j]);
        }
      }
    }
}

// ---------------- 256x256 dbuf GEMM, counted vmcnt (T3+T4+T5) ----------------
template<int OUTMODE>
__global__ __launch_bounds__(512, 2) void gemm256(const u16* __restrict__ A,
    const u16* __restrict__ BT, void* __restrict__ Cv, int M, int N, int K) {
  extern __shared__ __attribute__((aligned(16))) u16 DL[];  // [2][2][16384]
  const int tid = threadIdx.x;
  const int bn0 = blockIdx.x * 256, bm0 = blockIdx.y * 256;
  const int l = tid & 63, g = l >> 4, q = l & 15;
  const int w = tid >> 6;
  const int wm = (w >> 2) * 128, wn = (w & 3) * 64;
  const int nt = K >> 6;
  f32x4 acc[8][4] = {};

  auto STAGE = [&](int t, int buf) {
    const int kt = t << 6;
    u16* Ad = DL + buf * 32768;
    u16* Bd = Ad + 16384;
    #pragma unroll
    for (int p = 0; p < 4; ++p) {
      int idx = tid + p * 512;
      int row = idx >> 3, slot = idx & 7;
      int sk = (slot ^ (row & 7)) << 3;
      GLDS16(A + (size_t)(bm0 + row) * K + kt + sk, Ad + idx * 8);
    }
    #pragma unroll
    for (int p = 0; p < 4; ++p) {
      int idx = tid + p * 512;
      int row = idx >> 3, slot = idx & 7;
      int sk = (slot ^ (row & 7)) << 3;
      GLDS16(BT + (size_t)(bn0 + row) * K + kt + sk, Bd + idx * 8);
    }
  };

  STAGE(0, 0);
  STAGE(1, 1);
  asm volatile("s_waitcnt vmcnt(8)" ::: "memory");   // tile0 landed; tile1 in flight
  __builtin_amdgcn_s_barrier();

  for (int t = 0; t < nt; ++t) {
    const int buf = t & 1;
    const u16* As = DL + buf * 32768;
    const u16* Bs = As + 16384;
    #pragma unroll
    for (int ks = 0; ks < 2; ++ks) {
      bf16x8 a[8], bb[2];
      #pragma unroll
      for (int m = 0; m < 8; ++m) {
        int row = wm + m * 16 + q;
        a[m] = *(const bf16x8*)(As + row * 64 + (((ks * 4 + g) ^ (row & 7)) << 3));
      }
      #pragma unroll
      for (int n = 0; n < 2; ++n) {
        int row = wn + n * 16 + q;
        bb[n] = *(const bf16x8*)(Bs + row * 64 + (((ks * 4 + g) ^ (row & 7)) << 3));
      }
      __builtin_amdgcn_s_setprio(1);
      #pragma unroll
      for (int m = 0; m < 8; ++m)
        #pragma unroll
        for (int n = 0; n < 2; ++n)
          acc[m][n] = mfma16(a[m], bb[n], acc[m][n]);
      __builtin_amdgcn_s_setprio(0);
      #pragma unroll
      for (int n = 0; n < 2; ++n) {
        int row = wn + (n + 2) * 16 + q;
        bb[n] = *(const bf16x8*)(Bs + row * 64 + (((ks * 4 + g) ^ (row & 7)) << 3));
      }
      __builtin_amdgcn_s_setprio(1);
      #pragma unroll
      for (int m = 0; m < 8; ++m)
        #pragma unroll
        for (int n = 0; n < 2; ++n)
          acc[m][n + 2] = mfma16(a[m], bb[n], acc[m][n + 2]);
      __builtin_amdgcn_s_setprio(0);
    }
    if (t + 1 < nt) {
      asm volatile("s_waitcnt lgkmcnt(0)" ::: "memory");
      __builtin_amdgcn_s_barrier();            // all waves done reading buf
      if (t + 2 < nt) {
        STAGE(t + 2, buf);
        asm volatile("s_waitcnt vmcnt(8)" ::: "memory");  // tile t+1 complete
      } else {
        asm volatile("s_waitcnt vmcnt(0)" ::: "memory");
      }
      __builtin_amdgcn_s_barrier();            // buf^1 (tile t+1) ready for all
    }
  }

  #pragma unroll
  for (int m = 0; m < 8; ++m)
    #pragma unroll
    for (int n = 0; n < 4; ++n)
      #pragma unroll
      for (int j = 0; j < 4; ++j) {
        size_t off = (size_t)(bm0 + wm + m * 16 + g * 4 + j) * N + (bn0 + wn + n * 16 + q);
        if (OUTMODE == 1) ((float*)Cv)[off] = acc[m][n][j];
        else              ((u16*)Cv)[off]  = f2bf(acc[m][n][j]);
      }
}

// ---------------- RoPE (interleaved pairs, in-place on bf16) ----------------
__global__ __launch_bounds__(256) void rope_kernel(u16* __restrict__ t,
    const float* __restrict__ fc, const float* __restrict__ fs,
    int log2ppr, int total_pairs) {
  int i = blockIdx.x * 256 + threadIdx.x;
  if (i >= total_pairs) return;
  int fi = i & 63;
  int row = i >> log2ppr;           // b*S + s
  int pos = row & (S_ - 1);
  float c = fc[pos * 64 + fi], s = fs[pos * 64 + fi];
  unsigned* p = (unsigned*)(t + 2 * (size_t)i);
  unsigned v = *p;
  float x0 = bf2f((u16)(v & 0xffffu)), x1 = bf2f((u16)(v >> 16));
  float r0 = x0 * c - x1 * s, r1 = x0 * s + x1 * c;
  *p = (unsigned)f2bf(r0) | ((unsigned)f2bf(r1) << 16);
}

// ---------------- causal GQA flash attention (swapped-QK^T) ----------------
// grid (16, H, B) = 1024 blocks = 4/CU; block 256 = 4 waves; QT=64
// (16 q-rows/wave), pairing {31-p, p} -> uniform 33 K-iters/block.
// S^T = mfma(K_frag, Q_frag): each lane owns ONE q-col (l&15) with 16
// k-values in regs -> softmax = in-lane max/sum + 2 shfl (was 64 shfl +
// fstat LDS). P -> LDS as 4 x u16x4 vectorized writes (chunk-XOR swz).
// K single-buffered (R6: dbuf was null). Defer-max THR=16 (P<=4.1, bf16-safe).
// LDS 40KB -> 4 blocks/CU; launch_bounds (256,4) caps VGPR 128 (est ~104).
__global__ __launch_bounds__(256, 4) void attn_kernel(
    const u16* __restrict__ Qb, const u16* __restrict__ Kb,
    const u16* __restrict__ VTg, u16* __restrict__ Ob) {
  __shared__ __attribute__((aligned(16))) u16 SM[20480]; // 40KB
  u16* Ks = SM;            // [64][128] swz(row&7)
  u16* Vs = SM + 8192;     // [128][64] swz(row&7)
  u16* Ps = SM + 16384;    // 4 waves x [16 q][64 k], 16B-chunk ^ (q&7)
  const int pr = blockIdx.x;            // 0..15
  const int h = blockIdx.y, b = blockIdx.z;
  const int kvh = h >> 2;               // N_REP = 4
  const int tid = threadIdx.x, w = tid >> 6, l = tid & 63, g = l >> 4, ql = l & 15;
  const float SL2E = 0.08838834764831845f * 1.4426950408889634f;
  const u16* Qh = Qb + (size_t)b * S_ * NQ_ + h * HD_;
  const u16* Kh = Kb + ((size_t)b * S_ * KV_ + kvh) * HD_;
  const u16* Vh = VTg + (size_t)(b * KV_ + kvh) * (32 * 8192);
  u16* Oh = Ob + (size_t)b * S_ * NQ_ + h * HD_;

  for (int ph = 0; ph < 2; ++ph) {
    const int qt = ph ? pr : 31 - pr;
    __syncthreads();   // SM (epilogue scratch) free before restaging
    bf16x8 aq[4];
    #pragma unroll
    for (int kk = 0; kk < 4; ++kk)
      aq[kk] = *(const bf16x8*)(Qh + (size_t)(qt * 64 + w * 16 + ql) * NQ_ + kk * 32 + g * 8);

    f32x4 o[8] = {};
    float mrow = -3.0e38f, lrow = 0.f;

    const int nkt = qt + 1;
    for (int kt = 0; kt < nkt; ++kt) {
      #pragma unroll
      for (int p = 0; p < 4; ++p) {   // K: [64][128]
        int c = tid + p * 256;
        int row = c >> 4, slot = c & 15;
        GLDS16(Kh + (size_t)(kt * 64 + row) * (KV_ * HD_) + ((slot ^ (row & 7)) << 3), Ks + c * 8);
      }
      #pragma unroll
      for (int p = 0; p < 4; ++p) {   // V^T: [128][64] from contiguous 16KB tile
        int c = tid + p * 256;
        int row = c >> 3, slot = c & 7;
        GLDS16(Vh + (size_t)kt * 8192 + row * 64 + ((slot ^ (row & 7)) << 3), Vs + c * 8);
      }
      asm volatile("s_waitcnt vmcnt(0)" ::: "memory");
      __builtin_amdgcn_s_barrier();

      if (kt * 64 <= qt * 64 + w * 16 + 15) {   // wave-uniform activity gate
        // ---- S^T = K * Q^T ----
        f32x4 sc[4] = {};
        #pragma unroll
        for (int kk = 0; kk < 4; ++kk) {
          bf16x8 bk[4];
          #pragma unroll
          for (int n = 0; n < 4; ++n) {
            int row = n * 16 + ql;
            bk[n] = *(const bf16x8*)(Ks + row * 128 + (((kk * 4 + g) ^ (row & 7)) << 3));
          }
          #pragma unroll
          for (int n = 0; n < 4; ++n)
            sc[n] = mfma16(bk[n], aq[kk], sc[n]);
        }
        // ---- causal mask (diagonal tiles only); lane holds k=kt*64+n*16+g*4+j, q=ql ----
        const int qglob = qt * 64 + w * 16 + ql;
        if (kt * 64 + 63 > qt * 64 + w * 16) {
          #pragma unroll
          for (int n = 0; n < 4; ++n)
            #pragma unroll
            for (int j = 0; j < 4; ++j)
              if (kt * 64 + n * 16 + g * 4 + j > qglob) sc[n][j] = -3.0e38f;
        }
        // ---- online softmax: in-lane over 16 k-vals, then xor16/xor32 ----
        float mx = sc[0][0];
        #pragma unroll
        for (int n = 0; n < 4; ++n)
          #pragma unroll
          for (int j = 0; j < 4; ++j) mx = fmaxf(mx, sc[n][j]);
        mx = fmaxf(mx, __shfl_xor(mx, 16));
        mx = fmaxf(mx, __shfl_xor(mx, 32));
        if (!__all(mx - mrow <= 16.0f)) {      // defer-max: P bounded by 2^2.04
          float mnew = fmaxf(mrow, mx);
          float f = exp2f((mrow - mnew) * SL2E);
          lrow *= f;
          #pragma unroll
          for (int m = 0; m < 8; ++m) o[m] *= f;
          mrow = mnew;
        }
        float rs = 0.f;
        #pragma unroll
        for (int n = 0; n < 4; ++n)
          #pragma unroll
          for (int j = 0; j < 4; ++j) {
            float pv = exp2f((sc[n][j] - mrow) * SL2E);
            sc[n][j] = pv; rs += pv;
          }
        rs += __shfl_xor(rs, 16);
        rs += __shfl_xor(rs, 32);
        lrow += rs;
        // ---- P -> LDS: [16 q][64 k], 16B chunk ^ (q&7); 4 x u16x4 writes ----
        u16* Pw = Ps + w * 1024;
        #pragma unroll
        for (int n = 0; n < 4; ++n) {
          u16x4 pk;
          #pragma unroll
          for (int j = 0; j < 4; ++j) pk[j] = f2bft(sc[n][j]);
          *(u16x4*)(Pw + ql * 64 + (((n * 2 + (g >> 1)) ^ (ql & 7)) << 3) + (g & 1) * 4) = pk;
        }
        // ---- PV: O^T = V^T * P^T ----
        #pragma unroll
        for (int kk2 = 0; kk2 < 2; ++kk2) {
          bf16x8 bp = *(const bf16x8*)(Pw + ql * 64 + (((kk2 * 4 + g) ^ (ql & 7)) << 3));
          #pragma unroll
          for (int m = 0; m < 8; ++m) {
            int row = m * 16 + ql;
            bf16x8 av = *(const bf16x8*)(Vs + row * 64 + (((kk2 * 4 + g) ^ (row & 7)) << 3));
            o[m] = mfma16(av, bp, o[m]);
          }
        }
      }
      __builtin_amdgcn_s_barrier();   // all waves done with Ks/Vs before restage
    }
    // ---- epilogue: normalize (lane-local l), transpose via LDS, store ----
    __syncthreads();
    u16* OS = SM; // [64][136]
    float linv = 1.0f / lrow;
    #pragma unroll
    for (int m = 0; m < 8; ++m)
      #pragma unroll
      for (int j = 0; j < 4; ++j)
        OS[(w * 16 + ql) * 136 + m * 16 + g * 4 + j] = f2bf(o[m][j] * linv);
    __syncthreads();
    #pragma unroll
    for (int p = 0; p < 4; ++p) {
      int c = tid + p * 256;
      int row = c >> 4, col8 = c & 15;
      u16x8 d = *(const u16x8*)(OS + row * 136 + col8 * 8);
      *(u16x8*)(Oh + (size_t)(qt * 64 + row) * NQ_ + col8 * 8) = d;
    }
  }
}

extern "C" void kernel_launch(void* const* d_in, const int* in_sizes, int n_in,
                              void* d_out, int out_size, void* d_ws, size_t ws_size,
                              hipStream_t stream) {
  const float* x  = (const float*)d_in[0];
  const float* fc = (const float*)d_in[1];
  const float* fs = (const float*)d_in[2];
  // d_in[3] = mask (causal, applied analytically)
  const float* wq = (const float*)d_in[4];
  const float* wk = (const float*)d_in[5];
  const float* wv = (const float*)d_in[6];
  const float* wo = (const float*)d_in[7];

  char* ws = (char*)d_ws;
  u16* xb  = (u16*)(ws + 0);          // 33554432 B
  u16* wqT = (u16*)(ws + 33554432);   // 33554432
  u16* wkT = (u16*)(ws + 67108864);   // 8388608   (wkT||wvT = [2048][4096])
  u16* wvT = (u16*)(ws + 75497472);   // 8388608
  u16* woT = (u16*)(ws + 83886080);   // 33554432
  u16* qb  = (u16*)(ws + 117440512);  // 33554432
  u16* kb  = (u16*)(ws + 150994944);  // 8388608
  u16* vtg = (u16*)(ws + 159383552);  // 8388608  (V^T tiled: [B][KV][32][128][64])
  u16* ob  = (u16*)(ws + 167772160);  // 33554432  -> total 201326592
  if (ws_size < 201326592u) return;

  cvt_bf16<<<(M_ * D_) / (8 * 256), 256, 0, stream>>>(x, xb, M_ * D_);
  tcvt<<<dim3(NQ_ / 32, D_ / 32), 256, 0, stream>>>(wq, wqT, D_, NQ_);
  tcvt<<<dim3(NKV_ / 32, D_ / 32), 256, 0, stream>>>(wk, wkT, D_, NKV_);
  tcvt<<<dim3(NKV_ / 32, D_ / 32), 256, 0, stream>>>(wv, wvT, D_, NKV_);
  tcvt<<<dim3(D_ / 32, NQ_ / 32), 256, 0, stream>>>(wo, woT, NQ_, D_);

  gemm256<0><<<dim3(NQ_ / 256, M_ / 256), 512, 131072, stream>>>(xb, wqT, qb, M_, NQ_, D_);
  // fused K+V projection: N=2048 (wkT||wvT contiguous)
  gemm_bt<3><<<dim3(2048 / 128, M_ / 128), 256, 0, stream>>>(xb, wkT, kb, vtg, M_, 2048, D_);

  rope_kernel<<<(M_ * NQ_ / 2) / 256, 256, 0, stream>>>(qb, fc, fs, 11, M_ * NQ_ / 2);
  rope_kernel<<<(M_ * NKV_ / 2) / 256, 256, 0, stream>>>(kb, fc, fs, 9, M_ * NKV_ / 2);

  attn_kernel<<<dim3(16, H_, B_), 256, 0, stream>>>(qb, kb, vtg, ob);

  gemm256<1><<<dim3(D_ / 256, M_ / 256), 512, 131072, stream>>>(ob, woT, d_out, M_, D_, NQ_);
}

// Round 8
// 583.917 us; speedup vs baseline: 2.2837x; 1.0064x over previous
//
#include <hip/hip_runtime.h>
#include <stdint.h>

#define B_ 2
#define S_ 2048
#define D_ 4096
#define H_ 32
#define KV_ 8
#define HD_ 128
#define M_ (B_*S_)          // 4096 rows (b*S+s)
#define NQ_ (H_*HD_)        // 4096
#define NKV_ (KV_*HD_)      // 1024

typedef unsigned short u16;
typedef __bf16 bf16x8 __attribute__((ext_vector_type(8)));
typedef float f32x4 __attribute__((ext_vector_type(4)));
typedef u16 u16x8 __attribute__((ext_vector_type(8)));
typedef u16 u16x4 __attribute__((ext_vector_type(4)));

__device__ __forceinline__ u16 f2bf(float f) {
  union { float f; unsigned u; } v; v.f = f;
  unsigned r = v.u + 0x7fffu + ((v.u >> 16) & 1u);
  return (u16)(r >> 16);
}
__device__ __forceinline__ u16 f2bft(float f) {  // truncating (for P; values in [0,4.2])
  union { float f; unsigned u; } v; v.f = f;
  return (u16)(v.u >> 16);
}
__device__ __forceinline__ float bf2f(u16 u) {
  union { unsigned u; float f; } v; v.u = ((unsigned)u) << 16;
  return v.f;
}
__device__ __forceinline__ f32x4 mfma16(bf16x8 a, bf16x8 b, f32x4 c) {
  return __builtin_amdgcn_mfma_f32_16x16x32_bf16(a, b, c, 0, 0, 0);
}

#define GLDS16(gp, lp) __builtin_amdgcn_global_load_lds( \
    (const __attribute__((address_space(1))) unsigned int*)(gp), \
    (__attribute__((address_space(3))) unsigned int*)(lp), 16, 0, 0)

// ---------------- fp32 -> bf16 convert (vectorized) ----------------
__global__ __launch_bounds__(256) void cvt_bf16(const float* __restrict__ in,
                                                u16* __restrict__ out, int n) {
  int i = (blockIdx.x * 256 + threadIdx.x) * 8;
  if (i >= n) return;
  float4 a = *(const float4*)(in + i);
  float4 b = *(const float4*)(in + i + 4);
  u16x8 o;
  o[0]=f2bf(a.x); o[1]=f2bf(a.y); o[2]=f2bf(a.z); o[3]=f2bf(a.w);
  o[4]=f2bf(b.x); o[5]=f2bf(b.y); o[6]=f2bf(b.z); o[7]=f2bf(b.w);
  *(u16x8*)(out + i) = o;
}

// ---------------- transpose + convert: out[c][r] = in[r][c] ----------------
__global__ __launch_bounds__(256) void tcvt(const float* __restrict__ in,
                                            u16* __restrict__ out, int R, int C) {
  __shared__ __attribute__((aligned(16))) u16 tile[32][33];
  int c0 = blockIdx.x * 32, r0 = blockIdx.y * 32;
  int tx = threadIdx.x & 31, ty = threadIdx.x >> 5;
  #pragma unroll
  for (int j = ty; j < 32; j += 8)
    tile[j][tx] = f2bf(in[(size_t)(r0 + j) * C + c0 + tx]);
  __syncthreads();
  #pragma unroll
  for (int j = ty; j < 32; j += 8)
    out[(size_t)(c0 + j) * R + r0 + tx] = tile[tx][j];
}

// ---------------- 128x128 GEMM (m97-style) ----------------
// OUTMODE 3 = fused K/V projection: N=2048; col<1024 -> K row-major (Cv, stride
// 1024); col>=1024 -> V^T 16KB-tiled (Cv2): off = ((b*KV+kv)*32+t)*8192+d*64+s6.
template<int OUTMODE>
__global__ __launch_bounds__(256) void gemm_bt(const u16* __restrict__ A,
    const u16* __restrict__ BT, void* __restrict__ Cv, void* __restrict__ Cv2,
    int M, int N, int K) {
  __shared__ __attribute__((aligned(16))) u16 As[128 * 32];
  __shared__ __attribute__((aligned(16))) u16 Bs[128 * 32];
  const int tid = threadIdx.x;
  const int bn0 = blockIdx.x * 128, bm0 = blockIdx.y * 128;
  const int w = tid >> 6, l = tid & 63, g = l >> 4, q = l & 15;
  const int wm = (w >> 1) * 64, wn = (w & 1) * 64;
  f32x4 acc[4][4] = {};
  for (int kt = 0; kt < K; kt += 32) {
    __syncthreads();
    #pragma unroll
    for (int p = 0; p < 2; ++p) {
      int c = tid + p * 256;
      int row = c >> 2, slot = c & 3;
      int srck = (slot ^ ((row >> 1) & 3)) << 3;
      GLDS16(A + (size_t)(bm0 + row) * K + kt + srck, As + c * 8);
      GLDS16(BT + (size_t)(bn0 + row) * K + kt + srck, Bs + c * 8);
    }
    __syncthreads();
    bf16x8 af[4], bfr[4];
    #pragma unroll
    for (int m = 0; m < 4; ++m) {
      int row = wm + m * 16 + q;
      af[m] = *(const bf16x8*)(As + row * 32 + ((g ^ ((row >> 1) & 3)) << 3));
    }
    #pragma unroll
    for (int n = 0; n < 4; ++n) {
      int row = wn + n * 16 + q;
      bfr[n] = *(const bf16x8*)(Bs + row * 32 + ((g ^ ((row >> 1) & 3)) << 3));
    }
    #pragma unroll
    for (int m = 0; m < 4; ++m)
      #pragma unroll
      for (int n = 0; n < 4; ++n)
        acc[m][n] = mfma16(af[m], bfr[n], acc[m][n]);
  }
  #pragma unroll
  for (int m = 0; m < 4; ++m)
    #pragma unroll
    for (int n = 0; n < 4; ++n) {
      if (OUTMODE == 3) {
        int row0 = bm0 + wm + m * 16 + g * 4;
        int col  = bn0 + wn + n * 16 + q;
        if (col < 1024) {
          #pragma unroll
          for (int j = 0; j < 4; ++j)
            ((u16*)Cv)[(size_t)(row0 + j) * 1024 + col] = f2bf(acc[m][n][j]);
        } else {
          int c2 = col - 1024;
          u16x4 pk;
          #pragma unroll
          for (int j = 0; j < 4; ++j) pk[j] = f2bf(acc[m][n][j]);
          size_t off = ((size_t)((row0 >> 11) * KV_ + (c2 >> 7)) * 32 + ((row0 >> 6) & 31)) * 8192
                     + (size_t)(c2 & 127) * 64 + (row0 & 63);
          *(u16x4*)((u16*)Cv2 + off) = pk;
        }
      } else {
        #pragma unroll
        for (int j = 0; j < 4; ++j) {
          size_t off = (size_t)(bm0 + wm + m * 16 + g * 4 + j) * N + (bn0 + wn + n * 16 + q);
          if (OUTMODE == 1) ((float*)Cv)[off] = acc[m][n][j];
          else              ((u16*)Cv)[off]  = f2bf(acc[m][n][j]);
        }
      }
    }
}

// ------- 256x256 GEMM, 4-phase fine interleave + counted vmcnt (T2+T3+T4+T5) -------
// 512 thr = 8 waves (2M x 4N), per-wave 128x64, BK=64, dbuf 128KiB (1 block/CU).
// Per K-tile, 4 phases x {ds_read subtile; bar; lgkm(0); SB(0); prio1; 16 MFMA;
// prio0; bar}. Reads: P0 a_ks0[8]+b_ks0{n01}; P1 b_ks0{n23}; P2 a_ks1[8]+
// b_ks1{n01}; P3 b_ks1{n23}. STAGE_A(t+2) at P3-start (A(t) dead after P2's
// lgkm+bar); STAGE_B(t+2)+vmcnt(8) after P3 (B(t) dead after P3's lgkm+bar) --
// loads never drain to 0 in steady state. 1D grid + bijective XCD swizzle.
template<int OUTMODE>
__global__ __launch_bounds__(512, 2) void gemm256(const u16* __restrict__ A,
    const u16* __restrict__ BT, void* __restrict__ Cv, int M, int N, int K) {
  extern __shared__ __attribute__((aligned(16))) u16 DL[];  // 2 x (A 16384 + B 16384)
  const int tid = threadIdx.x;
  const int nbx = N >> 8;
  const int cpx = gridDim.x >> 3;                 // grid % 8 == 0
  const int swzb = (blockIdx.x & 7) * cpx + (blockIdx.x >> 3);
  const int bn0 = (swzb % nbx) << 8, bm0 = (swzb / nbx) << 8;
  const int l = tid & 63, g = l >> 4, q = l & 15;
  const int w = tid >> 6;
  const int wm = (w >> 2) * 128, wn = (w & 3) * 64;
  const int nt = K >> 6;
  f32x4 acc[8][4] = {};

  auto STAGE_A = [&](int t, int buf) {
    const int kt = t << 6;
    u16* Ad = DL + buf * 32768;
    #pragma unroll
    for (int p = 0; p < 4; ++p) {
      int idx = tid + p * 512;
      int row = idx >> 3, slot = idx & 7;
      GLDS16(A + (size_t)(bm0 + row) * K + kt + ((slot ^ (row & 7)) << 3), Ad + idx * 8);
    }
  };
  auto STAGE_B = [&](int t, int buf) {
    const int kt = t << 6;
    u16* Bd = DL + buf * 32768 + 16384;
    #pragma unroll
    for (int p = 0; p < 4; ++p) {
      int idx = tid + p * 512;
      int row = idx >> 3, slot = idx & 7;
      GLDS16(BT + (size_t)(bn0 + row) * K + kt + ((slot ^ (row & 7)) << 3), Bd + idx * 8);
    }
  };

  STAGE_A(0, 0); STAGE_B(0, 0);
  STAGE_A(1, 1); STAGE_B(1, 1);
  asm volatile("s_waitcnt vmcnt(8)" ::: "memory");   // tile0 landed; tile1 in flight
  __builtin_amdgcn_s_barrier();

  for (int t = 0; t < nt; ++t) {
    const int buf = t & 1;
    const u16* As = DL + buf * 32768;
    const u16* Bs = As + 16384;
    bf16x8 a[8];

    // ---- P0: a_ks0[8] + b_ks0{n0,n1} ----
    {
      bf16x8 b0, b1;
      #pragma unroll
      for (int m = 0; m < 8; ++m) {
        int row = wm + m * 16 + q;
        a[m] = *(const bf16x8*)(As + row * 64 + ((g ^ (row & 7)) << 3));
      }
      { int row = wn + q;      b0 = *(const bf16x8*)(Bs + row * 64 + ((g ^ (row & 7)) << 3)); }
      { int row = wn + 16 + q; b1 = *(const bf16x8*)(Bs + row * 64 + ((g ^ (row & 7)) << 3)); }
      __builtin_amdgcn_s_barrier();
      asm volatile("s_waitcnt lgkmcnt(0)" ::: "memory");
      __builtin_amdgcn_sched_barrier(0);
      __builtin_amdgcn_s_setprio(1);
      #pragma unroll
      for (int m = 0; m < 8; ++m) {
        acc[m][0] = mfma16(a[m], b0, acc[m][0]);
        acc[m][1] = mfma16(a[m], b1, acc[m][1]);
      }
      __builtin_amdgcn_s_setprio(0);
      __builtin_amdgcn_s_barrier();
    }
    // ---- P1: b_ks0{n2,n3} ----
    {
      bf16x8 b2, b3;
      { int row = wn + 32 + q; b2 = *(const bf16x8*)(Bs + row * 64 + ((g ^ (row & 7)) << 3)); }
      { int row = wn + 48 + q; b3 = *(const bf16x8*)(Bs + row * 64 + ((g ^ (row & 7)) << 3)); }
      __builtin_amdgcn_s_barrier();
      asm volatile("s_waitcnt lgkmcnt(0)" ::: "memory");
      __builtin_amdgcn_sched_barrier(0);
      __builtin_amdgcn_s_setprio(1);
      #pragma unroll
      for (int m = 0; m < 8; ++m) {
        acc[m][2] = mfma16(a[m], b2, acc[m][2]);
        acc[m][3] = mfma16(a[m], b3, acc[m][3]);
      }
      __builtin_amdgcn_s_setprio(0);
      __builtin_amdgcn_s_barrier();
    }
    // ---- P2: a_ks1[8] + b_ks1{n0,n1} ----
    {
      bf16x8 b0, b1;
      #pragma unroll
      for (int m = 0; m < 8; ++m) {
        int row = wm + m * 16 + q;
        a[m] = *(const bf16x8*)(As + row * 64 + (((4 + g) ^ (row & 7)) << 3));
      }
      { int row = wn + q;      b0 = *(const bf16x8*)(Bs + row * 64 + (((4 + g) ^ (row & 7)) << 3)); }
      { int row = wn + 16 + q; b1 = *(const bf16x8*)(Bs + row * 64 + (((4 + g) ^ (row & 7)) << 3)); }
      __builtin_amdgcn_s_barrier();
      asm volatile("s_waitcnt lgkmcnt(0)" ::: "memory");
      __builtin_amdgcn_sched_barrier(0);
      __builtin_amdgcn_s_setprio(1);
      #pragma unroll
      for (int m = 0; m < 8; ++m) {
        acc[m][0] = mfma16(a[m], b0, acc[m][0]);
        acc[m][1] = mfma16(a[m], b1, acc[m][1]);
      }
      __builtin_amdgcn_s_setprio(0);
      __builtin_amdgcn_s_barrier();
    }
    // ---- P3: STAGE_A(t+2); b_ks1{n2,n3} ----
    {
      if (t + 2 < nt) STAGE_A(t + 2, buf);
      bf16x8 b2, b3;
      { int row = wn + 32 + q; b2 = *(const bf16x8*)(Bs + row * 64 + (((4 + g) ^ (row & 7)) << 3)); }
      { int row = wn + 48 + q; b3 = *(const bf16x8*)(Bs + row * 64 + (((4 + g) ^ (row & 7)) << 3)); }
      __builtin_amdgcn_s_barrier();
      asm volatile("s_waitcnt lgkmcnt(0)" ::: "memory");
      __builtin_amdgcn_sched_barrier(0);
      __builtin_amdgcn_s_setprio(1);
      #pragma unroll
      for (int m = 0; m < 8; ++m) {
        acc[m][2] = mfma16(a[m], b2, acc[m][2]);
        acc[m][3] = mfma16(a[m], b3, acc[m][3]);
      }
      __builtin_amdgcn_s_setprio(0);
      __builtin_amdgcn_s_barrier();
    }
    // ---- tile end: STAGE_B(t+2), counted vmcnt, gate buf(t+1) ----
    if (t + 1 < nt) {
      if (t + 2 < nt) {
        STAGE_B(t + 2, buf);
        asm volatile("s_waitcnt vmcnt(8)" ::: "memory");  // tile t+1 fully landed
      } else {
        asm volatile("s_waitcnt vmcnt(0)" ::: "memory");
      }
      __builtin_amdgcn_s_barrier();
    }
  }

  #pragma unroll
  for (int m = 0; m < 8; ++m)
    #pragma unroll
    for (int n = 0; n < 4; ++n)
      #pragma unroll
      for (int j = 0; j < 4; ++j) {
        size_t off = (size_t)(bm0 + wm + m * 16 + g * 4 + j) * N + (bn0 + wn + n * 16 + q);
        if (OUTMODE == 1) ((float*)Cv)[off] = acc[m][n][j];
        else              ((u16*)Cv)[off]  = f2bf(acc[m][n][j]);
      }
}

// ---------------- RoPE (interleaved pairs, in-place on bf16) ----------------
__global__ __launch_bounds__(256) void rope_kernel(u16* __restrict__ t,
    const float* __restrict__ fc, const float* __restrict__ fs,
    int log2ppr, int total_pairs) {
  int i = blockIdx.x * 256 + threadIdx.x;
  if (i >= total_pairs) return;
  int fi = i & 63;
  int row = i >> log2ppr;           // b*S + s
  int pos = row & (S_ - 1);
  float c = fc[pos * 64 + fi], s = fs[pos * 64 + fi];
  unsigned* p = (unsigned*)(t + 2 * (size_t)i);
  unsigned v = *p;
  float x0 = bf2f((u16)(v & 0xffffu)), x1 = bf2f((u16)(v >> 16));
  float r0 = x0 * c - x1 * s, r1 = x0 * s + x1 * c;
  *p = (unsigned)f2bf(r0) | ((unsigned)f2bf(r1) << 16);
}

// ---------------- causal GQA flash attention (swapped-QK^T) ----------------
// grid (16, H, B) = 1024 blocks = 4/CU; block 256 = 4 waves; QT=64
// (16 q-rows/wave), pairing {31-p, p} -> uniform 33 K-iters/block.
// S^T = mfma(K_frag, Q_frag): each lane owns ONE q-col (l&15) with 16
// k-values in regs -> softmax = in-lane max/sum + 2 shfl. P -> LDS as
// 4 x u16x4 vectorized writes (chunk-XOR swz). Defer-max THR=16.
// LDS 40KB -> 4 blocks/CU; launch_bounds (256,4).
__global__ __launch_bounds__(256, 4) void attn_kernel(
    const u16* __restrict__ Qb, const u16* __restrict__ Kb,
    const u16* __restrict__ VTg, u16* __restrict__ Ob) {
  __shared__ __attribute__((aligned(16))) u16 SM[20480]; // 40KB
  u16* Ks = SM;            // [64][128] swz(row&7)
  u16* Vs = SM + 8192;     // [128][64] swz(row&7)
  u16* Ps = SM + 16384;    // 4 waves x [16 q][64 k], 16B-chunk ^ (q&7)
  const int pr = blockIdx.x;            // 0..15
  const int h = blockIdx.y, b = blockIdx.z;
  const int kvh = h >> 2;               // N_REP = 4
  const int tid = threadIdx.x, w = tid >> 6, l = tid & 63, g = l >> 4, ql = l & 15;
  const float SL2E = 0.08838834764831845f * 1.4426950408889634f;
  const u16* Qh = Qb + (size_t)b * S_ * NQ_ + h * HD_;
  const u16* Kh = Kb + ((size_t)b * S_ * KV_ + kvh) * HD_;
  const u16* Vh = VTg + (size_t)(b * KV_ + kvh) * (32 * 8192);
  u16* Oh = Ob + (size_t)b * S_ * NQ_ + h * HD_;

  for (int ph = 0; ph < 2; ++ph) {
    const int qt = ph ? pr : 31 - pr;
    __syncthreads();   // SM (epilogue scratch) free before restaging
    bf16x8 aq[4];
    #pragma unroll
    for (int kk = 0; kk < 4; ++kk)
      aq[kk] = *(const bf16x8*)(Qh + (size_t)(qt * 64 + w * 16 + ql) * NQ_ + kk * 32 + g * 8);

    f32x4 o[8] = {};
    float mrow = -3.0e38f, lrow = 0.f;

    const int nkt = qt + 1;
    for (int kt = 0; kt < nkt; ++kt) {
      #pragma unroll
      for (int p = 0; p < 4; ++p) {   // K: [64][128]
        int c = tid + p * 256;
        int row = c >> 4, slot = c & 15;
        GLDS16(Kh + (size_t)(kt * 64 + row) * (KV_ * HD_) + ((slot ^ (row & 7)) << 3), Ks + c * 8);
      }
      #pragma unroll
      for (int p = 0; p < 4; ++p) {   // V^T: [128][64] from contiguous 16KB tile
        int c = tid + p * 256;
        int row = c >> 3, slot = c & 7;
        GLDS16(Vh + (size_t)kt * 8192 + row * 64 + ((slot ^ (row & 7)) << 3), Vs + c * 8);
      }
      asm volatile("s_waitcnt vmcnt(0)" ::: "memory");
      __builtin_amdgcn_s_barrier();

      if (kt * 64 <= qt * 64 + w * 16 + 15) {   // wave-uniform activity gate
        // ---- S^T = K * Q^T ----
        f32x4 sc[4] = {};
        #pragma unroll
        for (int kk = 0; kk < 4; ++kk) {
          bf16x8 bk[4];
          #pragma unroll
          for (int n = 0; n < 4; ++n) {
            int row = n * 16 + ql;
            bk[n] = *(const bf16x8*)(Ks + row * 128 + (((kk * 4 + g) ^ (row & 7)) << 3));
          }
          #pragma unroll
          for (int n = 0; n < 4; ++n)
            sc[n] = mfma16(bk[n], aq[kk], sc[n]);
        }
        // ---- causal mask (diagonal tiles only); lane holds k=kt*64+n*16+g*4+j, q=ql ----
        const int qglob = qt * 64 + w * 16 + ql;
        if (kt * 64 + 63 > qt * 64 + w * 16) {
          #pragma unroll
          for (int n = 0; n < 4; ++n)
            #pragma unroll
            for (int j = 0; j < 4; ++j)
              if (kt * 64 + n * 16 + g * 4 + j > qglob) sc[n][j] = -3.0e38f;
        }
        // ---- online softmax: in-lane over 16 k-vals, then xor16/xor32 ----
        float mx = sc[0][0];
        #pragma unroll
        for (int n = 0; n < 4; ++n)
          #pragma unroll
          for (int j = 0; j < 4; ++j) mx = fmaxf(mx, sc[n][j]);
        mx = fmaxf(mx, __shfl_xor(mx, 16));
        mx = fmaxf(mx, __shfl_xor(mx, 32));
        if (!__all(mx - mrow <= 16.0f)) {      // defer-max: P bounded by 2^2.04
          float mnew = fmaxf(mrow, mx);
          float f = exp2f((mrow - mnew) * SL2E);
          lrow *= f;
          #pragma unroll
          for (int m = 0; m < 8; ++m) o[m] *= f;
          mrow = mnew;
        }
        float rs = 0.f;
        #pragma unroll
        for (int n = 0; n < 4; ++n)
          #pragma unroll
          for (int j = 0; j < 4; ++j) {
            float pv = exp2f((sc[n][j] - mrow) * SL2E);
            sc[n][j] = pv; rs += pv;
          }
        rs += __shfl_xor(rs, 16);
        rs += __shfl_xor(rs, 32);
        lrow += rs;
        // ---- P -> LDS: [16 q][64 k], 16B chunk ^ (q&7); 4 x u16x4 writes ----
        u16* Pw = Ps + w * 1024;
        #pragma unroll
        for (int n = 0; n < 4; ++n) {
          u16x4 pk;
          #pragma unroll
          for (int j = 0; j < 4; ++j) pk[j] = f2bft(sc[n][j]);
          *(u16x4*)(Pw + ql * 64 + (((n * 2 + (g >> 1)) ^ (ql & 7)) << 3) + (g & 1) * 4) = pk;
        }
        // ---- PV: O^T = V^T * P^T ----
        #pragma unroll
        for (int kk2 = 0; kk2 < 2; ++kk2) {
          bf16x8 bp = *(const bf16x8*)(Pw + ql * 64 + (((kk2 * 4 + g) ^ (ql & 7)) << 3));
          #pragma unroll
          for (int m = 0; m < 8; ++m) {
            int row = m * 16 + ql;
            bf16x8 av = *(const bf16x8*)(Vs + row * 64 + (((kk2 * 4 + g) ^ (row & 7)) << 3));
            o[m] = mfma16(av, bp, o[m]);
          }
        }
      }
      __builtin_amdgcn_s_barrier();   // all waves done with Ks/Vs before restage
    }
    // ---- epilogue: normalize (lane-local l), transpose via LDS, store ----
    __syncthreads();
    u16* OS = SM; // [64][136]
    float linv = 1.0f / lrow;
    #pragma unroll
    for (int m = 0; m < 8; ++m)
      #pragma unroll
      for (int j = 0; j < 4; ++j)
        OS[(w * 16 + ql) * 136 + m * 16 + g * 4 + j] = f2bf(o[m][j] * linv);
    __syncthreads();
    #pragma unroll
    for (int p = 0; p < 4; ++p) {
      int c = tid + p * 256;
      int row = c >> 4, col8 = c & 15;
      u16x8 d = *(const u16x8*)(OS + row * 136 + col8 * 8);
      *(u16x8*)(Oh + (size_t)(qt * 64 + row) * NQ_ + col8 * 8) = d;
    }
  }
}

extern "C" void kernel_launch(void* const* d_in, const int* in_sizes, int n_in,
                              void* d_out, int out_size, void* d_ws, size_t ws_size,
                              hipStream_t stream) {
  const float* x  = (const float*)d_in[0];
  const float* fc = (const float*)d_in[1];
  const float* fs = (const float*)d_in[2];
  // d_in[3] = mask (causal, applied analytically)
  const float* wq = (const float*)d_in[4];
  const float* wk = (const float*)d_in[5];
  const float* wv = (const float*)d_in[6];
  const float* wo = (const float*)d_in[7];

  char* ws = (char*)d_ws;
  u16* xb  = (u16*)(ws + 0);          // 33554432 B
  u16* wqT = (u16*)(ws + 33554432);   // 33554432
  u16* wkT = (u16*)(ws + 67108864);   // 8388608   (wkT||wvT = [2048][4096])
  u16* wvT = (u16*)(ws + 75497472);   // 8388608
  u16* woT = (u16*)(ws + 83886080);   // 33554432
  u16* qb  = (u16*)(ws + 117440512);  // 33554432
  u16* kb  = (u16*)(ws + 150994944);  // 8388608
  u16* vtg = (u16*)(ws + 159383552);  // 8388608  (V^T tiled: [B][KV][32][128][64])
  u16* ob  = (u16*)(ws + 167772160);  // 33554432  -> total 201326592
  if (ws_size < 201326592u) return;

  cvt_bf16<<<(M_ * D_) / (8 * 256), 256, 0, stream>>>(x, xb, M_ * D_);
  tcvt<<<dim3(NQ_ / 32, D_ / 32), 256, 0, stream>>>(wq, wqT, D_, NQ_);
  tcvt<<<dim3(NKV_ / 32, D_ / 32), 256, 0, stream>>>(wk, wkT, D_, NKV_);
  tcvt<<<dim3(NKV_ / 32, D_ / 32), 256, 0, stream>>>(wv, wvT, D_, NKV_);
  tcvt<<<dim3(D_ / 32, NQ_ / 32), 256, 0, stream>>>(wo, woT, NQ_, D_);

  gemm256<0><<<(NQ_ / 256) * (M_ / 256), 512, 131072, stream>>>(xb, wqT, qb, M_, NQ_, D_);
  // fused K+V projection: N=2048 (wkT||wvT contiguous)
  gemm_bt<3><<<dim3(2048 / 128, M_ / 128), 256, 0, stream>>>(xb, wkT, kb, vtg, M_, 2048, D_);

  rope_kernel<<<(M_ * NQ_ / 2) / 256, 256, 0, stream>>>(qb, fc, fs, 11, M_ * NQ_ / 2);
  rope_kernel<<<(M_ * NKV_ / 2) / 256, 256, 0, stream>>>(kb, fc, fs, 9, M_ * NKV_ / 2);

  attn_kernel<<<dim3(16, H_, B_), 256, 0, stream>>>(qb, kb, vtg, ob);

  gemm256<1><<<(D_ / 256) * (M_ / 256), 512, 131072, stream>>>(ob, woT, d_out, M_, D_, NQ_);
}

// Round 9
// 581.041 us; speedup vs baseline: 2.2950x; 1.0049x over previous
//
#include <hip/hip_runtime.h>
#include <stdint.h>

#define B_ 2
#define S_ 2048
#define D_ 4096
#define H_ 32
#define KV_ 8
#define HD_ 128
#define M_ (B_*S_)          // 4096 rows (b*S+s)
#define NQ_ (H_*HD_)        // 4096
#define NKV_ (KV_*HD_)      // 1024

typedef unsigned short u16;
typedef __bf16 bf16x8 __attribute__((ext_vector_type(8)));
typedef float f32x4 __attribute__((ext_vector_type(4)));
typedef u16 u16x8 __attribute__((ext_vector_type(8)));
typedef u16 u16x4 __attribute__((ext_vector_type(4)));

__device__ __forceinline__ u16 f2bf(float f) {
  union { float f; unsigned u; } v; v.f = f;
  unsigned r = v.u + 0x7fffu + ((v.u >> 16) & 1u);
  return (u16)(r >> 16);
}
__device__ __forceinline__ u16 f2bft(float f) {  // truncating (for P; values in [0,4.2])
  union { float f; unsigned u; } v; v.f = f;
  return (u16)(v.u >> 16);
}
__device__ __forceinline__ float bf2f(u16 u) {
  union { unsigned u; float f; } v; v.u = ((unsigned)u) << 16;
  return v.f;
}
__device__ __forceinline__ f32x4 mfma16(bf16x8 a, bf16x8 b, f32x4 c) {
  return __builtin_amdgcn_mfma_f32_16x16x32_bf16(a, b, c, 0, 0, 0);
}

#define GLDS16(gp, lp) __builtin_amdgcn_global_load_lds( \
    (const __attribute__((address_space(1))) unsigned int*)(gp), \
    (__attribute__((address_space(3))) unsigned int*)(lp), 16, 0, 0)

// ---------------- fp32 -> bf16 convert (vectorized) ----------------
__global__ __launch_bounds__(256) void cvt_bf16(const float* __restrict__ in,
                                                u16* __restrict__ out, int n) {
  int i = (blockIdx.x * 256 + threadIdx.x) * 8;
  if (i >= n) return;
  float4 a = *(const float4*)(in + i);
  float4 b = *(const float4*)(in + i + 4);
  u16x8 o;
  o[0]=f2bf(a.x); o[1]=f2bf(a.y); o[2]=f2bf(a.z); o[3]=f2bf(a.w);
  o[4]=f2bf(b.x); o[5]=f2bf(b.y); o[6]=f2bf(b.z); o[7]=f2bf(b.w);
  *(u16x8*)(out + i) = o;
}

// ---------------- transpose + convert: out[c][r] = in[r][c] ----------------
__global__ __launch_bounds__(256) void tcvt(const float* __restrict__ in,
                                            u16* __restrict__ out, int R, int C) {
  __shared__ __attribute__((aligned(16))) u16 tile[32][33];
  int c0 = blockIdx.x * 32, r0 = blockIdx.y * 32;
  int tx = threadIdx.x & 31, ty = threadIdx.x >> 5;
  #pragma unroll
  for (int j = ty; j < 32; j += 8)
    tile[j][tx] = f2bf(in[(size_t)(r0 + j) * C + c0 + tx]);
  __syncthreads();
  #pragma unroll
  for (int j = ty; j < 32; j += 8)
    out[(size_t)(c0 + j) * R + r0 + tx] = tile[tx][j];
}

// ---------------- 128x128 GEMM (m97-style) ----------------
// OUTMODE 3 = fused K/V projection: N=2048; col<1024 -> K row-major (Cv, stride
// 1024); col>=1024 -> V^T 16KB-tiled (Cv2): off = ((b*KV+kv)*32+t)*8192+d*64+s6.
template<int OUTMODE>
__global__ __launch_bounds__(256) void gemm_bt(const u16* __restrict__ A,
    const u16* __restrict__ BT, void* __restrict__ Cv, void* __restrict__ Cv2,
    int M, int N, int K) {
  __shared__ __attribute__((aligned(16))) u16 As[128 * 32];
  __shared__ __attribute__((aligned(16))) u16 Bs[128 * 32];
  const int tid = threadIdx.x;
  const int bn0 = blockIdx.x * 128, bm0 = blockIdx.y * 128;
  const int w = tid >> 6, l = tid & 63, g = l >> 4, q = l & 15;
  const int wm = (w >> 1) * 64, wn = (w & 1) * 64;
  f32x4 acc[4][4] = {};
  for (int kt = 0; kt < K; kt += 32) {
    __syncthreads();
    #pragma unroll
    for (int p = 0; p < 2; ++p) {
      int c = tid + p * 256;
      int row = c >> 2, slot = c & 3;
      int srck = (slot ^ ((row >> 1) & 3)) << 3;
      GLDS16(A + (size_t)(bm0 + row) * K + kt + srck, As + c * 8);
      GLDS16(BT + (size_t)(bn0 + row) * K + kt + srck, Bs + c * 8);
    }
    __syncthreads();
    bf16x8 af[4], bfr[4];
    #pragma unroll
    for (int m = 0; m < 4; ++m) {
      int row = wm + m * 16 + q;
      af[m] = *(const bf16x8*)(As + row * 32 + ((g ^ ((row >> 1) & 3)) << 3));
    }
    #pragma unroll
    for (int n = 0; n < 4; ++n) {
      int row = wn + n * 16 + q;
      bfr[n] = *(const bf16x8*)(Bs + row * 32 + ((g ^ ((row >> 1) & 3)) << 3));
    }
    #pragma unroll
    for (int m = 0; m < 4; ++m)
      #pragma unroll
      for (int n = 0; n < 4; ++n)
        acc[m][n] = mfma16(af[m], bfr[n], acc[m][n]);
  }
  #pragma unroll
  for (int m = 0; m < 4; ++m)
    #pragma unroll
    for (int n = 0; n < 4; ++n) {
      if (OUTMODE == 3) {
        int row0 = bm0 + wm + m * 16 + g * 4;
        int col  = bn0 + wn + n * 16 + q;
        if (col < 1024) {
          #pragma unroll
          for (int j = 0; j < 4; ++j)
            ((u16*)Cv)[(size_t)(row0 + j) * 1024 + col] = f2bf(acc[m][n][j]);
        } else {
          int c2 = col - 1024;
          u16x4 pk;
          #pragma unroll
          for (int j = 0; j < 4; ++j) pk[j] = f2bf(acc[m][n][j]);
          size_t off = ((size_t)((row0 >> 11) * KV_ + (c2 >> 7)) * 32 + ((row0 >> 6) & 31)) * 8192
                     + (size_t)(c2 & 127) * 64 + (row0 & 63);
          *(u16x4*)((u16*)Cv2 + off) = pk;
        }
      } else {
        #pragma unroll
        for (int j = 0; j < 4; ++j) {
          size_t off = (size_t)(bm0 + wm + m * 16 + g * 4 + j) * N + (bn0 + wn + n * 16 + q);
          if (OUTMODE == 1) ((float*)Cv)[off] = acc[m][n][j];
          else              ((u16*)Cv)[off]  = f2bf(acc[m][n][j]);
        }
      }
    }
}

// ------- 256x256 GEMM, 3-buf rotation + cross-tile register pipeline -------
// 512 thr = 8 waves (2M x 4N), per-wave 128x64, BK=32, LDS 96 KiB = 3 bufs x
// (A[256][32] + B[256][32]). R5/R8 both 40% MfmaUtil: with 2 bufs, tile t+1's
// reads are gated behind tile t's end vmcnt -> reads/MFMA serialize per tile.
// Here tile t+1's data lands a tile early (staged t-2..t-1, gated at t-1), so
// during MFMA(t) we prefetch A(t+1) into regs (aN[8]); b(t) read fresh (4).
// Body: STAGE(t+2); vmcnt(4); s_barrier; b(t) ds_reads; aN(t+1) ds_reads;
// 32 MFMA on aC. One barrier + one counted vmcnt per tile; plain-C++ ds_reads
// let the compiler emit precise lgkm counts (no inline-asm read hazard).
// Swizzle: 4 chunks/row, chunk ^= (row>>1)&3 (2-way max = free), matched on
// staging source. Regs ~112 VGPR + 128 AGPR -> 2 waves/SIMD.
template<int OUTMODE>
__global__ __launch_bounds__(512, 2) void gemm256(const u16* __restrict__ A,
    const u16* __restrict__ BT, void* __restrict__ Cv, int M, int N, int K) {
  extern __shared__ __attribute__((aligned(16))) u16 DL[];  // 3 x 16384 u16
  const int tid = threadIdx.x;
  const int nbx = N >> 8;
  const int cpx = gridDim.x >> 3;                 // grid % 8 == 0
  const int swzb = (blockIdx.x & 7) * cpx + (blockIdx.x >> 3);
  const int bn0 = (swzb % nbx) << 8, bm0 = (swzb / nbx) << 8;
  const int l = tid & 63, g = l >> 4, q = l & 15;
  const int w = tid >> 6;
  const int wm = (w >> 2) * 128, wn = (w & 3) * 64;
  const int nt = K >> 5;   // BK = 32
  f32x4 acc[8][4] = {};

  // staging source addrs (pre-swizzled k-chunk), 4 gloads/tile
  const int srow = tid >> 2, schunk = tid & 3;
  const int ssw = (schunk ^ ((srow >> 1) & 3)) << 3;
  const u16* gA0 = A  + (size_t)(bm0 + srow) * K + ssw;
  const u16* gA1 = gA0 + (size_t)128 * K;
  const u16* gB0 = BT + (size_t)(bn0 + srow) * K + ssw;
  const u16* gB1 = gB0 + (size_t)128 * K;

  auto STAGE = [&](int t) {
    const int kt = t << 5;
    u16* d = DL + (t % 3) * 16384;
    GLDS16(gA0 + kt, d + tid * 8);
    GLDS16(gA1 + kt, d + 4096 + tid * 8);
    GLDS16(gB0 + kt, d + 8192 + tid * 8);
    GLDS16(gB1 + kt, d + 12288 + tid * 8);
  };

  // per-wave LDS read bases (chunk swizzle folded; constant across m/n)
  const u16* ra = DL + (wm + q) * 32 + ((g ^ (((wm + q) >> 1) & 3)) << 3);
  const u16* rb = DL + 8192 + (wn + q) * 32 + ((g ^ (((wn + q) >> 1) & 3)) << 3);

  bf16x8 aC[8], aN[8];

  STAGE(0); STAGE(1);
  asm volatile("s_waitcnt vmcnt(4)" ::: "memory");   // tile0 landed; tile1 in flight
  __builtin_amdgcn_s_barrier();
  #pragma unroll
  for (int m = 0; m < 8; ++m) aC[m] = *(const bf16x8*)(ra + m * 512);  // buf0

  auto TILE = [&](int t, bf16x8 (&ac)[8], bf16x8 (&an)[8]) {
    if (t + 2 < nt) {
      STAGE(t + 2);
      asm volatile("s_waitcnt vmcnt(4)" ::: "memory");  // tile t+1 fully landed
    } else {
      asm volatile("s_waitcnt vmcnt(0)" ::: "memory");
    }
    __builtin_amdgcn_s_barrier();
    const u16* pb = rb + (t % 3) * 16384;
    bf16x8 b0 = *(const bf16x8*)(pb);
    bf16x8 b1 = *(const bf16x8*)(pb + 512);
    bf16x8 b2 = *(const bf16x8*)(pb + 1024);
    bf16x8 b3 = *(const bf16x8*)(pb + 1536);
    if (t + 1 < nt) {
      const u16* pa = ra + ((t + 1) % 3) * 16384;
      #pragma unroll
      for (int m = 0; m < 8; ++m) an[m] = *(const bf16x8*)(pa + m * 512);
    }
    #pragma unroll
    for (int m = 0; m < 8; ++m) {
      acc[m][0] = mfma16(ac[m], b0, acc[m][0]);
      acc[m][1] = mfma16(ac[m], b1, acc[m][1]);
      acc[m][2] = mfma16(ac[m], b2, acc[m][2]);
      acc[m][3] = mfma16(ac[m], b3, acc[m][3]);
    }
  };

  for (int t = 0; t < nt; t += 2) {
    TILE(t,     aC, aN);
    TILE(t + 1, aN, aC);
  }

  #pragma unroll
  for (int m = 0; m < 8; ++m)
    #pragma unroll
    for (int n = 0; n < 4; ++n)
      #pragma unroll
      for (int j = 0; j < 4; ++j) {
        size_t off = (size_t)(bm0 + wm + m * 16 + g * 4 + j) * N + (bn0 + wn + n * 16 + q);
        if (OUTMODE == 1) ((float*)Cv)[off] = acc[m][n][j];
        else              ((u16*)Cv)[off]  = f2bf(acc[m][n][j]);
      }
}

// ---------------- RoPE (interleaved pairs, in-place on bf16) ----------------
__global__ __launch_bounds__(256) void rope_kernel(u16* __restrict__ t,
    const float* __restrict__ fc, const float* __restrict__ fs,
    int log2ppr, int total_pairs) {
  int i = blockIdx.x * 256 + threadIdx.x;
  if (i >= total_pairs) return;
  int fi = i & 63;
  int row = i >> log2ppr;           // b*S + s
  int pos = row & (S_ - 1);
  float c = fc[pos * 64 + fi], s = fs[pos * 64 + fi];
  unsigned* p = (unsigned*)(t + 2 * (size_t)i);
  unsigned v = *p;
  float x0 = bf2f((u16)(v & 0xffffu)), x1 = bf2f((u16)(v >> 16));
  float r0 = x0 * c - x1 * s, r1 = x0 * s + x1 * c;
  *p = (unsigned)f2bf(r0) | ((unsigned)f2bf(r1) << 16);
}

// ---------------- causal GQA flash attention (swapped-QK^T) ----------------
// grid (16, H, B) = 1024 blocks = 4/CU; block 256 = 4 waves; QT=64
// (16 q-rows/wave), pairing {31-p, p} -> uniform 33 K-iters/block.
// S^T = mfma(K_frag, Q_frag): each lane owns ONE q-col (l&15) with 16
// k-values in regs -> softmax = in-lane max/sum + 2 shfl. P -> LDS as
// 4 x u16x4 vectorized writes (chunk-XOR swz). Defer-max THR=16.
// LDS 40KB -> 4 blocks/CU; launch_bounds (256,4).
__global__ __launch_bounds__(256, 4) void attn_kernel(
    const u16* __restrict__ Qb, const u16* __restrict__ Kb,
    const u16* __restrict__ VTg, u16* __restrict__ Ob) {
  __shared__ __attribute__((aligned(16))) u16 SM[20480]; // 40KB
  u16* Ks = SM;            // [64][128] swz(row&7)
  u16* Vs = SM + 8192;     // [128][64] swz(row&7)
  u16* Ps = SM + 16384;    // 4 waves x [16 q][64 k], 16B-chunk ^ (q&7)
  const int pr = blockIdx.x;            // 0..15
  const int h = blockIdx.y, b = blockIdx.z;
  const int kvh = h >> 2;               // N_REP = 4
  const int tid = threadIdx.x, w = tid >> 6, l = tid & 63, g = l >> 4, ql = l & 15;
  const float SL2E = 0.08838834764831845f * 1.4426950408889634f;
  const u16* Qh = Qb + (size_t)b * S_ * NQ_ + h * HD_;
  const u16* Kh = Kb + ((size_t)b * S_ * KV_ + kvh) * HD_;
  const u16* Vh = VTg + (size_t)(b * KV_ + kvh) * (32 * 8192);
  u16* Oh = Ob + (size_t)b * S_ * NQ_ + h * HD_;

  for (int ph = 0; ph < 2; ++ph) {
    const int qt = ph ? pr : 31 - pr;
    __syncthreads();   // SM (epilogue scratch) free before restaging
    bf16x8 aq[4];
    #pragma unroll
    for (int kk = 0; kk < 4; ++kk)
      aq[kk] = *(const bf16x8*)(Qh + (size_t)(qt * 64 + w * 16 + ql) * NQ_ + kk * 32 + g * 8);

    f32x4 o[8] = {};
    float mrow = -3.0e38f, lrow = 0.f;

    const int nkt = qt + 1;
    for (int kt = 0; kt < nkt; ++kt) {
      #pragma unroll
      for (int p = 0; p < 4; ++p) {   // K: [64][128]
        int c = tid + p * 256;
        int row = c >> 4, slot = c & 15;
        GLDS16(Kh + (size_t)(kt * 64 + row) * (KV_ * HD_) + ((slot ^ (row & 7)) << 3), Ks + c * 8);
      }
      #pragma unroll
      for (int p = 0; p < 4; ++p) {   // V^T: [128][64] from contiguous 16KB tile
        int c = tid + p * 256;
        int row = c >> 3, slot = c & 7;
        GLDS16(Vh + (size_t)kt * 8192 + row * 64 + ((slot ^ (row & 7)) << 3), Vs + c * 8);
      }
      asm volatile("s_waitcnt vmcnt(0)" ::: "memory");
      __builtin_amdgcn_s_barrier();

      if (kt * 64 <= qt * 64 + w * 16 + 15) {   // wave-uniform activity gate
        // ---- S^T = K * Q^T ----
        f32x4 sc[4] = {};
        #pragma unroll
        for (int kk = 0; kk < 4; ++kk) {
          bf16x8 bk[4];
          #pragma unroll
          for (int n = 0; n < 4; ++n) {
            int row = n * 16 + ql;
            bk[n] = *(const bf16x8*)(Ks + row * 128 + (((kk * 4 + g) ^ (row & 7)) << 3));
          }
          #pragma unroll
          for (int n = 0; n < 4; ++n)
            sc[n] = mfma16(bk[n], aq[kk], sc[n]);
        }
        // ---- causal mask (diagonal tiles only); lane holds k=kt*64+n*16+g*4+j, q=ql ----
        const int qglob = qt * 64 + w * 16 + ql;
        if (kt * 64 + 63 > qt * 64 + w * 16) {
          #pragma unroll
          for (int n = 0; n < 4; ++n)
            #pragma unroll
            for (int j = 0; j < 4; ++j)
              if (kt * 64 + n * 16 + g * 4 + j > qglob) sc[n][j] = -3.0e38f;
        }
        // ---- online softmax: in-lane over 16 k-vals, then xor16/xor32 ----
        float mx = sc[0][0];
        #pragma unroll
        for (int n = 0; n < 4; ++n)
          #pragma unroll
          for (int j = 0; j < 4; ++j) mx = fmaxf(mx, sc[n][j]);
        mx = fmaxf(mx, __shfl_xor(mx, 16));
        mx = fmaxf(mx, __shfl_xor(mx, 32));
        if (!__all(mx - mrow <= 16.0f)) {      // defer-max: P bounded by 2^2.04
          float mnew = fmaxf(mrow, mx);
          float f = exp2f((mrow - mnew) * SL2E);
          lrow *= f;
          #pragma unroll
          for (int m = 0; m < 8; ++m) o[m] *= f;
          mrow = mnew;
        }
        float rs = 0.f;
        #pragma unroll
        for (int n = 0; n < 4; ++n)
          #pragma unroll
          for (int j = 0; j < 4; ++j) {
            float pv = exp2f((sc[n][j] - mrow) * SL2E);
            sc[n][j] = pv; rs += pv;
          }
        rs += __shfl_xor(rs, 16);
        rs += __shfl_xor(rs, 32);
        lrow += rs;
        // ---- P -> LDS: [16 q][64 k], 16B chunk ^ (q&7); 4 x u16x4 writes ----
        u16* Pw = Ps + w * 1024;
        #pragma unroll
        for (int n = 0; n < 4; ++n) {
          u16x4 pk;
          #pragma unroll
          for (int j = 0; j < 4; ++j) pk[j] = f2bft(sc[n][j]);
          *(u16x4*)(Pw + ql * 64 + (((n * 2 + (g >> 1)) ^ (ql & 7)) << 3) + (g & 1) * 4) = pk;
        }
        // ---- PV: O^T = V^T * P^T ----
        #pragma unroll
        for (int kk2 = 0; kk2 < 2; ++kk2) {
          bf16x8 bp = *(const bf16x8*)(Pw + ql * 64 + (((kk2 * 4 + g) ^ (ql & 7)) << 3));
          #pragma unroll
          for (int m = 0; m < 8; ++m) {
            int row = m * 16 + ql;
            bf16x8 av = *(const bf16x8*)(Vs + row * 64 + (((kk2 * 4 + g) ^ (row & 7)) << 3));
            o[m] = mfma16(av, bp, o[m]);
          }
        }
      }
      __builtin_amdgcn_s_barrier();   // all waves done with Ks/Vs before restage
    }
    // ---- epilogue: normalize (lane-local l), transpose via LDS, store ----
    __syncthreads();
    u16* OS = SM; // [64][136]
    float linv = 1.0f / lrow;
    #pragma unroll
    for (int m = 0; m < 8; ++m)
      #pragma unroll
      for (int j = 0; j < 4; ++j)
        OS[(w * 16 + ql) * 136 + m * 16 + g * 4 + j] = f2bf(o[m][j] * linv);
    __syncthreads();
    #pragma unroll
    for (int p = 0; p < 4; ++p) {
      int c = tid + p * 256;
      int row = c >> 4, col8 = c & 15;
      u16x8 d = *(const u16x8*)(OS + row * 136 + col8 * 8);
      *(u16x8*)(Oh + (size_t)(qt * 64 + row) * NQ_ + col8 * 8) = d;
    }
  }
}

extern "C" void kernel_launch(void* const* d_in, const int* in_sizes, int n_in,
                              void* d_out, int out_size, void* d_ws, size_t ws_size,
                              hipStream_t stream) {
  const float* x  = (const float*)d_in[0];
  const float* fc = (const float*)d_in[1];
  const float* fs = (const float*)d_in[2];
  // d_in[3] = mask (causal, applied analytically)
  const float* wq = (const float*)d_in[4];
  const float* wk = (const float*)d_in[5];
  const float* wv = (const float*)d_in[6];
  const float* wo = (const float*)d_in[7];

  char* ws = (char*)d_ws;
  u16* xb  = (u16*)(ws + 0);          // 33554432 B
  u16* wqT = (u16*)(ws + 33554432);   // 33554432
  u16* wkT = (u16*)(ws + 67108864);   // 8388608   (wkT||wvT = [2048][4096])
  u16* wvT = (u16*)(ws + 75497472);   // 8388608
  u16* woT = (u16*)(ws + 83886080);   // 33554432
  u16* qb  = (u16*)(ws + 117440512);  // 33554432
  u16* kb  = (u16*)(ws + 150994944);  // 8388608
  u16* vtg = (u16*)(ws + 159383552);  // 8388608  (V^T tiled: [B][KV][32][128][64])
  u16* ob  = (u16*)(ws + 167772160);  // 33554432  -> total 201326592
  if (ws_size < 201326592u) return;

  cvt_bf16<<<(M_ * D_) / (8 * 256), 256, 0, stream>>>(x, xb, M_ * D_);
  tcvt<<<dim3(NQ_ / 32, D_ / 32), 256, 0, stream>>>(wq, wqT, D_, NQ_);
  tcvt<<<dim3(NKV_ / 32, D_ / 32), 256, 0, stream>>>(wk, wkT, D_, NKV_);
  tcvt<<<dim3(NKV_ / 32, D_ / 32), 256, 0, stream>>>(wv, wvT, D_, NKV_);
  tcvt<<<dim3(D_ / 32, NQ_ / 32), 256, 0, stream>>>(wo, woT, NQ_, D_);

  gemm256<0><<<(NQ_ / 256) * (M_ / 256), 512, 98304, stream>>>(xb, wqT, qb, M_, NQ_, D_);
  // fused K+V projection: N=2048 (wkT||wvT contiguous)
  gemm_bt<3><<<dim3(2048 / 128, M_ / 128), 256, 0, stream>>>(xb, wkT, kb, vtg, M_, 2048, D_);

  rope_kernel<<<(M_ * NQ_ / 2) / 256, 256, 0, stream>>>(qb, fc, fs, 11, M_ * NQ_ / 2);
  rope_kernel<<<(M_ * NKV_ / 2) / 256, 256, 0, stream>>>(kb, fc, fs, 9, M_ * NKV_ / 2);

  attn_kernel<<<dim3(16, H_, B_), 256, 0, stream>>>(qb, kb, vtg, ob);

  gemm256<1><<<(D_ / 256) * (M_ / 256), 512, 98304, stream>>>(ob, woT, d_out, M_, D_, NQ_);
}

// Round 10
// 580.360 us; speedup vs baseline: 2.2977x; 1.0012x over previous
//
#include <hip/hip_runtime.h>
#include <stdint.h>

#define B_ 2
#define S_ 2048
#define D_ 4096
#define H_ 32
#define KV_ 8
#define HD_ 128
#define M_ (B_*S_)          // 4096 rows (b*S+s)
#define NQ_ (H_*HD_)        // 4096
#define NKV_ (KV_*HD_)      // 1024

typedef unsigned short u16;
typedef __bf16 bf16x8 __attribute__((ext_vector_type(8)));
typedef float f32x4 __attribute__((ext_vector_type(4)));
typedef u16 u16x8 __attribute__((ext_vector_type(8)));
typedef u16 u16x4 __attribute__((ext_vector_type(4)));

__device__ __forceinline__ u16 f2bf(float f) {
  union { float f; unsigned u; } v; v.f = f;
  unsigned r = v.u + 0x7fffu + ((v.u >> 16) & 1u);
  return (u16)(r >> 16);
}
__device__ __forceinline__ u16 f2bft(float f) {  // truncating (for P; values in [0,4.2])
  union { float f; unsigned u; } v; v.f = f;
  return (u16)(v.u >> 16);
}
__device__ __forceinline__ float bf2f(u16 u) {
  union { unsigned u; float f; } v; v.u = ((unsigned)u) << 16;
  return v.f;
}
__device__ __forceinline__ f32x4 mfma16(bf16x8 a, bf16x8 b, f32x4 c) {
  return __builtin_amdgcn_mfma_f32_16x16x32_bf16(a, b, c, 0, 0, 0);
}

#define GLDS16(gp, lp) __builtin_amdgcn_global_load_lds( \
    (const __attribute__((address_space(1))) unsigned int*)(gp), \
    (__attribute__((address_space(3))) unsigned int*)(lp), 16, 0, 0)

// ---------------- fp32 -> bf16 convert (vectorized) ----------------
__global__ __launch_bounds__(256) void cvt_bf16(const float* __restrict__ in,
                                                u16* __restrict__ out, int n) {
  int i = (blockIdx.x * 256 + threadIdx.x) * 8;
  if (i >= n) return;
  float4 a = *(const float4*)(in + i);
  float4 b = *(const float4*)(in + i + 4);
  u16x8 o;
  o[0]=f2bf(a.x); o[1]=f2bf(a.y); o[2]=f2bf(a.z); o[3]=f2bf(a.w);
  o[4]=f2bf(b.x); o[5]=f2bf(b.y); o[6]=f2bf(b.z); o[7]=f2bf(b.w);
  *(u16x8*)(out + i) = o;
}

// ---------------- transpose + convert: out[c][r] = in[r][c] ----------------
__global__ __launch_bounds__(256) void tcvt(const float* __restrict__ in,
                                            u16* __restrict__ out, int R, int C) {
  __shared__ __attribute__((aligned(16))) u16 tile[32][33];
  int c0 = blockIdx.x * 32, r0 = blockIdx.y * 32;
  int tx = threadIdx.x & 31, ty = threadIdx.x >> 5;
  #pragma unroll
  for (int j = ty; j < 32; j += 8)
    tile[j][tx] = f2bf(in[(size_t)(r0 + j) * C + c0 + tx]);
  __syncthreads();
  #pragma unroll
  for (int j = ty; j < 32; j += 8)
    out[(size_t)(c0 + j) * R + r0 + tx] = tile[tx][j];
}

// ---------------- 128x128 GEMM (m97-style) ----------------
// OUTMODE 3 = fused K/V projection: N=2048; col<1024 -> K row-major (Cv, stride
// 1024); col>=1024 -> V^T 16KB-tiled (Cv2): off = ((b*KV+kv)*32+t)*8192+d*64+s6.
template<int OUTMODE>
__global__ __launch_bounds__(256) void gemm_bt(const u16* __restrict__ A,
    const u16* __restrict__ BT, void* __restrict__ Cv, void* __restrict__ Cv2,
    int M, int N, int K) {
  __shared__ __attribute__((aligned(16))) u16 As[128 * 32];
  __shared__ __attribute__((aligned(16))) u16 Bs[128 * 32];
  const int tid = threadIdx.x;
  const int bn0 = blockIdx.x * 128, bm0 = blockIdx.y * 128;
  const int w = tid >> 6, l = tid & 63, g = l >> 4, q = l & 15;
  const int wm = (w >> 1) * 64, wn = (w & 1) * 64;
  f32x4 acc[4][4] = {};
  for (int kt = 0; kt < K; kt += 32) {
    __syncthreads();
    #pragma unroll
    for (int p = 0; p < 2; ++p) {
      int c = tid + p * 256;
      int row = c >> 2, slot = c & 3;
      int srck = (slot ^ ((row >> 1) & 3)) << 3;
      GLDS16(A + (size_t)(bm0 + row) * K + kt + srck, As + c * 8);
      GLDS16(BT + (size_t)(bn0 + row) * K + kt + srck, Bs + c * 8);
    }
    __syncthreads();
    bf16x8 af[4], bfr[4];
    #pragma unroll
    for (int m = 0; m < 4; ++m) {
      int row = wm + m * 16 + q;
      af[m] = *(const bf16x8*)(As + row * 32 + ((g ^ ((row >> 1) & 3)) << 3));
    }
    #pragma unroll
    for (int n = 0; n < 4; ++n) {
      int row = wn + n * 16 + q;
      bfr[n] = *(const bf16x8*)(Bs + row * 32 + ((g ^ ((row >> 1) & 3)) << 3));
    }
    #pragma unroll
    for (int m = 0; m < 4; ++m)
      #pragma unroll
      for (int n = 0; n < 4; ++n)
        acc[m][n] = mfma16(af[m], bfr[n], acc[m][n]);
  }
  #pragma unroll
  for (int m = 0; m < 4; ++m)
    #pragma unroll
    for (int n = 0; n < 4; ++n) {
      if (OUTMODE == 3) {
        int row0 = bm0 + wm + m * 16 + g * 4;
        int col  = bn0 + wn + n * 16 + q;
        if (col < 1024) {
          #pragma unroll
          for (int j = 0; j < 4; ++j)
            ((u16*)Cv)[(size_t)(row0 + j) * 1024 + col] = f2bf(acc[m][n][j]);
        } else {
          int c2 = col - 1024;
          u16x4 pk;
          #pragma unroll
          for (int j = 0; j < 4; ++j) pk[j] = f2bf(acc[m][n][j]);
          size_t off = ((size_t)((row0 >> 11) * KV_ + (c2 >> 7)) * 32 + ((row0 >> 6) & 31)) * 8192
                     + (size_t)(c2 & 127) * 64 + (row0 & 63);
          *(u16x4*)((u16*)Cv2 + off) = pk;
        }
      } else {
        #pragma unroll
        for (int j = 0; j < 4; ++j) {
          size_t off = (size_t)(bm0 + wm + m * 16 + g * 4 + j) * N + (bn0 + wn + n * 16 + q);
          if (OUTMODE == 1) ((float*)Cv)[off] = acc[m][n][j];
          else              ((u16*)Cv)[off]  = f2bf(acc[m][n][j]);
        }
      }
    }
}

// ------- 256x256 GEMM, 3-buf rotation + FULL cross-tile register pipeline -------
// 512 thr = 8 waves (2M x 4N), per-wave 128x64, BK=32, LDS 96 KiB = 3 bufs.
// R9 prefetched A(t+1) into regs; B(t) was still read pre-MFMA each tile
// (~170cy serial). Now BOTH A(t+1) and B(t+1) prefetch during MFMA(t):
// body = STAGE(t+2); vmcnt(4); s_barrier; [12 ds_reads -> aN/bN];
// setprio(1); 32 MFMA on aC/bC; setprio(0).  Zero reads on the MFMA
// critical path; lgkm waits only on last tile's prefetches (long done).
// Buffers disjoint: read (t+1)%3, stage (t+2)%3. vmcnt(4)+barrier publishes
// tile t+1 across waves (per-wave vmcnt + barrier = all waves' loads done).
// Regs ~240 (acc 128 AGPR + aC/aN 64 + bC/bN 32 + addr) under the 256 cap
// at 2 waves/SIMD. Swizzle: chunk ^= (row>>1)&3, matched on staging source
// (conflicts measured 0).
template<int OUTMODE>
__global__ __launch_bounds__(512, 2) void gemm256(const u16* __restrict__ A,
    const u16* __restrict__ BT, void* __restrict__ Cv, int M, int N, int K) {
  extern __shared__ __attribute__((aligned(16))) u16 DL[];  // 3 x 16384 u16
  const int tid = threadIdx.x;
  const int nbx = N >> 8;
  const int cpx = gridDim.x >> 3;                 // grid % 8 == 0
  const int swzb = (blockIdx.x & 7) * cpx + (blockIdx.x >> 3);
  const int bn0 = (swzb % nbx) << 8, bm0 = (swzb / nbx) << 8;
  const int l = tid & 63, g = l >> 4, q = l & 15;
  const int w = tid >> 6;
  const int wm = (w >> 2) * 128, wn = (w & 3) * 64;
  const int nt = K >> 5;   // BK = 32
  f32x4 acc[8][4] = {};

  // staging source addrs (pre-swizzled k-chunk), 4 gloads/tile
  const int srow = tid >> 2, schunk = tid & 3;
  const int ssw = (schunk ^ ((srow >> 1) & 3)) << 3;
  const u16* gA0 = A  + (size_t)(bm0 + srow) * K + ssw;
  const u16* gA1 = gA0 + (size_t)128 * K;
  const u16* gB0 = BT + (size_t)(bn0 + srow) * K + ssw;
  const u16* gB1 = gB0 + (size_t)128 * K;

  auto STAGE = [&](int t) {
    const int kt = t << 5;
    u16* d = DL + (t % 3) * 16384;
    GLDS16(gA0 + kt, d + tid * 8);
    GLDS16(gA1 + kt, d + 4096 + tid * 8);
    GLDS16(gB0 + kt, d + 8192 + tid * 8);
    GLDS16(gB1 + kt, d + 12288 + tid * 8);
  };

  // per-wave LDS read bases (chunk swizzle folded; constant across m/n)
  const u16* ra = DL + (wm + q) * 32 + ((g ^ (((wm + q) >> 1) & 3)) << 3);
  const u16* rb = DL + 8192 + (wn + q) * 32 + ((g ^ (((wn + q) >> 1) & 3)) << 3);

  bf16x8 aC[8], aN[8], bC[4], bN[4];

  STAGE(0); STAGE(1);
  asm volatile("s_waitcnt vmcnt(4)" ::: "memory");   // tile0 landed; tile1 in flight
  __builtin_amdgcn_s_barrier();
  #pragma unroll
  for (int m = 0; m < 8; ++m) aC[m] = *(const bf16x8*)(ra + m * 512);  // buf0
  #pragma unroll
  for (int n = 0; n < 4; ++n) bC[n] = *(const bf16x8*)(rb + n * 512);

  auto TILE = [&](int t, bf16x8 (&ac)[8], bf16x8 (&bc)[4],
                         bf16x8 (&an)[8], bf16x8 (&bn)[4]) {
    if (t + 2 < nt) {
      STAGE(t + 2);
      asm volatile("s_waitcnt vmcnt(4)" ::: "memory");  // tile t+1 fully landed
    } else {
      asm volatile("s_waitcnt vmcnt(0)" ::: "memory");
    }
    __builtin_amdgcn_s_barrier();
    if (t + 1 < nt) {
      const u16* pa = ra + ((t + 1) % 3) * 16384;
      const u16* pb = rb + ((t + 1) % 3) * 16384;
      #pragma unroll
      for (int m = 0; m < 8; ++m) an[m] = *(const bf16x8*)(pa + m * 512);
      #pragma unroll
      for (int n = 0; n < 4; ++n) bn[n] = *(const bf16x8*)(pb + n * 512);
    }
    __builtin_amdgcn_s_setprio(1);
    #pragma unroll
    for (int m = 0; m < 8; ++m) {
      acc[m][0] = mfma16(ac[m], bc[0], acc[m][0]);
      acc[m][1] = mfma16(ac[m], bc[1], acc[m][1]);
      acc[m][2] = mfma16(ac[m], bc[2], acc[m][2]);
      acc[m][3] = mfma16(ac[m], bc[3], acc[m][3]);
    }
    __builtin_amdgcn_s_setprio(0);
  };

  for (int t = 0; t < nt; t += 2) {
    TILE(t,     aC, bC, aN, bN);
    TILE(t + 1, aN, bN, aC, bC);
  }

  #pragma unroll
  for (int m = 0; m < 8; ++m)
    #pragma unroll
    for (int n = 0; n < 4; ++n)
      #pragma unroll
      for (int j = 0; j < 4; ++j) {
        size_t off = (size_t)(bm0 + wm + m * 16 + g * 4 + j) * N + (bn0 + wn + n * 16 + q);
        if (OUTMODE == 1) ((float*)Cv)[off] = acc[m][n][j];
        else              ((u16*)Cv)[off]  = f2bf(acc[m][n][j]);
      }
}

// ---------------- RoPE (interleaved pairs, in-place on bf16) ----------------
__global__ __launch_bounds__(256) void rope_kernel(u16* __restrict__ t,
    const float* __restrict__ fc, const float* __restrict__ fs,
    int log2ppr, int total_pairs) {
  int i = blockIdx.x * 256 + threadIdx.x;
  if (i >= total_pairs) return;
  int fi = i & 63;
  int row = i >> log2ppr;           // b*S + s
  int pos = row & (S_ - 1);
  float c = fc[pos * 64 + fi], s = fs[pos * 64 + fi];
  unsigned* p = (unsigned*)(t + 2 * (size_t)i);
  unsigned v = *p;
  float x0 = bf2f((u16)(v & 0xffffu)), x1 = bf2f((u16)(v >> 16));
  float r0 = x0 * c - x1 * s, r1 = x0 * s + x1 * c;
  *p = (unsigned)f2bf(r0) | ((unsigned)f2bf(r1) << 16);
}

// ---------------- causal GQA flash attention (swapped-QK^T) ----------------
// grid (16, H, B) = 1024 blocks = 4/CU; block 256 = 4 waves; QT=64
// (16 q-rows/wave), pairing {31-p, p} -> uniform 33 K-iters/block.
// S^T = mfma(K_frag, Q_frag): each lane owns ONE q-col (l&15) with 16
// k-values in regs -> softmax = in-lane max/sum + 2 shfl. P -> LDS as
// 4 x u16x4 vectorized writes (chunk-XOR swz). Defer-max THR=16.
// LDS 40KB -> 4 blocks/CU; launch_bounds (256,4).
__global__ __launch_bounds__(256, 4) void attn_kernel(
    const u16* __restrict__ Qb, const u16* __restrict__ Kb,
    const u16* __restrict__ VTg, u16* __restrict__ Ob) {
  __shared__ __attribute__((aligned(16))) u16 SM[20480]; // 40KB
  u16* Ks = SM;            // [64][128] swz(row&7)
  u16* Vs = SM + 8192;     // [128][64] swz(row&7)
  u16* Ps = SM + 16384;    // 4 waves x [16 q][64 k], 16B-chunk ^ (q&7)
  const int pr = blockIdx.x;            // 0..15
  const int h = blockIdx.y, b = blockIdx.z;
  const int kvh = h >> 2;               // N_REP = 4
  const int tid = threadIdx.x, w = tid >> 6, l = tid & 63, g = l >> 4, ql = l & 15;
  const float SL2E = 0.08838834764831845f * 1.4426950408889634f;
  const u16* Qh = Qb + (size_t)b * S_ * NQ_ + h * HD_;
  const u16* Kh = Kb + ((size_t)b * S_ * KV_ + kvh) * HD_;
  const u16* Vh = VTg + (size_t)(b * KV_ + kvh) * (32 * 8192);
  u16* Oh = Ob + (size_t)b * S_ * NQ_ + h * HD_;

  for (int ph = 0; ph < 2; ++ph) {
    const int qt = ph ? pr : 31 - pr;
    __syncthreads();   // SM (epilogue scratch) free before restaging
    bf16x8 aq[4];
    #pragma unroll
    for (int kk = 0; kk < 4; ++kk)
      aq[kk] = *(const bf16x8*)(Qh + (size_t)(qt * 64 + w * 16 + ql) * NQ_ + kk * 32 + g * 8);

    f32x4 o[8] = {};
    float mrow = -3.0e38f, lrow = 0.f;

    const int nkt = qt + 1;
    for (int kt = 0; kt < nkt; ++kt) {
      #pragma unroll
      for (int p = 0; p < 4; ++p) {   // K: [64][128]
        int c = tid + p * 256;
        int row = c >> 4, slot = c & 15;
        GLDS16(Kh + (size_t)(kt * 64 + row) * (KV_ * HD_) + ((slot ^ (row & 7)) << 3), Ks + c * 8);
      }
      #pragma unroll
      for (int p = 0; p < 4; ++p) {   // V^T: [128][64] from contiguous 16KB tile
        int c = tid + p * 256;
        int row = c >> 3, slot = c & 7;
        GLDS16(Vh + (size_t)kt * 8192 + row * 64 + ((slot ^ (row & 7)) << 3), Vs + c * 8);
      }
      asm volatile("s_waitcnt vmcnt(0)" ::: "memory");
      __builtin_amdgcn_s_barrier();

      if (kt * 64 <= qt * 64 + w * 16 + 15) {   // wave-uniform activity gate
        // ---- S^T = K * Q^T ----
        f32x4 sc[4] = {};
        #pragma unroll
        for (int kk = 0; kk < 4; ++kk) {
          bf16x8 bk[4];
          #pragma unroll
          for (int n = 0; n < 4; ++n) {
            int row = n * 16 + ql;
            bk[n] = *(const bf16x8*)(Ks + row * 128 + (((kk * 4 + g) ^ (row & 7)) << 3));
          }
          #pragma unroll
          for (int n = 0; n < 4; ++n)
            sc[n] = mfma16(bk[n], aq[kk], sc[n]);
        }
        // ---- causal mask (diagonal tiles only); lane holds k=kt*64+n*16+g*4+j, q=ql ----
        const int qglob = qt * 64 + w * 16 + ql;
        if (kt * 64 + 63 > qt * 64 + w * 16) {
          #pragma unroll
          for (int n = 0; n < 4; ++n)
            #pragma unroll
            for (int j = 0; j < 4; ++j)
              if (kt * 64 + n * 16 + g * 4 + j > qglob) sc[n][j] = -3.0e38f;
        }
        // ---- online softmax: in-lane over 16 k-vals, then xor16/xor32 ----
        float mx = sc[0][0];
        #pragma unroll
        for (int n = 0; n < 4; ++n)
          #pragma unroll
          for (int j = 0; j < 4; ++j) mx = fmaxf(mx, sc[n][j]);
        mx = fmaxf(mx, __shfl_xor(mx, 16));
        mx = fmaxf(mx, __shfl_xor(mx, 32));
        if (!__all(mx - mrow <= 16.0f)) {      // defer-max: P bounded by 2^2.04
          float mnew = fmaxf(mrow, mx);
          float f = exp2f((mrow - mnew) * SL2E);
          lrow *= f;
          #pragma unroll
          for (int m = 0; m < 8; ++m) o[m] *= f;
          mrow = mnew;
        }
        float rs = 0.f;
        #pragma unroll
        for (int n = 0; n < 4; ++n)
          #pragma unroll
          for (int j = 0; j < 4; ++j) {
            float pv = exp2f((sc[n][j] - mrow) * SL2E);
            sc[n][j] = pv; rs += pv;
          }
        rs += __shfl_xor(rs, 16);
        rs += __shfl_xor(rs, 32);
        lrow += rs;
        // ---- P -> LDS: [16 q][64 k], 16B chunk ^ (q&7); 4 x u16x4 writes ----
        u16* Pw = Ps + w * 1024;
        #pragma unroll
        for (int n = 0; n < 4; ++n) {
          u16x4 pk;
          #pragma unroll
          for (int j = 0; j < 4; ++j) pk[j] = f2bft(sc[n][j]);
          *(u16x4*)(Pw + ql * 64 + (((n * 2 + (g >> 1)) ^ (ql & 7)) << 3) + (g & 1) * 4) = pk;
        }
        // ---- PV: O^T = V^T * P^T ----
        #pragma unroll
        for (int kk2 = 0; kk2 < 2; ++kk2) {
          bf16x8 bp = *(const bf16x8*)(Pw + ql * 64 + (((kk2 * 4 + g) ^ (ql & 7)) << 3));
          #pragma unroll
          for (int m = 0; m < 8; ++m) {
            int row = m * 16 + ql;
            bf16x8 av = *(const bf16x8*)(Vs + row * 64 + (((kk2 * 4 + g) ^ (row & 7)) << 3));
            o[m] = mfma16(av, bp, o[m]);
          }
        }
      }
      __builtin_amdgcn_s_barrier();   // all waves done with Ks/Vs before restage
    }
    // ---- epilogue: normalize (lane-local l), transpose via LDS, store ----
    __syncthreads();
    u16* OS = SM; // [64][136]
    float linv = 1.0f / lrow;
    #pragma unroll
    for (int m = 0; m < 8; ++m)
      #pragma unroll
      for (int j = 0; j < 4; ++j)
        OS[(w * 16 + ql) * 136 + m * 16 + g * 4 + j] = f2bf(o[m][j] * linv);
    __syncthreads();
    #pragma unroll
    for (int p = 0; p < 4; ++p) {
      int c = tid + p * 256;
      int row = c >> 4, col8 = c & 15;
      u16x8 d = *(const u16x8*)(OS + row * 136 + col8 * 8);
      *(u16x8*)(Oh + (size_t)(qt * 64 + row) * NQ_ + col8 * 8) = d;
    }
  }
}

extern "C" void kernel_launch(void* const* d_in, const int* in_sizes, int n_in,
                              void* d_out, int out_size, void* d_ws, size_t ws_size,
                              hipStream_t stream) {
  const float* x  = (const float*)d_in[0];
  const float* fc = (const float*)d_in[1];
  const float* fs = (const float*)d_in[2];
  // d_in[3] = mask (causal, applied analytically)
  const float* wq = (const float*)d_in[4];
  const float* wk = (const float*)d_in[5];
  const float* wv = (const float*)d_in[6];
  const float* wo = (const float*)d_in[7];

  char* ws = (char*)d_ws;
  u16* xb  = (u16*)(ws + 0);          // 33554432 B
  u16* wqT = (u16*)(ws + 33554432);   // 33554432
  u16* wkT = (u16*)(ws + 67108864);   // 8388608   (wkT||wvT = [2048][4096])
  u16* wvT = (u16*)(ws + 75497472);   // 8388608
  u16* woT = (u16*)(ws + 83886080);   // 33554432
  u16* qb  = (u16*)(ws + 117440512);  // 33554432
  u16* kb  = (u16*)(ws + 150994944);  // 8388608
  u16* vtg = (u16*)(ws + 159383552);  // 8388608  (V^T tiled: [B][KV][32][128][64])
  u16* ob  = (u16*)(ws + 167772160);  // 33554432  -> total 201326592
  if (ws_size < 201326592u) return;

  cvt_bf16<<<(M_ * D_) / (8 * 256), 256, 0, stream>>>(x, xb, M_ * D_);
  tcvt<<<dim3(NQ_ / 32, D_ / 32), 256, 0, stream>>>(wq, wqT, D_, NQ_);
  tcvt<<<dim3(NKV_ / 32, D_ / 32), 256, 0, stream>>>(wk, wkT, D_, NKV_);
  tcvt<<<dim3(NKV_ / 32, D_ / 32), 256, 0, stream>>>(wv, wvT, D_, NKV_);
  tcvt<<<dim3(D_ / 32, NQ_ / 32), 256, 0, stream>>>(wo, woT, NQ_, D_);

  gemm256<0><<<(NQ_ / 256) * (M_ / 256), 512, 98304, stream>>>(xb, wqT, qb, M_, NQ_, D_);
  // fused K+V projection: N=2048 (wkT||wvT contiguous)
  gemm_bt<3><<<dim3(2048 / 128, M_ / 128), 256, 0, stream>>>(xb, wkT, kb, vtg, M_, 2048, D_);

  rope_kernel<<<(M_ * NQ_ / 2) / 256, 256, 0, stream>>>(qb, fc, fs, 11, M_ * NQ_ / 2);
  rope_kernel<<<(M_ * NKV_ / 2) / 256, 256, 0, stream>>>(kb, fc, fs, 9, M_ * NKV_ / 2);

  attn_kernel<<<dim3(16, H_, B_), 256, 0, stream>>>(qb, kb, vtg, ob);

  gemm256<1><<<(D_ / 256) * (M_ / 256), 512, 98304, stream>>>(ob, woT, d_out, M_, D_, NQ_);
}

// Round 11
// 526.890 us; speedup vs baseline: 2.5309x; 1.1015x over previous
//
#include <hip/hip_runtime.h>
#include <stdint.h>

#define B_ 2
#define S_ 2048
#define D_ 4096
#define H_ 32
#define KV_ 8
#define HD_ 128
#define M_ (B_*S_)          // 4096 rows (b*S+s)
#define NQ_ (H_*HD_)        // 4096
#define NKV_ (KV_*HD_)      // 1024

typedef unsigned short u16;
typedef __bf16 bf16x8 __attribute__((ext_vector_type(8)));
typedef float f32x4 __attribute__((ext_vector_type(4)));
typedef u16 u16x8 __attribute__((ext_vector_type(8)));
typedef u16 u16x4 __attribute__((ext_vector_type(4)));

__device__ __forceinline__ u16 f2bf(float f) {
  union { float f; unsigned u; } v; v.f = f;
  unsigned r = v.u + 0x7fffu + ((v.u >> 16) & 1u);
  return (u16)(r >> 16);
}
__device__ __forceinline__ u16 f2bft(float f) {  // truncating (for P; values in [0,4.2])
  union { float f; unsigned u; } v; v.f = f;
  return (u16)(v.u >> 16);
}
__device__ __forceinline__ float bf2f(u16 u) {
  union { unsigned u; float f; } v; v.u = ((unsigned)u) << 16;
  return v.f;
}
__device__ __forceinline__ f32x4 mfma16(bf16x8 a, bf16x8 b, f32x4 c) {
  return __builtin_amdgcn_mfma_f32_16x16x32_bf16(a, b, c, 0, 0, 0);
}

#define GLDS16(gp, lp) __builtin_amdgcn_global_load_lds( \
    (const __attribute__((address_space(1))) unsigned int*)(gp), \
    (__attribute__((address_space(3))) unsigned int*)(lp), 16, 0, 0)

// ---------------- fp32 -> bf16 convert (vectorized) ----------------
__global__ __launch_bounds__(256) void cvt_bf16(const float* __restrict__ in,
                                                u16* __restrict__ out, int n) {
  int i = (blockIdx.x * 256 + threadIdx.x) * 8;
  if (i >= n) return;
  float4 a = *(const float4*)(in + i);
  float4 b = *(const float4*)(in + i + 4);
  u16x8 o;
  o[0]=f2bf(a.x); o[1]=f2bf(a.y); o[2]=f2bf(a.z); o[3]=f2bf(a.w);
  o[4]=f2bf(b.x); o[5]=f2bf(b.y); o[6]=f2bf(b.z); o[7]=f2bf(b.w);
  *(u16x8*)(out + i) = o;
}

// -------- transpose + convert: out[c][r] = in[r][c], 64x64, vectorized --------
// float4 loads (16B/lane), f32 LDS [64][65] (stage 2-way, drain 2-way max),
// u16x8 x2 coalesced stores (32B/lane). ~2x the old scalar 32x32 version.
__global__ __launch_bounds__(256) void tcvt(const float* __restrict__ in,
                                            u16* __restrict__ out, int R, int C) {
  __shared__ float tf[64][65];
  int c0 = blockIdx.x * 64, r0 = blockIdx.y * 64;
  int l16 = threadIdx.x & 15, r16 = threadIdx.x >> 4;
  #pragma unroll
  for (int p = 0; p < 4; ++p) {
    int r = p * 16 + r16;
    float4 v = *(const float4*)(in + (size_t)(r0 + r) * C + c0 + l16 * 4);
    tf[r][l16 * 4 + 0] = v.x; tf[r][l16 * 4 + 1] = v.y;
    tf[r][l16 * 4 + 2] = v.z; tf[r][l16 * 4 + 3] = v.w;
  }
  __syncthreads();
  int oc = threadIdx.x >> 2, ch = threadIdx.x & 3;
  u16x8 o1, o2;
  #pragma unroll
  for (int i = 0; i < 8; ++i) o1[i] = f2bf(tf[ch * 16 + i][oc]);
  #pragma unroll
  for (int i = 0; i < 8; ++i) o2[i] = f2bf(tf[ch * 16 + 8 + i][oc]);
  *(u16x8*)(out + (size_t)(c0 + oc) * R + r0 + ch * 16) = o1;
  *(u16x8*)(out + (size_t)(c0 + oc) * R + r0 + ch * 16 + 8) = o2;
}

// ------- 256x256 GEMM, 3-buf rotation + FULL cross-tile register pipeline -------
// (unchanged from R10; ~1015 TF. Sync-economics-capped: 1 vmcnt+barrier/tile is
// the feasible minimum at this LDS budget; >2 waves/SIMD blocked by 128-AGPR acc.)
template<int OUTMODE>
__global__ __launch_bounds__(512, 2) void gemm256(const u16* __restrict__ A,
    const u16* __restrict__ BT, void* __restrict__ Cv, int M, int N, int K) {
  extern __shared__ __attribute__((aligned(16))) u16 DL[];  // 3 x 16384 u16
  const int tid = threadIdx.x;
  const int nbx = N >> 8;
  const int cpx = gridDim.x >> 3;                 // grid % 8 == 0
  const int swzb = (blockIdx.x & 7) * cpx + (blockIdx.x >> 3);
  const int bn0 = (swzb % nbx) << 8, bm0 = (swzb / nbx) << 8;
  const int l = tid & 63, g = l >> 4, q = l & 15;
  const int w = tid >> 6;
  const int wm = (w >> 2) * 128, wn = (w & 3) * 64;
  const int nt = K >> 5;   // BK = 32
  f32x4 acc[8][4] = {};

  const int srow = tid >> 2, schunk = tid & 3;
  const int ssw = (schunk ^ ((srow >> 1) & 3)) << 3;
  const u16* gA0 = A  + (size_t)(bm0 + srow) * K + ssw;
  const u16* gA1 = gA0 + (size_t)128 * K;
  const u16* gB0 = BT + (size_t)(bn0 + srow) * K + ssw;
  const u16* gB1 = gB0 + (size_t)128 * K;

  auto STAGE = [&](int t) {
    const int kt = t << 5;
    u16* d = DL + (t % 3) * 16384;
    GLDS16(gA0 + kt, d + tid * 8);
    GLDS16(gA1 + kt, d + 4096 + tid * 8);
    GLDS16(gB0 + kt, d + 8192 + tid * 8);
    GLDS16(gB1 + kt, d + 12288 + tid * 8);
  };

  const u16* ra = DL + (wm + q) * 32 + ((g ^ (((wm + q) >> 1) & 3)) << 3);
  const u16* rb = DL + 8192 + (wn + q) * 32 + ((g ^ (((wn + q) >> 1) & 3)) << 3);

  bf16x8 aC[8], aN[8], bC[4], bN[4];

  STAGE(0); STAGE(1);
  asm volatile("s_waitcnt vmcnt(4)" ::: "memory");
  __builtin_amdgcn_s_barrier();
  #pragma unroll
  for (int m = 0; m < 8; ++m) aC[m] = *(const bf16x8*)(ra + m * 512);
  #pragma unroll
  for (int n = 0; n < 4; ++n) bC[n] = *(const bf16x8*)(rb + n * 512);

  auto TILE = [&](int t, bf16x8 (&ac)[8], bf16x8 (&bc)[4],
                         bf16x8 (&an)[8], bf16x8 (&bn)[4]) {
    if (t + 2 < nt) {
      STAGE(t + 2);
      asm volatile("s_waitcnt vmcnt(4)" ::: "memory");
    } else {
      asm volatile("s_waitcnt vmcnt(0)" ::: "memory");
    }
    __builtin_amdgcn_s_barrier();
    if (t + 1 < nt) {
      const u16* pa = ra + ((t + 1) % 3) * 16384;
      const u16* pb = rb + ((t + 1) % 3) * 16384;
      #pragma unroll
      for (int m = 0; m < 8; ++m) an[m] = *(const bf16x8*)(pa + m * 512);
      #pragma unroll
      for (int n = 0; n < 4; ++n) bn[n] = *(const bf16x8*)(pb + n * 512);
    }
    __builtin_amdgcn_s_setprio(1);
    #pragma unroll
    for (int m = 0; m < 8; ++m) {
      acc[m][0] = mfma16(ac[m], bc[0], acc[m][0]);
      acc[m][1] = mfma16(ac[m], bc[1], acc[m][1]);
      acc[m][2] = mfma16(ac[m], bc[2], acc[m][2]);
      acc[m][3] = mfma16(ac[m], bc[3], acc[m][3]);
    }
    __builtin_amdgcn_s_setprio(0);
  };

  for (int t = 0; t < nt; t += 2) {
    TILE(t,     aC, bC, aN, bN);
    TILE(t + 1, aN, bN, aC, bC);
  }

  #pragma unroll
  for (int m = 0; m < 8; ++m)
    #pragma unroll
    for (int n = 0; n < 4; ++n)
      #pragma unroll
      for (int j = 0; j < 4; ++j) {
        size_t off = (size_t)(bm0 + wm + m * 16 + g * 4 + j) * N + (bn0 + wn + n * 16 + q);
        if (OUTMODE == 1) ((float*)Cv)[off] = acc[m][n][j];
        else              ((u16*)Cv)[off]  = f2bf(acc[m][n][j]);
      }
}

// ------- KV projection GEMM: BM=256 x BN=128, same 3-buf reg pipeline -------
// Replaces the m97-class gemm_bt<3>. N=2048 -> grid 16x16 = 256 = 1 block/CU.
// acc[8][2] (64 AGPR), 3 gloads/tile (A 16KB = 2, B 8KB = 1), LDS 3x24KB=72KB,
// counted vmcnt(3). Epilogue: col<1024 -> K row-major; col>=1024 -> V^T
// 16KB-tiled [B][KV][32][128][64].
__global__ __launch_bounds__(512, 2) void gemm_kv(const u16* __restrict__ A,
    const u16* __restrict__ BT, u16* __restrict__ Ck, u16* __restrict__ Cvt,
    int M, int N, int K) {
  extern __shared__ __attribute__((aligned(16))) u16 DL[];  // 3 x 12288 u16
  const int tid = threadIdx.x;
  const int nbx = N >> 7;                          // 16
  const int cpx = gridDim.x >> 3;
  const int swzb = (blockIdx.x & 7) * cpx + (blockIdx.x >> 3);
  const int bn0 = (swzb % nbx) << 7, bm0 = (swzb / nbx) << 8;
  const int l = tid & 63, g = l >> 4, q = l & 15;
  const int w = tid >> 6;
  const int wm = (w >> 2) * 128, wn = (w & 3) * 32;
  const int nt = K >> 5;
  f32x4 acc[8][2] = {};

  const int srow = tid >> 2, schunk = tid & 3;
  const int ssw = (schunk ^ ((srow >> 1) & 3)) << 3;
  const u16* gA0 = A  + (size_t)(bm0 + srow) * K + ssw;
  const u16* gA1 = gA0 + (size_t)128 * K;
  const u16* gB0 = BT + (size_t)(bn0 + srow) * K + ssw;

  auto STAGE = [&](int t) {
    const int kt = t << 5;
    u16* d = DL + (t % 3) * 12288;
    GLDS16(gA0 + kt, d + tid * 8);
    GLDS16(gA1 + kt, d + 4096 + tid * 8);
    GLDS16(gB0 + kt, d + 8192 + tid * 8);
  };

  const u16* ra = DL + (wm + q) * 32 + ((g ^ (((wm + q) >> 1) & 3)) << 3);
  const u16* rb = DL + 8192 + (wn + q) * 32 + ((g ^ (((wn + q) >> 1) & 3)) << 3);

  bf16x8 aC[8], aN[8], bC[2], bN[2];

  STAGE(0); STAGE(1);
  asm volatile("s_waitcnt vmcnt(3)" ::: "memory");
  __builtin_amdgcn_s_barrier();
  #pragma unroll
  for (int m = 0; m < 8; ++m) aC[m] = *(const bf16x8*)(ra + m * 512);
  #pragma unroll
  for (int n = 0; n < 2; ++n) bC[n] = *(const bf16x8*)(rb + n * 512);

  auto TILE = [&](int t, bf16x8 (&ac)[8], bf16x8 (&bc)[2],
                         bf16x8 (&an)[8], bf16x8 (&bn)[2]) {
    if (t + 2 < nt) {
      STAGE(t + 2);
      asm volatile("s_waitcnt vmcnt(3)" ::: "memory");
    } else {
      asm volatile("s_waitcnt vmcnt(0)" ::: "memory");
    }
    __builtin_amdgcn_s_barrier();
    if (t + 1 < nt) {
      const u16* pa = ra + ((t + 1) % 3) * 12288;
      const u16* pb = rb + ((t + 1) % 3) * 12288;
      #pragma unroll
      for (int m = 0; m < 8; ++m) an[m] = *(const bf16x8*)(pa + m * 512);
      #pragma unroll
      for (int n = 0; n < 2; ++n) bn[n] = *(const bf16x8*)(pb + n * 512);
    }
    __builtin_amdgcn_s_setprio(1);
    #pragma unroll
    for (int m = 0; m < 8; ++m) {
      acc[m][0] = mfma16(ac[m], bc[0], acc[m][0]);
      acc[m][1] = mfma16(ac[m], bc[1], acc[m][1]);
    }
    __builtin_amdgcn_s_setprio(0);
  };

  for (int t = 0; t < nt; t += 2) {
    TILE(t,     aC, bC, aN, bN);
    TILE(t + 1, aN, bN, aC, bC);
  }

  #pragma unroll
  for (int m = 0; m < 8; ++m)
    #pragma unroll
    for (int n = 0; n < 2; ++n) {
      int row0 = bm0 + wm + m * 16 + g * 4;
      int col  = bn0 + wn + n * 16 + q;
      if (col < 1024) {
        #pragma unroll
        for (int j = 0; j < 4; ++j)
          Ck[(size_t)(row0 + j) * 1024 + col] = f2bf(acc[m][n][j]);
      } else {
        int c2 = col - 1024;
        u16x4 pk;
        #pragma unroll
        for (int j = 0; j < 4; ++j) pk[j] = f2bf(acc[m][n][j]);
        size_t off = ((size_t)((row0 >> 11) * KV_ + (c2 >> 7)) * 32 + ((row0 >> 6) & 31)) * 8192
                   + (size_t)(c2 & 127) * 64 + (row0 & 63);
        *(u16x4*)(Cvt + off) = pk;
      }
    }
}

// ---------------- RoPE (interleaved pairs, in-place on bf16) ----------------
__global__ __launch_bounds__(256) void rope_kernel(u16* __restrict__ t,
    const float* __restrict__ fc, const float* __restrict__ fs,
    int log2ppr, int total_pairs) {
  int i = blockIdx.x * 256 + threadIdx.x;
  if (i >= total_pairs) return;
  int fi = i & 63;
  int row = i >> log2ppr;           // b*S + s
  int pos = row & (S_ - 1);
  float c = fc[pos * 64 + fi], s = fs[pos * 64 + fi];
  unsigned* p = (unsigned*)(t + 2 * (size_t)i);
  unsigned v = *p;
  float x0 = bf2f((u16)(v & 0xffffu)), x1 = bf2f((u16)(v >> 16));
  float r0 = x0 * c - x1 * s, r1 = x0 * s + x1 * c;
  *p = (unsigned)f2bf(r0) | ((unsigned)f2bf(r1) << 16);
}

// ---------------- causal GQA flash attention (swapped-QK^T) ----------------
// grid (16, H, B) = 1024 blocks = 4/CU; block 256 = 4 waves; QT=64
// (16 q-rows/wave), pairing {31-p, p} -> uniform 33 K-iters/block.
// S^T = mfma(K_frag, Q_frag): each lane owns ONE q-col (l&15) with 16
// k-values in regs -> softmax = in-lane max/sum + 2 shfl. P -> LDS as
// 4 x u16x4 vectorized writes (chunk-XOR swz). Defer-max THR=16.
// LDS 40KB -> 4 blocks/CU; launch_bounds (256,4).
__global__ __launch_bounds__(256, 4) void attn_kernel(
    const u16* __restrict__ Qb, const u16* __restrict__ Kb,
    const u16* __restrict__ VTg, u16* __restrict__ Ob) {
  __shared__ __attribute__((aligned(16))) u16 SM[20480]; // 40KB
  u16* Ks = SM;            // [64][128] swz(row&7)
  u16* Vs = SM + 8192;     // [128][64] swz(row&7)
  u16* Ps = SM + 16384;    // 4 waves x [16 q][64 k], 16B-chunk ^ (q&7)
  const int pr = blockIdx.x;            // 0..15
  const int h = blockIdx.y, b = blockIdx.z;
  const int kvh = h >> 2;               // N_REP = 4
  const int tid = threadIdx.x, w = tid >> 6, l = tid & 63, g = l >> 4, ql = l & 15;
  const float SL2E = 0.08838834764831845f * 1.4426950408889634f;
  const u16* Qh = Qb + (size_t)b * S_ * NQ_ + h * HD_;
  const u16* Kh = Kb + ((size_t)b * S_ * KV_ + kvh) * HD_;
  const u16* Vh = VTg + (size_t)(b * KV_ + kvh) * (32 * 8192);
  u16* Oh = Ob + (size_t)b * S_ * NQ_ + h * HD_;

  for (int ph = 0; ph < 2; ++ph) {
    const int qt = ph ? pr : 31 - pr;
    __syncthreads();   // SM (epilogue scratch) free before restaging
    bf16x8 aq[4];
    #pragma unroll
    for (int kk = 0; kk < 4; ++kk)
      aq[kk] = *(const bf16x8*)(Qh + (size_t)(qt * 64 + w * 16 + ql) * NQ_ + kk * 32 + g * 8);

    f32x4 o[8] = {};
    float mrow = -3.0e38f, lrow = 0.f;

    const int nkt = qt + 1;
    for (int kt = 0; kt < nkt; ++kt) {
      #pragma unroll
      for (int p = 0; p < 4; ++p) {   // K: [64][128]
        int c = tid + p * 256;
        int row = c >> 4, slot = c & 15;
        GLDS16(Kh + (size_t)(kt * 64 + row) * (KV_ * HD_) + ((slot ^ (row & 7)) << 3), Ks + c * 8);
      }
      #pragma unroll
      for (int p = 0; p < 4; ++p) {   // V^T: [128][64] from contiguous 16KB tile
        int c = tid + p * 256;
        int row = c >> 3, slot = c & 7;
        GLDS16(Vh + (size_t)kt * 8192 + row * 64 + ((slot ^ (row & 7)) << 3), Vs + c * 8);
      }
      asm volatile("s_waitcnt vmcnt(0)" ::: "memory");
      __builtin_amdgcn_s_barrier();

      if (kt * 64 <= qt * 64 + w * 16 + 15) {   // wave-uniform activity gate
        // ---- S^T = K * Q^T ----
        f32x4 sc[4] = {};
        #pragma unroll
        for (int kk = 0; kk < 4; ++kk) {
          bf16x8 bk[4];
          #pragma unroll
          for (int n = 0; n < 4; ++n) {
            int row = n * 16 + ql;
            bk[n] = *(const bf16x8*)(Ks + row * 128 + (((kk * 4 + g) ^ (row & 7)) << 3));
          }
          #pragma unroll
          for (int n = 0; n < 4; ++n)
            sc[n] = mfma16(bk[n], aq[kk], sc[n]);
        }
        // ---- causal mask (diagonal tiles only); lane holds k=kt*64+n*16+g*4+j, q=ql ----
        const int qglob = qt * 64 + w * 16 + ql;
        if (kt * 64 + 63 > qt * 64 + w * 16) {
          #pragma unroll
          for (int n = 0; n < 4; ++n)
            #pragma unroll
            for (int j = 0; j < 4; ++j)
              if (kt * 64 + n * 16 + g * 4 + j > qglob) sc[n][j] = -3.0e38f;
        }
        // ---- online softmax: in-lane over 16 k-vals, then xor16/xor32 ----
        float mx = sc[0][0];
        #pragma unroll
        for (int n = 0; n < 4; ++n)
          #pragma unroll
          for (int j = 0; j < 4; ++j) mx = fmaxf(mx, sc[n][j]);
        mx = fmaxf(mx, __shfl_xor(mx, 16));
        mx = fmaxf(mx, __shfl_xor(mx, 32));
        if (!__all(mx - mrow <= 16.0f)) {      // defer-max: P bounded by 2^2.04
          float mnew = fmaxf(mrow, mx);
          float f = exp2f((mrow - mnew) * SL2E);
          lrow *= f;
          #pragma unroll
          for (int m = 0; m < 8; ++m) o[m] *= f;
          mrow = mnew;
        }
        float rs = 0.f;
        #pragma unroll
        for (int n = 0; n < 4; ++n)
          #pragma unroll
          for (int j = 0; j < 4; ++j) {
            float pv = exp2f((sc[n][j] - mrow) * SL2E);
            sc[n][j] = pv; rs += pv;
          }
        rs += __shfl_xor(rs, 16);
        rs += __shfl_xor(rs, 32);
        lrow += rs;
        // ---- P -> LDS: [16 q][64 k], 16B chunk ^ (q&7); 4 x u16x4 writes ----
        u16* Pw = Ps + w * 1024;
        #pragma unroll
        for (int n = 0; n < 4; ++n) {
          u16x4 pk;
          #pragma unroll
          for (int j = 0; j < 4; ++j) pk[j] = f2bft(sc[n][j]);
          *(u16x4*)(Pw + ql * 64 + (((n * 2 + (g >> 1)) ^ (ql & 7)) << 3) + (g & 1) * 4) = pk;
        }
        // ---- PV: O^T = V^T * P^T ----
        #pragma unroll
        for (int kk2 = 0; kk2 < 2; ++kk2) {
          bf16x8 bp = *(const bf16x8*)(Pw + ql * 64 + (((kk2 * 4 + g) ^ (ql & 7)) << 3));
          #pragma unroll
          for (int m = 0; m < 8; ++m) {
            int row = m * 16 + ql;
            bf16x8 av = *(const bf16x8*)(Vs + row * 64 + (((kk2 * 4 + g) ^ (row & 7)) << 3));
            o[m] = mfma16(av, bp, o[m]);
          }
        }
      }
      __builtin_amdgcn_s_barrier();   // all waves done with Ks/Vs before restage
    }
    // ---- epilogue: normalize (lane-local l), transpose via LDS, store ----
    __syncthreads();
    u16* OS = SM; // [64][136]
    float linv = 1.0f / lrow;
    #pragma unroll
    for (int m = 0; m < 8; ++m)
      #pragma unroll
      for (int j = 0; j < 4; ++j)
        OS[(w * 16 + ql) * 136 + m * 16 + g * 4 + j] = f2bf(o[m][j] * linv);
    __syncthreads();
    #pragma unroll
    for (int p = 0; p < 4; ++p) {
      int c = tid + p * 256;
      int row = c >> 4, col8 = c & 15;
      u16x8 d = *(const u16x8*)(OS + row * 136 + col8 * 8);
      *(u16x8*)(Oh + (size_t)(qt * 64 + row) * NQ_ + col8 * 8) = d;
    }
  }
}

extern "C" void kernel_launch(void* const* d_in, const int* in_sizes, int n_in,
                              void* d_out, int out_size, void* d_ws, size_t ws_size,
                              hipStream_t stream) {
  const float* x  = (const float*)d_in[0];
  const float* fc = (const float*)d_in[1];
  const float* fs = (const float*)d_in[2];
  // d_in[3] = mask (causal, applied analytically)
  const float* wq = (const float*)d_in[4];
  const float* wk = (const float*)d_in[5];
  const float* wv = (const float*)d_in[6];
  const float* wo = (const float*)d_in[7];

  char* ws = (char*)d_ws;
  u16* xb  = (u16*)(ws + 0);          // 33554432 B
  u16* wqT = (u16*)(ws + 33554432);   // 33554432
  u16* wkT = (u16*)(ws + 67108864);   // 8388608   (wkT||wvT = [2048][4096])
  u16* wvT = (u16*)(ws + 75497472);   // 8388608
  u16* woT = (u16*)(ws + 83886080);   // 33554432
  u16* qb  = (u16*)(ws + 117440512);  // 33554432
  u16* kb  = (u16*)(ws + 150994944);  // 8388608
  u16* vtg = (u16*)(ws + 159383552);  // 8388608  (V^T tiled: [B][KV][32][128][64])
  u16* ob  = (u16*)(ws + 167772160);  // 33554432  -> total 201326592
  if (ws_size < 201326592u) return;

  cvt_bf16<<<(M_ * D_) / (8 * 256), 256, 0, stream>>>(x, xb, M_ * D_);
  tcvt<<<dim3(NQ_ / 64, D_ / 64), 256, 0, stream>>>(wq, wqT, D_, NQ_);
  tcvt<<<dim3(NKV_ / 64, D_ / 64), 256, 0, stream>>>(wk, wkT, D_, NKV_);
  tcvt<<<dim3(NKV_ / 64, D_ / 64), 256, 0, stream>>>(wv, wvT, D_, NKV_);
  tcvt<<<dim3(D_ / 64, NQ_ / 64), 256, 0, stream>>>(wo, woT, NQ_, D_);

  gemm256<0><<<(NQ_ / 256) * (M_ / 256), 512, 98304, stream>>>(xb, wqT, qb, M_, NQ_, D_);
  // fused K+V projection: N=2048 (wkT||wvT contiguous), 256x128-tile pipeline
  gemm_kv<<<(2048 / 128) * (M_ / 256), 512, 73728, stream>>>(xb, wkT, kb, vtg, M_, 2048, D_);

  rope_kernel<<<(M_ * NQ_ / 2) / 256, 256, 0, stream>>>(qb, fc, fs, 11, M_ * NQ_ / 2);
  rope_kernel<<<(M_ * NKV_ / 2) / 256, 256, 0, stream>>>(kb, fc, fs, 9, M_ * NKV_ / 2);

  attn_kernel<<<dim3(16, H_, B_), 256, 0, stream>>>(qb, kb, vtg, ob);

  gemm256<1><<<(D_ / 256) * (M_ / 256), 512, 98304, stream>>>(ob, woT, d_out, M_, D_, NQ_);
}